// Round 2
// baseline (2441.377 us; speedup 1.0000x reference)
//
#include <hip/hip_runtime.h>
#include <hip/hip_bf16.h>
#include <math.h>

#define MROWS 4096      // BATCH * L
#define DMODEL 384
#define DINNER 768
#define GCOLS 56        // DT_RANK + 2*D_STATE
#define DTRANK 24
#define NSTATE 16

__device__ __forceinline__ float silu_f(float x){ return x / (1.f + __expf(-x)); }

// seq index t -> token index, per direction
__device__ __forceinline__ int perm_tok(int dir, int t){
  if (dir == 0) return t;
  if (dir == 2) return 1023 - t;
  int tt = (dir == 1) ? t : (1023 - t);
  int i = tt >> 5, j = tt & 31;
  return ((31 - j) << 5) | i;   // token = (31-j)*32 + i
}

// ---------------- generic fp32 GEMM: C[M,N] = A[M,K] @ W[N,K]^T ----------------
// EPI 0: none; 1: softplus(x + bias); 2: x + bias + res
template<int EPI>
__launch_bounds__(256)
__global__ void gemm_k(const float* __restrict__ A, int lda,
                       const float* __restrict__ W,
                       float* __restrict__ C, int ldc,
                       int Ndim, int Kdim,
                       const float* __restrict__ bias,
                       const float* __restrict__ res)
{
  __shared__ float As[16][68];   // [k][m]
  __shared__ float Bs[16][68];   // [k][n]
  const int tid = threadIdx.x;
  const int m0 = blockIdx.y * 64;
  const int n0 = blockIdx.x * 64;
  const int tr = tid >> 4, tc = tid & 15;
  const int r  = tid >> 2, q  = tid & 3;
  float acc[4][4] = {};

  for (int k0 = 0; k0 < Kdim; k0 += 16) {
    { // A tile: 64 rows x 16 k
      const float* ap = A + (size_t)(m0 + r) * lda + (k0 + q*4);
      float v0=0.f,v1=0.f,v2=0.f,v3=0.f;
      int kc = Kdim - (k0 + q*4);
      if (kc >= 4) { float4 t4 = *(const float4*)ap; v0=t4.x; v1=t4.y; v2=t4.z; v3=t4.w; }
      else { if (kc>0) v0=ap[0]; if (kc>1) v1=ap[1]; if (kc>2) v2=ap[2]; }
      As[q*4+0][r]=v0; As[q*4+1][r]=v1; As[q*4+2][r]=v2; As[q*4+3][r]=v3;
    }
    { // W tile: 64 n-rows x 16 k
      int nr = n0 + r;
      float v0=0.f,v1=0.f,v2=0.f,v3=0.f;
      if (nr < Ndim) {
        const float* wp = W + (size_t)nr * Kdim + (k0 + q*4);
        int kc = Kdim - (k0 + q*4);
        if (kc >= 4) { float4 t4 = *(const float4*)wp; v0=t4.x; v1=t4.y; v2=t4.z; v3=t4.w; }
        else { if (kc>0) v0=wp[0]; if (kc>1) v1=wp[1]; if (kc>2) v2=wp[2]; }
      }
      Bs[q*4+0][r]=v0; Bs[q*4+1][r]=v1; Bs[q*4+2][r]=v2; Bs[q*4+3][r]=v3;
    }
    __syncthreads();
#pragma unroll
    for (int kk = 0; kk < 16; kk++) {
      float4 a4 = *(const float4*)&As[kk][tr*4];
      float4 b4 = *(const float4*)&Bs[kk][tc*4];
      float av[4] = {a4.x,a4.y,a4.z,a4.w};
      float bv[4] = {b4.x,b4.y,b4.z,b4.w};
#pragma unroll
      for (int i2=0;i2<4;i2++)
#pragma unroll
        for (int j2=0;j2<4;j2++)
          acc[i2][j2] = __builtin_fmaf(av[i2], bv[j2], acc[i2][j2]);
    }
    __syncthreads();
  }

#pragma unroll
  for (int i2=0;i2<4;i2++){
    int m = m0 + tr*4 + i2;
#pragma unroll
    for (int j2=0;j2<4;j2++){
      int n = n0 + tc*4 + j2;
      if (n < Ndim){
        float v = acc[i2][j2];
        if (EPI == 1) { v += bias[n]; v = (v > 20.f) ? v : log1pf(__expf(v)); }
        if (EPI == 2) { v += bias[n] + res[(size_t)m*ldc + n]; }
        C[(size_t)m*ldc + n] = v;
      }
    }
  }
}

// ---------------- misc ----------------
__global__ void zero_k(float* __restrict__ p, int n){
  int id = blockIdx.x*256 + threadIdx.x;
  if (id < n) p[id] = 0.f;
}

// depthwise causal conv (k=4) over permuted sequence + bias + silu
__launch_bounds__(256)
__global__ void conv_k(const float* __restrict__ xz, const float* __restrict__ cw,
                       const float* __restrict__ cb, float* __restrict__ ucv)
{
  int id = blockIdx.x*256 + threadIdx.x;          // ((dir*4+b)*1024+t)*768+d
  int d = id % DINNER;
  int t = (id / DINNER) & 1023;
  int btdir = id / (DINNER*1024);
  int b_ = btdir & 3, dir = btdir >> 2;
  float s = cb[d];
  const float* up = xz + (size_t)b_*1024*1536 + d;   // u0 = first 768 cols of xz
#pragma unroll
  for (int j=0;j<4;j++){
    int tm = t - 3 + j;
    if (tm >= 0) s += cw[d*4+j] * up[(size_t)perm_tok(dir,tm)*1536];
  }
  ucv[id] = silu_f(s);
}

// sequential selective scan; one thread per (dir,b,d); scatter-add into token-space acc
__launch_bounds__(64)
__global__ void scan_k(const float* __restrict__ dtb, const float* __restrict__ ucv,
                       const float* __restrict__ xdb,
                       const float* __restrict__ A_log, const float* __restrict__ Dp,
                       float* __restrict__ acc)
{
  int gid = blockIdx.x * 64 + threadIdx.x;   // 4*4*768 = 12288
  int dir = gid / 3072;
  int rem = gid - dir * 3072;
  int b = rem / DINNER;
  int d = rem - b * DINNER;

  float A2[NSTATE];
#pragma unroll
  for (int n=0;n<NSTATE;n++)
    A2[n] = -__expf(A_log[d*NSTATE + n]) * 1.44269504f;   // A*log2(e)
  float Dd = Dp[d];

  const float* dtp = dtb + (size_t)dir*MROWS*DINNER + (size_t)b*1024*DINNER + d;
  const float* up  = ucv + (size_t)dir*MROWS*DINNER + (size_t)b*1024*DINNER + d;
  const float* bc  = xdb + (size_t)dir*MROWS*GCOLS  + (size_t)b*1024*GCOLS;
  float* ab = acc + (size_t)b*1024*DINNER + d;

  float h[NSTATE] = {};
  for (int t=0;t<1024;t++){
    float dt = dtp[(size_t)t*DINNER];
    float u  = up[(size_t)t*DINNER];
    const float* Bv = bc + t*GCOLS + DTRANK;
    const float* Cv = Bv + NSTATE;
    float du = dt * u;
    float y = 0.f;
#pragma unroll
    for (int n=0;n<NSTATE;n++){
      float w = exp2f(dt * A2[n]);
      h[n] = h[n]*w + du * Bv[n];
      y = __builtin_fmaf(h[n], Cv[n], y);
    }
    int tok = perm_tok(dir, t);
    atomicAdd(ab + (size_t)tok*DINNER, y + u*Dd);
  }
}

// acc *= silu(z)   (z = cols 768.. of xz)
__global__ void combine_k(float* __restrict__ acc, const float* __restrict__ xz)
{
  int id = blockIdx.x*256 + threadIdx.x;     // < MROWS*DINNER
  int row = id / DINNER;
  int d = id - row*DINNER;
  float z = xz[(size_t)row*1536 + DINNER + d];
  acc[id] *= silu_f(z);
}

// layernorm over 384, one wave per row
__launch_bounds__(256)
__global__ void ln384_k(const float* __restrict__ in, float* __restrict__ out,
                        const float* __restrict__ w, const float* __restrict__ b)
{
  int wv = threadIdx.x >> 6, lane = threadIdx.x & 63;
  size_t row = (size_t)blockIdx.x * 4 + wv;
  const float* ip = in + row * DMODEL;
  float v[6];
#pragma unroll
  for (int k=0;k<6;k++) v[k] = ip[lane + 64*k];
  float s = 0.f;
#pragma unroll
  for (int k=0;k<6;k++) s += v[k];
#pragma unroll
  for (int o=32;o>0;o>>=1) s += __shfl_xor(s, o);
  float mu = s * (1.f/DMODEL);
  float ss = 0.f;
#pragma unroll
  for (int k=0;k<6;k++){ float dd = v[k]-mu; ss += dd*dd; }
#pragma unroll
  for (int o=32;o>0;o>>=1) ss += __shfl_xor(ss, o);
  float inv = rsqrtf(ss*(1.f/DMODEL) + 1e-5f);
  float* op = out + row * DMODEL;
#pragma unroll
  for (int k=0;k<6;k++){ int c = lane + 64*k; op[c] = (v[k]-mu)*inv*w[c] + b[c]; }
}

// pixel-shuffle gather + layernorm over 192 + fp32 store
__launch_bounds__(256)
__global__ void peln_k(const float* __restrict__ xe, const float* __restrict__ w,
                       const float* __restrict__ b, float* __restrict__ out)
{
  int wv = threadIdx.x >> 6, lane = threadIdx.x & 63;
  int row = blockIdx.x * 4 + wv;          // 0..16383 = b*4096 + h2*64 + w2
  int bb = row >> 12;
  int r2 = row & 4095;
  int h2 = r2 >> 6, w2 = r2 & 63;
  int h = h2 >> 1, s1 = h2 & 1, w_ = w2 >> 1, s2 = w2 & 1;
  const float* ip = xe + ((size_t)(bb*1024 + h*32 + w_))*768 + (s1*2+s2)*192;
  float v[3];
#pragma unroll
  for (int k=0;k<3;k++) v[k] = ip[lane + 64*k];
  float s = v[0]+v[1]+v[2];
#pragma unroll
  for (int o=32;o>0;o>>=1) s += __shfl_xor(s, o);
  float mu = s * (1.f/192);
  float ss = 0.f;
#pragma unroll
  for (int k=0;k<3;k++){ float dd=v[k]-mu; ss+=dd*dd; }
#pragma unroll
  for (int o=32;o>0;o>>=1) ss += __shfl_xor(ss, o);
  float inv = rsqrtf(ss*(1.f/192) + 1e-5f);
  float* op = out + (size_t)row * 192;
#pragma unroll
  for (int k=0;k<3;k++){ int c = lane + 64*k; op[c] = (v[k]-mu)*inv*w[c] + b[c]; }
}

extern "C" void kernel_launch(void* const* d_in, const int* in_sizes, int n_in,
                              void* d_out, int out_size, void* d_ws, size_t ws_size,
                              hipStream_t stream)
{
  const float* x_in   = (const float*)d_in[0];
  const float* in_w   = (const float*)d_in[1];
  const float* conv_w = (const float*)d_in[2];
  const float* conv_b = (const float*)d_in[3];
  const float* xp_w   = (const float*)d_in[4];
  const float* dt_w   = (const float*)d_in[5];
  const float* dt_b   = (const float*)d_in[6];
  const float* A_log  = (const float*)d_in[7];
  const float* Dp     = (const float*)d_in[8];
  const float* mn_w   = (const float*)d_in[9];
  const float* mn_b   = (const float*)d_in[10];
  const float* mout_w = (const float*)d_in[11];
  const float* bp_w   = (const float*)d_in[12];
  const float* bp_b   = (const float*)d_in[13];
  const float* ln_w   = (const float*)d_in[14];
  const float* ln_b   = (const float*)d_in[15];
  const float* exp_w  = (const float*)d_in[16];
  const float* pe_w   = (const float*)d_in[17];
  const float* pe_b   = (const float*)d_in[18];

  float* ws = (float*)d_ws;
  float* xcur = ws;                              // 4096*384
  float* xz   = xcur + (size_t)MROWS*DMODEL;     // 4096*1536 (u0 | z)
  float* ucv  = xz   + (size_t)MROWS*1536;       // 4*4096*768
  float* xdb  = ucv  + (size_t)4*MROWS*DINNER;   // 4*4096*56
  float* dtb  = xdb  + (size_t)4*MROWS*GCOLS;    // 4*4096*768
  float* acc  = dtb  + (size_t)4*MROWS*DINNER;   // 4096*768
  float* t1   = acc  + (size_t)MROWS*DINNER;     // 4096*384
  float* t2   = t1   + (size_t)MROWS*DMODEL;     // 4096*384
  float* t3   = dtb;                             // reuse (free after scan)
  float* xe   = acc;                             // reuse (free after layers)

  // xcur = x (already fp32): copy via a cheap kernel-free path: use zero+add? simpler: d2d copy
  hipMemcpyAsync(xcur, x_in, (size_t)MROWS*DMODEL*sizeof(float), hipMemcpyDeviceToDevice, stream);

  for (int i = 0; i < 2; i++) {
    // xz = x @ in_w^T   (M=4096, N=1536, K=384)
    gemm_k<0><<<dim3(24,64), dim3(256), 0, stream>>>(
        xcur, DMODEL, in_w + (size_t)i*1536*DMODEL, xz, 1536, 1536, DMODEL, nullptr, nullptr);

    // per-direction depthwise conv + silu
    conv_k<<<dim3((4*MROWS*DINNER)/256), dim3(256), 0, stream>>>(
        xz, conv_w + (size_t)i*DINNER*4, conv_b + (size_t)i*DINNER, ucv);

    for (int dir = 0; dir < 4; dir++) {
      // xdb = u @ xp_w^T  (N=56, K=768)
      gemm_k<0><<<dim3(1,64), dim3(256), 0, stream>>>(
          ucv + (size_t)dir*MROWS*DINNER, DINNER, xp_w + (size_t)i*GCOLS*DINNER,
          xdb + (size_t)dir*MROWS*GCOLS, GCOLS, GCOLS, DINNER, nullptr, nullptr);
      // dt = softplus(xdb[:,:24] @ dt_w^T + dt_b)  (N=768, K=24)
      gemm_k<1><<<dim3(12,64), dim3(256), 0, stream>>>(
          xdb + (size_t)dir*MROWS*GCOLS, GCOLS, dt_w + (size_t)i*DINNER*DTRANK,
          dtb + (size_t)dir*MROWS*DINNER, DINNER, DINNER, DTRANK,
          dt_b + (size_t)i*DINNER, nullptr);
    }

    zero_k<<<dim3((MROWS*DINNER)/256), dim3(256), 0, stream>>>(acc, MROWS*DINNER);
    scan_k<<<dim3(192), dim3(64), 0, stream>>>(
        dtb, ucv, xdb, A_log + (size_t)i*DINNER*NSTATE, Dp + (size_t)i*DINNER, acc);
    combine_k<<<dim3((MROWS*DINNER)/256), dim3(256), 0, stream>>>(acc, xz);

    // t1 = ymix @ mout_w^T  (N=384, K=768)
    gemm_k<0><<<dim3(6,64), dim3(256), 0, stream>>>(
        acc, DINNER, mout_w + (size_t)i*DMODEL*DINNER, t1, DMODEL, DMODEL, DINNER, nullptr, nullptr);
    ln384_k<<<dim3(1024), dim3(256), 0, stream>>>(t1, t2, mn_w + (size_t)i*DMODEL, mn_b + (size_t)i*DMODEL);
    // t3 = xcur + t2 @ bp_w^T + bp_b  (N=384, K=384)
    gemm_k<2><<<dim3(6,64), dim3(256), 0, stream>>>(
        t2, DMODEL, bp_w + (size_t)i*DMODEL*DMODEL, t3, DMODEL, DMODEL, DMODEL,
        bp_b + (size_t)i*DMODEL, xcur);
    ln384_k<<<dim3(1024), dim3(256), 0, stream>>>(t3, xcur, ln_w + (size_t)i*DMODEL, ln_b + (size_t)i*DMODEL);
  }

  // xe = x @ exp_w^T  (N=768, K=384)
  gemm_k<0><<<dim3(12,64), dim3(256), 0, stream>>>(
      xcur, DMODEL, exp_w, xe, 2*DMODEL, 2*DMODEL, DMODEL, nullptr, nullptr);
  // pixel-shuffle + LN(192) -> fp32 out
  peln_k<<<dim3(4096), dim3(256), 0, stream>>>(xe, pe_w, pe_b, (float*)d_out);
}

// Round 3
// 1567.092 us; speedup vs baseline: 1.5579x; 1.5579x over previous
//
#include <hip/hip_runtime.h>
#include <hip/hip_bf16.h>
#include <math.h>

#define MROWS 4096      // BATCH * L
#define DMODEL 384
#define DINNER 768
#define GCOLS 56        // DT_RANK + 2*D_STATE
#define DTRANK 24
#define NSTATE 16
#define NCHUNK 16
#define TCHUNK 64

__device__ __forceinline__ float silu_f(float x){ return x / (1.f + __expf(-x)); }

// seq index t -> token index, per direction
__device__ __forceinline__ int perm_tok(int dir, int t){
  if (dir == 0) return t;
  if (dir == 2) return 1023 - t;
  int tt = (dir == 1) ? t : (1023 - t);
  int i = tt >> 5, j = tt & 31;
  return ((31 - j) << 5) | i;   // token = (31-j)*32 + i
}

// ---------------- generic fp32 GEMM: C[M,N] = A[M,K] @ W[N,K]^T ----------------
// EPI 0: none; 1: softplus(x + bias); 2: x + bias + res
template<int EPI>
__launch_bounds__(256)
__global__ void gemm_k(const float* __restrict__ A, int lda,
                       const float* __restrict__ W,
                       float* __restrict__ C, int ldc,
                       int Ndim, int Kdim,
                       const float* __restrict__ bias,
                       const float* __restrict__ res)
{
  __shared__ float As[16][68];   // [k][m]
  __shared__ float Bs[16][68];   // [k][n]
  const int tid = threadIdx.x;
  const int m0 = blockIdx.y * 64;
  const int n0 = blockIdx.x * 64;
  const int tr = tid >> 4, tc = tid & 15;
  const int r  = tid >> 2, q  = tid & 3;
  float acc[4][4] = {};

  for (int k0 = 0; k0 < Kdim; k0 += 16) {
    { // A tile: 64 rows x 16 k
      const float* ap = A + (size_t)(m0 + r) * lda + (k0 + q*4);
      float v0=0.f,v1=0.f,v2=0.f,v3=0.f;
      int kc = Kdim - (k0 + q*4);
      if (kc >= 4) { float4 t4 = *(const float4*)ap; v0=t4.x; v1=t4.y; v2=t4.z; v3=t4.w; }
      else { if (kc>0) v0=ap[0]; if (kc>1) v1=ap[1]; if (kc>2) v2=ap[2]; }
      As[q*4+0][r]=v0; As[q*4+1][r]=v1; As[q*4+2][r]=v2; As[q*4+3][r]=v3;
    }
    { // W tile: 64 n-rows x 16 k
      int nr = n0 + r;
      float v0=0.f,v1=0.f,v2=0.f,v3=0.f;
      if (nr < Ndim) {
        const float* wp = W + (size_t)nr * Kdim + (k0 + q*4);
        int kc = Kdim - (k0 + q*4);
        if (kc >= 4) { float4 t4 = *(const float4*)wp; v0=t4.x; v1=t4.y; v2=t4.z; v3=t4.w; }
        else { if (kc>0) v0=wp[0]; if (kc>1) v1=wp[1]; if (kc>2) v2=wp[2]; }
      }
      Bs[q*4+0][r]=v0; Bs[q*4+1][r]=v1; Bs[q*4+2][r]=v2; Bs[q*4+3][r]=v3;
    }
    __syncthreads();
#pragma unroll
    for (int kk = 0; kk < 16; kk++) {
      float4 a4 = *(const float4*)&As[kk][tr*4];
      float4 b4 = *(const float4*)&Bs[kk][tc*4];
      float av[4] = {a4.x,a4.y,a4.z,a4.w};
      float bv[4] = {b4.x,b4.y,b4.z,b4.w};
#pragma unroll
      for (int i2=0;i2<4;i2++)
#pragma unroll
        for (int j2=0;j2<4;j2++)
          acc[i2][j2] = __builtin_fmaf(av[i2], bv[j2], acc[i2][j2]);
    }
    __syncthreads();
  }

#pragma unroll
  for (int i2=0;i2<4;i2++){
    int m = m0 + tr*4 + i2;
#pragma unroll
    for (int j2=0;j2<4;j2++){
      int n = n0 + tc*4 + j2;
      if (n < Ndim){
        float v = acc[i2][j2];
        if (EPI == 1) { v += bias[n]; v = (v > 20.f) ? v : log1pf(__expf(v)); }
        if (EPI == 2) { v += bias[n] + res[(size_t)m*ldc + n]; }
        C[(size_t)m*ldc + n] = v;
      }
    }
  }
}

// ---------------- misc ----------------
__global__ void zero_k(float* __restrict__ p, int n){
  int id = blockIdx.x*256 + threadIdx.x;
  if (id < n) p[id] = 0.f;
}

// depthwise causal conv (k=4) over permuted sequence + bias + silu
__launch_bounds__(256)
__global__ void conv_k(const float* __restrict__ xz, const float* __restrict__ cw,
                       const float* __restrict__ cb, float* __restrict__ ucv)
{
  int id = blockIdx.x*256 + threadIdx.x;          // ((dir*4+b)*1024+t)*768+d
  int d = id % DINNER;
  int t = (id / DINNER) & 1023;
  int btdir = id / (DINNER*1024);
  int b_ = btdir & 3, dir = btdir >> 2;
  float s = cb[d];
  const float* up = xz + (size_t)b_*1024*1536 + d;   // u0 = first 768 cols of xz
#pragma unroll
  for (int j=0;j<4;j++){
    int tm = t - 3 + j;
    if (tm >= 0) s += cw[d*4+j] * up[(size_t)perm_tok(dir,tm)*1536];
  }
  ucv[id] = silu_f(s);
}

// ============ chunked selective scan ============
// Pass A: per (dir,b,d,chunk): local scan from h=0 -> hL[n], decay product W[n]
__launch_bounds__(256)
__global__ void chunk_scan_k(const float* __restrict__ dtb, const float* __restrict__ ucv,
                             const float* __restrict__ xdb, const float* __restrict__ A_log,
                             float* __restrict__ Wb, float* __restrict__ hLb)
{
  int id = blockIdx.x*256 + threadIdx.x;    // ((dir*4+b)*16+c)*768+d
  int d = id % DINNER;
  int rem = id / DINNER;
  int c = rem & (NCHUNK-1);
  int bd = rem >> 4;
  int b = bd & 3, dir = bd >> 2;

  float A2[NSTATE];
#pragma unroll
  for (int n=0;n<NSTATE;n++)
    A2[n] = -__expf(A_log[d*NSTATE + n]) * 1.44269504f;

  const size_t seqbase = (size_t)(dir*4 + b) * 1024;
  const float* dtp = dtb + seqbase*DINNER + d;
  const float* up  = ucv + seqbase*DINNER + d;
  const float* bc  = xdb + seqbase*GCOLS;

  float h[NSTATE] = {};
  float Wp[NSTATE];
#pragma unroll
  for (int n=0;n<NSTATE;n++) Wp[n] = 1.f;

  int t0 = c * TCHUNK;
  for (int tt=0; tt<TCHUNK; tt++){
    int t = t0 + tt;
    float dt = dtp[(size_t)t*DINNER];
    float u  = up[(size_t)t*DINNER];
    float du = dt * u;
    const float* Bv = bc + t*GCOLS + DTRANK;
    float4 B0 = *(const float4*)(Bv+0), B1 = *(const float4*)(Bv+4);
    float4 B2 = *(const float4*)(Bv+8), B3 = *(const float4*)(Bv+12);
    float Bf[NSTATE] = {B0.x,B0.y,B0.z,B0.w, B1.x,B1.y,B1.z,B1.w,
                        B2.x,B2.y,B2.z,B2.w, B3.x,B3.y,B3.z,B3.w};
#pragma unroll
    for (int n=0;n<NSTATE;n++){
      float w = exp2f(dt * A2[n]);
      Wp[n] *= w;
      h[n] = h[n]*w + du * Bf[n];
    }
  }
  size_t ob = ((size_t)((dir*4+b)*NCHUNK + c) * NSTATE) * DINNER + d;
#pragma unroll
  for (int n=0;n<NSTATE;n++){
    Wb[ob + (size_t)n*DINNER]  = Wp[n];
    hLb[ob + (size_t)n*DINNER] = h[n];
  }
}

// Pass B: per (dir,b,d): serial combine over chunks; hLb becomes chunk-initial h0
__launch_bounds__(256)
__global__ void chunk_comb_k(const float* __restrict__ Wb, float* __restrict__ hLb)
{
  int id = blockIdx.x*256 + threadIdx.x;    // (dir*4+b)*768+d
  int d = id % DINNER;
  int bd = id / DINNER;
  float h[NSTATE] = {};
  for (int c=0; c<NCHUNK; c++){
    size_t ob = ((size_t)(bd*NCHUNK + c) * NSTATE) * DINNER + d;
#pragma unroll
    for (int n=0;n<NSTATE;n++){
      float Wc = Wb[ob + (size_t)n*DINNER];
      float hL = hLb[ob + (size_t)n*DINNER];
      float h0 = h[n];
      h[n] = Wc*h0 + hL;
      hLb[ob + (size_t)n*DINNER] = h0;
    }
  }
}

// Pass C: per (dir,b,d,chunk): replay from h0, emit y, scatter-add token-space
__launch_bounds__(256)
__global__ void chunk_emit_k(const float* __restrict__ dtb, const float* __restrict__ ucv,
                             const float* __restrict__ xdb, const float* __restrict__ A_log,
                             const float* __restrict__ Dp, const float* __restrict__ h0b,
                             float* __restrict__ acc)
{
  int id = blockIdx.x*256 + threadIdx.x;
  int d = id % DINNER;
  int rem = id / DINNER;
  int c = rem & (NCHUNK-1);
  int bd = rem >> 4;
  int b = bd & 3, dir = bd >> 2;

  float A2[NSTATE];
#pragma unroll
  for (int n=0;n<NSTATE;n++)
    A2[n] = -__expf(A_log[d*NSTATE + n]) * 1.44269504f;
  float Dd = Dp[d];

  const size_t seqbase = (size_t)(dir*4 + b) * 1024;
  const float* dtp = dtb + seqbase*DINNER + d;
  const float* up  = ucv + seqbase*DINNER + d;
  const float* bc  = xdb + seqbase*GCOLS;
  float* ab = acc + (size_t)b*1024*DINNER + d;

  float h[NSTATE];
  size_t ob = ((size_t)((dir*4+b)*NCHUNK + c) * NSTATE) * DINNER + d;
#pragma unroll
  for (int n=0;n<NSTATE;n++) h[n] = h0b[ob + (size_t)n*DINNER];

  int t0 = c * TCHUNK;
  for (int tt=0; tt<TCHUNK; tt++){
    int t = t0 + tt;
    float dt = dtp[(size_t)t*DINNER];
    float u  = up[(size_t)t*DINNER];
    float du = dt * u;
    const float* Bv = bc + t*GCOLS + DTRANK;
    float4 B0 = *(const float4*)(Bv+0), B1 = *(const float4*)(Bv+4);
    float4 B2 = *(const float4*)(Bv+8), B3 = *(const float4*)(Bv+12);
    const float* Cv = Bv + NSTATE;
    float4 C0 = *(const float4*)(Cv+0), C1 = *(const float4*)(Cv+4);
    float4 C2 = *(const float4*)(Cv+8), C3 = *(const float4*)(Cv+12);
    float Bf[NSTATE] = {B0.x,B0.y,B0.z,B0.w, B1.x,B1.y,B1.z,B1.w,
                        B2.x,B2.y,B2.z,B2.w, B3.x,B3.y,B3.z,B3.w};
    float Cf[NSTATE] = {C0.x,C0.y,C0.z,C0.w, C1.x,C1.y,C1.z,C1.w,
                        C2.x,C2.y,C2.z,C2.w, C3.x,C3.y,C3.z,C3.w};
    float y = 0.f;
#pragma unroll
    for (int n=0;n<NSTATE;n++){
      float w = exp2f(dt * A2[n]);
      h[n] = h[n]*w + du * Bf[n];
      y = __builtin_fmaf(h[n], Cf[n], y);
    }
    int tok = perm_tok(dir, t);
    atomicAdd(ab + (size_t)tok*DINNER, y + u*Dd);
  }
}

// acc *= silu(z)   (z = cols 768.. of xz)
__global__ void combine_k(float* __restrict__ acc, const float* __restrict__ xz)
{
  int id = blockIdx.x*256 + threadIdx.x;     // < MROWS*DINNER
  int row = id / DINNER;
  int d = id - row*DINNER;
  float z = xz[(size_t)row*1536 + DINNER + d];
  acc[id] *= silu_f(z);
}

// layernorm over 384, one wave per row
__launch_bounds__(256)
__global__ void ln384_k(const float* __restrict__ in, float* __restrict__ out,
                        const float* __restrict__ w, const float* __restrict__ b)
{
  int wv = threadIdx.x >> 6, lane = threadIdx.x & 63;
  size_t row = (size_t)blockIdx.x * 4 + wv;
  const float* ip = in + row * DMODEL;
  float v[6];
#pragma unroll
  for (int k=0;k<6;k++) v[k] = ip[lane + 64*k];
  float s = 0.f;
#pragma unroll
  for (int k=0;k<6;k++) s += v[k];
#pragma unroll
  for (int o=32;o>0;o>>=1) s += __shfl_xor(s, o);
  float mu = s * (1.f/DMODEL);
  float ss = 0.f;
#pragma unroll
  for (int k=0;k<6;k++){ float dd = v[k]-mu; ss += dd*dd; }
#pragma unroll
  for (int o=32;o>0;o>>=1) ss += __shfl_xor(ss, o);
  float inv = rsqrtf(ss*(1.f/DMODEL) + 1e-5f);
  float* op = out + row * DMODEL;
#pragma unroll
  for (int k=0;k<6;k++){ int c = lane + 64*k; op[c] = (v[k]-mu)*inv*w[c] + b[c]; }
}

// pixel-shuffle gather + layernorm over 192 + fp32 store
__launch_bounds__(256)
__global__ void peln_k(const float* __restrict__ xe, const float* __restrict__ w,
                       const float* __restrict__ b, float* __restrict__ out)
{
  int wv = threadIdx.x >> 6, lane = threadIdx.x & 63;
  int row = blockIdx.x * 4 + wv;          // 0..16383 = b*4096 + h2*64 + w2
  int bb = row >> 12;
  int r2 = row & 4095;
  int h2 = r2 >> 6, w2 = r2 & 63;
  int h = h2 >> 1, s1 = h2 & 1, w_ = w2 >> 1, s2 = w2 & 1;
  const float* ip = xe + ((size_t)(bb*1024 + h*32 + w_))*768 + (s1*2+s2)*192;
  float v[3];
#pragma unroll
  for (int k=0;k<3;k++) v[k] = ip[lane + 64*k];
  float s = v[0]+v[1]+v[2];
#pragma unroll
  for (int o=32;o>0;o>>=1) s += __shfl_xor(s, o);
  float mu = s * (1.f/192);
  float ss = 0.f;
#pragma unroll
  for (int k=0;k<3;k++){ float dd=v[k]-mu; ss+=dd*dd; }
#pragma unroll
  for (int o=32;o>0;o>>=1) ss += __shfl_xor(ss, o);
  float inv = rsqrtf(ss*(1.f/192) + 1e-5f);
  float* op = out + (size_t)row * 192;
#pragma unroll
  for (int k=0;k<3;k++){ int c = lane + 64*k; op[c] = (v[k]-mu)*inv*w[c] + b[c]; }
}

extern "C" void kernel_launch(void* const* d_in, const int* in_sizes, int n_in,
                              void* d_out, int out_size, void* d_ws, size_t ws_size,
                              hipStream_t stream)
{
  const float* x_in   = (const float*)d_in[0];
  const float* in_w   = (const float*)d_in[1];
  const float* conv_w = (const float*)d_in[2];
  const float* conv_b = (const float*)d_in[3];
  const float* xp_w   = (const float*)d_in[4];
  const float* dt_w   = (const float*)d_in[5];
  const float* dt_b   = (const float*)d_in[6];
  const float* A_log  = (const float*)d_in[7];
  const float* Dp     = (const float*)d_in[8];
  const float* mn_w   = (const float*)d_in[9];
  const float* mn_b   = (const float*)d_in[10];
  const float* mout_w = (const float*)d_in[11];
  const float* bp_w   = (const float*)d_in[12];
  const float* bp_b   = (const float*)d_in[13];
  const float* ln_w   = (const float*)d_in[14];
  const float* ln_b   = (const float*)d_in[15];
  const float* exp_w  = (const float*)d_in[16];
  const float* pe_w   = (const float*)d_in[17];
  const float* pe_b   = (const float*)d_in[18];

  float* ws = (float*)d_ws;
  float* xcur = ws;                              // 4096*384
  float* xz   = xcur + (size_t)MROWS*DMODEL;     // 4096*1536 (u0 | z)
  float* ucv  = xz   + (size_t)MROWS*1536;       // 4*4096*768
  float* xdb  = ucv  + (size_t)4*MROWS*DINNER;   // 4*4096*56
  float* dtb  = xdb  + (size_t)4*MROWS*GCOLS;    // 4*4096*768
  float* acc  = dtb  + (size_t)4*MROWS*DINNER;   // 4096*768
  float* t1   = acc  + (size_t)MROWS*DINNER;     // 4096*384
  float* t2   = t1   + (size_t)MROWS*DMODEL;     // 4096*384
  float* hLb  = t2   + (size_t)MROWS*DMODEL;     // 16*16*16*16*768 = 3.15M (NEW +12.6MB)
  float* Wb   = t1;                              // aliases t1+t2 (dead during scan; 3.146M exact)
  float* t3   = dtb;                             // reuse (free after scan)
  float* xe   = acc;                             // reuse (free after layers)

  hipMemcpyAsync(xcur, x_in, (size_t)MROWS*DMODEL*sizeof(float), hipMemcpyDeviceToDevice, stream);

  for (int i = 0; i < 2; i++) {
    // xz = x @ in_w^T   (M=4096, N=1536, K=384)
    gemm_k<0><<<dim3(24,64), dim3(256), 0, stream>>>(
        xcur, DMODEL, in_w + (size_t)i*1536*DMODEL, xz, 1536, 1536, DMODEL, nullptr, nullptr);

    // per-direction depthwise conv + silu
    conv_k<<<dim3((4*MROWS*DINNER)/256), dim3(256), 0, stream>>>(
        xz, conv_w + (size_t)i*DINNER*4, conv_b + (size_t)i*DINNER, ucv);

    for (int dir = 0; dir < 4; dir++) {
      // xdb = u @ xp_w^T  (N=56, K=768)
      gemm_k<0><<<dim3(1,64), dim3(256), 0, stream>>>(
          ucv + (size_t)dir*MROWS*DINNER, DINNER, xp_w + (size_t)i*GCOLS*DINNER,
          xdb + (size_t)dir*MROWS*GCOLS, GCOLS, GCOLS, DINNER, nullptr, nullptr);
      // dt = softplus(xdb[:,:24] @ dt_w^T + dt_b)  (N=768, K=24)
      gemm_k<1><<<dim3(12,64), dim3(256), 0, stream>>>(
          xdb + (size_t)dir*MROWS*GCOLS, GCOLS, dt_w + (size_t)i*DINNER*DTRANK,
          dtb + (size_t)dir*MROWS*DINNER, DINNER, DINNER, DTRANK,
          dt_b + (size_t)i*DINNER, nullptr);
    }

    zero_k<<<dim3((MROWS*DINNER)/256), dim3(256), 0, stream>>>(acc, MROWS*DINNER);
    // chunked scan: A, B, C
    chunk_scan_k<<<dim3(768), dim3(256), 0, stream>>>(
        dtb, ucv, xdb, A_log + (size_t)i*DINNER*NSTATE, Wb, hLb);
    chunk_comb_k<<<dim3(48), dim3(256), 0, stream>>>(Wb, hLb);
    chunk_emit_k<<<dim3(768), dim3(256), 0, stream>>>(
        dtb, ucv, xdb, A_log + (size_t)i*DINNER*NSTATE, Dp + (size_t)i*DINNER, hLb, acc);
    combine_k<<<dim3((MROWS*DINNER)/256), dim3(256), 0, stream>>>(acc, xz);

    // t1 = ymix @ mout_w^T  (N=384, K=768)
    gemm_k<0><<<dim3(6,64), dim3(256), 0, stream>>>(
        acc, DINNER, mout_w + (size_t)i*DMODEL*DINNER, t1, DMODEL, DMODEL, DINNER, nullptr, nullptr);
    ln384_k<<<dim3(1024), dim3(256), 0, stream>>>(t1, t2, mn_w + (size_t)i*DMODEL, mn_b + (size_t)i*DMODEL);
    // t3 = xcur + t2 @ bp_w^T + bp_b  (N=384, K=384)
    gemm_k<2><<<dim3(6,64), dim3(256), 0, stream>>>(
        t2, DMODEL, bp_w + (size_t)i*DMODEL*DMODEL, t3, DMODEL, DMODEL, DMODEL,
        bp_b + (size_t)i*DMODEL, xcur);
    ln384_k<<<dim3(1024), dim3(256), 0, stream>>>(t3, xcur, ln_w + (size_t)i*DMODEL, ln_b + (size_t)i*DMODEL);
  }

  // xe = x @ exp_w^T  (N=768, K=384)
  gemm_k<0><<<dim3(12,64), dim3(256), 0, stream>>>(
      xcur, DMODEL, exp_w, xe, 2*DMODEL, 2*DMODEL, DMODEL, nullptr, nullptr);
  // pixel-shuffle + LN(192) -> fp32 out
  peln_k<<<dim3(4096), dim3(256), 0, stream>>>(xe, pe_w, pe_b, (float*)d_out);
}

// Round 4
// 993.121 us; speedup vs baseline: 2.4583x; 1.5779x over previous
//
#include <hip/hip_runtime.h>
#include <hip/hip_bf16.h>
#include <math.h>

typedef __hip_bfloat16 bf16;

#define MROWS 4096      // BATCH * L
#define DMODEL 384
#define DINNER 768
#define GCOLS 56        // DT_RANK + 2*D_STATE
#define DTRANK 24
#define NSTATE 16
#define NCHUNK 16
#define TCHUNK 64

typedef __attribute__((ext_vector_type(8))) short bf16x8;
typedef __attribute__((ext_vector_type(4))) float f32x4;

__device__ __forceinline__ float silu_f(float x){ return x / (1.f + __expf(-x)); }
__device__ __forceinline__ short f2bs(float x){
  bf16 h = __float2bfloat16(x);
  return *(short*)&h;
}

// seq index t -> token index, per direction
__device__ __forceinline__ int perm_tok(int dir, int t){
  if (dir == 0) return t;
  if (dir == 2) return 1023 - t;
  int tt = (dir == 1) ? t : (1023 - t);
  int i = tt >> 5, j = tt & 31;
  return ((31 - j) << 5) | i;   // token = (31-j)*32 + i
}

// ---------------- bf16 MFMA GEMM: C[M,N] = A[M,K] @ W[N,K]^T (fp32 accum) ----
// EPI 0: none; 2: + bias[n] + res[m,n]
// block 256 = 4 waves; block tile 64(M) x 64(N); wave tile 64(M) x 16(N)
template<int EPI>
__launch_bounds__(256)
__global__ void gemm_mfma_k(const short* __restrict__ A, int lda,
                            const short* __restrict__ W, int ldw,
                            float* __restrict__ C, int ldc,
                            int Ndim, int Kdim,
                            const float* __restrict__ bias,
                            const float* __restrict__ res)
{
  const int wv = threadIdx.x >> 6, lane = threadIdx.x & 63;
  const int m0 = blockIdx.y * 64;
  const int n0 = blockIdx.x * 64 + wv * 16;
  const int lm = lane & 15;          // fragment row (A-m / B-n)
  const int kq = (lane >> 4) * 8;    // fragment k offset
  f32x4 acc0 = {0.f,0.f,0.f,0.f}, acc1 = acc0, acc2 = acc0, acc3 = acc0;
  const bool nok = (n0 + lm) < Ndim;
  const short* ap = A + (size_t)(m0 + lm) * lda + kq;
  const short* wp = W + (size_t)(nok ? (n0 + lm) : 0) * ldw + kq;
  const size_t ar16 = (size_t)16 * lda;
  const bf16x8 bz = {0,0,0,0,0,0,0,0};

  for (int k0 = 0; k0 < Kdim; k0 += 32) {
    bf16x8 b = bz;
    if (nok) b = *(const bf16x8*)(wp + k0);
    bf16x8 a0 = *(const bf16x8*)(ap + k0);
    bf16x8 a1 = *(const bf16x8*)(ap + ar16 + k0);
    bf16x8 a2 = *(const bf16x8*)(ap + 2*ar16 + k0);
    bf16x8 a3 = *(const bf16x8*)(ap + 3*ar16 + k0);
    acc0 = __builtin_amdgcn_mfma_f32_16x16x32_bf16(a0, b, acc0, 0, 0, 0);
    acc1 = __builtin_amdgcn_mfma_f32_16x16x32_bf16(a1, b, acc1, 0, 0, 0);
    acc2 = __builtin_amdgcn_mfma_f32_16x16x32_bf16(a2, b, acc2, 0, 0, 0);
    acc3 = __builtin_amdgcn_mfma_f32_16x16x32_bf16(a3, b, acc3, 0, 0, 0);
  }

  const int ncol = n0 + lm;                 // C/D: col = lane&15
  if (ncol < Ndim) {
    const int mr = m0 + (lane >> 4) * 4;    // C/D: row = quad*4 + reg
    f32x4 av[4] = {acc0, acc1, acc2, acc3};
#pragma unroll
    for (int mt = 0; mt < 4; mt++) {
#pragma unroll
      for (int reg = 0; reg < 4; reg++) {
        int m = mr + mt*16 + reg;
        float v = av[mt][reg];
        if (EPI == 2) v += bias[ncol] + res[(size_t)m*ldc + ncol];
        C[(size_t)m*ldc + ncol] = v;
      }
    }
  }
}

// ---------------- fp32 SIMT GEMM (kept for dt: K=24) ----------------
// EPI 1: softplus(x + bias)
template<int EPI>
__launch_bounds__(256)
__global__ void gemm_k(const float* __restrict__ A, int lda,
                       const float* __restrict__ W,
                       float* __restrict__ C, int ldc,
                       int Ndim, int Kdim,
                       const float* __restrict__ bias,
                       const float* __restrict__ res)
{
  __shared__ float As[16][68];
  __shared__ float Bs[16][68];
  const int tid = threadIdx.x;
  const int m0 = blockIdx.y * 64;
  const int n0 = blockIdx.x * 64;
  const int tr = tid >> 4, tc = tid & 15;
  const int r  = tid >> 2, q  = tid & 3;
  float acc[4][4] = {};

  for (int k0 = 0; k0 < Kdim; k0 += 16) {
    {
      const float* ap = A + (size_t)(m0 + r) * lda + (k0 + q*4);
      float v0=0.f,v1=0.f,v2=0.f,v3=0.f;
      int kc = Kdim - (k0 + q*4);
      if (kc >= 4) { float4 t4 = *(const float4*)ap; v0=t4.x; v1=t4.y; v2=t4.z; v3=t4.w; }
      else { if (kc>0) v0=ap[0]; if (kc>1) v1=ap[1]; if (kc>2) v2=ap[2]; }
      As[q*4+0][r]=v0; As[q*4+1][r]=v1; As[q*4+2][r]=v2; As[q*4+3][r]=v3;
    }
    {
      int nr = n0 + r;
      float v0=0.f,v1=0.f,v2=0.f,v3=0.f;
      if (nr < Ndim) {
        const float* wp = W + (size_t)nr * Kdim + (k0 + q*4);
        int kc = Kdim - (k0 + q*4);
        if (kc >= 4) { float4 t4 = *(const float4*)wp; v0=t4.x; v1=t4.y; v2=t4.z; v3=t4.w; }
        else { if (kc>0) v0=wp[0]; if (kc>1) v1=wp[1]; if (kc>2) v2=wp[2]; }
      }
      Bs[q*4+0][r]=v0; Bs[q*4+1][r]=v1; Bs[q*4+2][r]=v2; Bs[q*4+3][r]=v3;
    }
    __syncthreads();
#pragma unroll
    for (int kk = 0; kk < 16; kk++) {
      float4 a4 = *(const float4*)&As[kk][tr*4];
      float4 b4 = *(const float4*)&Bs[kk][tc*4];
      float av[4] = {a4.x,a4.y,a4.z,a4.w};
      float bv[4] = {b4.x,b4.y,b4.z,b4.w};
#pragma unroll
      for (int i2=0;i2<4;i2++)
#pragma unroll
        for (int j2=0;j2<4;j2++)
          acc[i2][j2] = __builtin_fmaf(av[i2], bv[j2], acc[i2][j2]);
    }
    __syncthreads();
  }

#pragma unroll
  for (int i2=0;i2<4;i2++){
    int m = m0 + tr*4 + i2;
#pragma unroll
    for (int j2=0;j2<4;j2++){
      int n = n0 + tc*4 + j2;
      if (n < Ndim){
        float v = acc[i2][j2];
        if (EPI == 1) { v += bias[n]; v = (v > 20.f) ? v : log1pf(__expf(v)); }
        C[(size_t)m*ldc + n] = v;
      }
    }
  }
}

// ---------------- conversions / misc ----------------
__global__ void f2b_k(const float* __restrict__ in, short* __restrict__ out, int n){
  int id = blockIdx.x*256 + threadIdx.x;
  if (id < n) out[id] = f2bs(in[id]);
}
__global__ void cvt_dual_k(const float* __restrict__ in, float* __restrict__ of,
                           short* __restrict__ ob, int n){
  int id = blockIdx.x*256 + threadIdx.x;
  if (id < n) { float v = in[id]; of[id] = v; ob[id] = f2bs(v); }
}
__global__ void zero_k(float* __restrict__ p, int n){
  int id = blockIdx.x*256 + threadIdx.x;
  if (id < n) p[id] = 0.f;
}

// depthwise causal conv (k=4) over permuted sequence + bias + silu; fp32 + bf16 out
__launch_bounds__(256)
__global__ void conv_k(const float* __restrict__ xz, const float* __restrict__ cw,
                       const float* __restrict__ cb, float* __restrict__ ucv,
                       short* __restrict__ ucv_b)
{
  int id = blockIdx.x*256 + threadIdx.x;          // ((dir*4+b)*1024+t)*768+d
  int d = id % DINNER;
  int t = (id / DINNER) & 1023;
  int btdir = id / (DINNER*1024);
  int b_ = btdir & 3, dir = btdir >> 2;
  float s = cb[d];
  const float* up = xz + (size_t)b_*1024*1536 + d;
#pragma unroll
  for (int j=0;j<4;j++){
    int tm = t - 3 + j;
    if (tm >= 0) s += cw[d*4+j] * up[(size_t)perm_tok(dir,tm)*1536];
  }
  float v = silu_f(s);
  ucv[id] = v;
  ucv_b[id] = f2bs(v);
}

// ============ chunked selective scan ============
__launch_bounds__(256)
__global__ void chunk_scan_k(const float* __restrict__ dtb, const float* __restrict__ ucv,
                             const float* __restrict__ xdb, const float* __restrict__ A_log,
                             float* __restrict__ Wb, float* __restrict__ hLb)
{
  int id = blockIdx.x*256 + threadIdx.x;    // ((dir*4+b)*16+c)*768+d
  int d = id % DINNER;
  int rem = id / DINNER;
  int c = rem & (NCHUNK-1);
  int bd = rem >> 4;

  float A2[NSTATE];
#pragma unroll
  for (int n=0;n<NSTATE;n++)
    A2[n] = -__expf(A_log[d*NSTATE + n]) * 1.44269504f;

  const size_t seqbase = (size_t)bd * 1024;
  const float* dtp = dtb + seqbase*DINNER + d;
  const float* up  = ucv + seqbase*DINNER + d;
  const float* bc  = xdb + seqbase*GCOLS;

  float h[NSTATE] = {};
  float Wp[NSTATE];
#pragma unroll
  for (int n=0;n<NSTATE;n++) Wp[n] = 1.f;

  int t0 = c * TCHUNK;
  for (int tt=0; tt<TCHUNK; tt++){
    int t = t0 + tt;
    float dt = dtp[(size_t)t*DINNER];
    float u  = up[(size_t)t*DINNER];
    float du = dt * u;
    const float* Bv = bc + t*GCOLS + DTRANK;
    float4 B0 = *(const float4*)(Bv+0), B1 = *(const float4*)(Bv+4);
    float4 B2 = *(const float4*)(Bv+8), B3 = *(const float4*)(Bv+12);
    float Bf[NSTATE] = {B0.x,B0.y,B0.z,B0.w, B1.x,B1.y,B1.z,B1.w,
                        B2.x,B2.y,B2.z,B2.w, B3.x,B3.y,B3.z,B3.w};
#pragma unroll
    for (int n=0;n<NSTATE;n++){
      float w = exp2f(dt * A2[n]);
      Wp[n] *= w;
      h[n] = h[n]*w + du * Bf[n];
    }
  }
  size_t ob = ((size_t)(bd*NCHUNK + c) * NSTATE) * DINNER + d;
#pragma unroll
  for (int n=0;n<NSTATE;n++){
    Wb[ob + (size_t)n*DINNER]  = Wp[n];
    hLb[ob + (size_t)n*DINNER] = h[n];
  }
}

__launch_bounds__(256)
__global__ void chunk_comb_k(const float* __restrict__ Wb, float* __restrict__ hLb)
{
  int id = blockIdx.x*256 + threadIdx.x;    // (dir*4+b)*768+d
  int d = id % DINNER;
  int bd = id / DINNER;
  float h[NSTATE] = {};
  for (int c=0; c<NCHUNK; c++){
    size_t ob = ((size_t)(bd*NCHUNK + c) * NSTATE) * DINNER + d;
#pragma unroll
    for (int n=0;n<NSTATE;n++){
      float Wc = Wb[ob + (size_t)n*DINNER];
      float hL = hLb[ob + (size_t)n*DINNER];
      float h0 = h[n];
      h[n] = Wc*h0 + hL;
      hLb[ob + (size_t)n*DINNER] = h0;
    }
  }
}

__launch_bounds__(256)
__global__ void chunk_emit_k(const float* __restrict__ dtb, const float* __restrict__ ucv,
                             const float* __restrict__ xdb, const float* __restrict__ A_log,
                             const float* __restrict__ Dp, const float* __restrict__ h0b,
                             float* __restrict__ acc)
{
  int id = blockIdx.x*256 + threadIdx.x;
  int d = id % DINNER;
  int rem = id / DINNER;
  int c = rem & (NCHUNK-1);
  int bd = rem >> 4;
  int b = bd & 3, dir = bd >> 2;

  float A2[NSTATE];
#pragma unroll
  for (int n=0;n<NSTATE;n++)
    A2[n] = -__expf(A_log[d*NSTATE + n]) * 1.44269504f;
  float Dd = Dp[d];

  const size_t seqbase = (size_t)bd * 1024;
  const float* dtp = dtb + seqbase*DINNER + d;
  const float* up  = ucv + seqbase*DINNER + d;
  const float* bc  = xdb + seqbase*GCOLS;
  float* ab = acc + (size_t)b*1024*DINNER + d;

  float h[NSTATE];
  size_t ob = ((size_t)(bd*NCHUNK + c) * NSTATE) * DINNER + d;
#pragma unroll
  for (int n=0;n<NSTATE;n++) h[n] = h0b[ob + (size_t)n*DINNER];

  int t0 = c * TCHUNK;
  for (int tt=0; tt<TCHUNK; tt++){
    int t = t0 + tt;
    float dt = dtp[(size_t)t*DINNER];
    float u  = up[(size_t)t*DINNER];
    float du = dt * u;
    const float* Bv = bc + t*GCOLS + DTRANK;
    float4 B0 = *(const float4*)(Bv+0), B1 = *(const float4*)(Bv+4);
    float4 B2 = *(const float4*)(Bv+8), B3 = *(const float4*)(Bv+12);
    const float* Cv = Bv + NSTATE;
    float4 C0 = *(const float4*)(Cv+0), C1 = *(const float4*)(Cv+4);
    float4 C2 = *(const float4*)(Cv+8), C3 = *(const float4*)(Cv+12);
    float Bf[NSTATE] = {B0.x,B0.y,B0.z,B0.w, B1.x,B1.y,B1.z,B1.w,
                        B2.x,B2.y,B2.z,B2.w, B3.x,B3.y,B3.z,B3.w};
    float Cf[NSTATE] = {C0.x,C0.y,C0.z,C0.w, C1.x,C1.y,C1.z,C1.w,
                        C2.x,C2.y,C2.z,C2.w, C3.x,C3.y,C3.z,C3.w};
    float y = 0.f;
#pragma unroll
    for (int n=0;n<NSTATE;n++){
      float w = exp2f(dt * A2[n]);
      h[n] = h[n]*w + du * Bf[n];
      y = __builtin_fmaf(h[n], Cf[n], y);
    }
    int tok = perm_tok(dir, t);
    atomicAdd(ab + (size_t)tok*DINNER, y + u*Dd);
  }
}

// acc *= silu(z); also emit bf16
__global__ void combine_k(float* __restrict__ acc, const float* __restrict__ xz,
                          short* __restrict__ acc_b)
{
  int id = blockIdx.x*256 + threadIdx.x;     // < MROWS*DINNER
  int row = id / DINNER;
  int d = id - row*DINNER;
  float z = xz[(size_t)row*1536 + DINNER + d];
  float v = acc[id] * silu_f(z);
  acc[id] = v;
  acc_b[id] = f2bs(v);
}

// layernorm over 384; fp32 out + bf16 out
__launch_bounds__(256)
__global__ void ln384_k(const float* __restrict__ in, float* __restrict__ out,
                        const float* __restrict__ w, const float* __restrict__ b,
                        short* __restrict__ bout)
{
  int wv = threadIdx.x >> 6, lane = threadIdx.x & 63;
  size_t row = (size_t)blockIdx.x * 4 + wv;
  const float* ip = in + row * DMODEL;
  float v[6];
#pragma unroll
  for (int k=0;k<6;k++) v[k] = ip[lane + 64*k];
  float s = 0.f;
#pragma unroll
  for (int k=0;k<6;k++) s += v[k];
#pragma unroll
  for (int o=32;o>0;o>>=1) s += __shfl_xor(s, o);
  float mu = s * (1.f/DMODEL);
  float ss = 0.f;
#pragma unroll
  for (int k=0;k<6;k++){ float dd = v[k]-mu; ss += dd*dd; }
#pragma unroll
  for (int o=32;o>0;o>>=1) ss += __shfl_xor(ss, o);
  float inv = rsqrtf(ss*(1.f/DMODEL) + 1e-5f);
  float* op = out + row * DMODEL;
  short* bp = bout + row * DMODEL;
#pragma unroll
  for (int k=0;k<6;k++){
    int c = lane + 64*k;
    float r = (v[k]-mu)*inv*w[c] + b[c];
    op[c] = r;
    bp[c] = f2bs(r);
  }
}

// pixel-shuffle gather + layernorm over 192 + fp32 store
__launch_bounds__(256)
__global__ void peln_k(const float* __restrict__ xe, const float* __restrict__ w,
                       const float* __restrict__ b, float* __restrict__ out)
{
  int wv = threadIdx.x >> 6, lane = threadIdx.x & 63;
  int row = blockIdx.x * 4 + wv;          // b*4096 + h2*64 + w2
  int bb = row >> 12;
  int r2 = row & 4095;
  int h2 = r2 >> 6, w2 = r2 & 63;
  int h = h2 >> 1, s1 = h2 & 1, w_ = w2 >> 1, s2 = w2 & 1;
  const float* ip = xe + ((size_t)(bb*1024 + h*32 + w_))*768 + (s1*2+s2)*192;
  float v[3];
#pragma unroll
  for (int k=0;k<3;k++) v[k] = ip[lane + 64*k];
  float s = v[0]+v[1]+v[2];
#pragma unroll
  for (int o=32;o>0;o>>=1) s += __shfl_xor(s, o);
  float mu = s * (1.f/192);
  float ss = 0.f;
#pragma unroll
  for (int k=0;k<3;k++){ float dd=v[k]-mu; ss+=dd*dd; }
#pragma unroll
  for (int o=32;o>0;o>>=1) ss += __shfl_xor(ss, o);
  float inv = rsqrtf(ss*(1.f/192) + 1e-5f);
  float* op = out + (size_t)row * 192;
#pragma unroll
  for (int k=0;k<3;k++){ int c = lane + 64*k; op[c] = (v[k]-mu)*inv*w[c] + b[c]; }
}

extern "C" void kernel_launch(void* const* d_in, const int* in_sizes, int n_in,
                              void* d_out, int out_size, void* d_ws, size_t ws_size,
                              hipStream_t stream)
{
  const float* x_in   = (const float*)d_in[0];
  const float* in_w   = (const float*)d_in[1];
  const float* conv_w = (const float*)d_in[2];
  const float* conv_b = (const float*)d_in[3];
  const float* xp_w   = (const float*)d_in[4];
  const float* dt_w   = (const float*)d_in[5];
  const float* dt_b   = (const float*)d_in[6];
  const float* A_log  = (const float*)d_in[7];
  const float* Dp     = (const float*)d_in[8];
  const float* mn_w   = (const float*)d_in[9];
  const float* mn_b   = (const float*)d_in[10];
  const float* mout_w = (const float*)d_in[11];
  const float* bp_w   = (const float*)d_in[12];
  const float* bp_b   = (const float*)d_in[13];
  const float* ln_w   = (const float*)d_in[14];
  const float* ln_b   = (const float*)d_in[15];
  const float* exp_w  = (const float*)d_in[16];
  const float* pe_w   = (const float*)d_in[17];
  const float* pe_b   = (const float*)d_in[18];

  float* ws = (float*)d_ws;
  float* xcur = ws;                              // 1.57M
  float* xz   = xcur + (size_t)MROWS*DMODEL;     // 6.29M (u0 | z)
  float* ucv  = xz   + (size_t)MROWS*1536;       // 12.58M
  float* xdb  = ucv  + (size_t)4*MROWS*DINNER;   // 0.92M
  float* dtb  = xdb  + (size_t)4*MROWS*GCOLS;    // 12.58M
  float* acc  = dtb  + (size_t)4*MROWS*DINNER;   // 3.15M
  float* t1   = acc  + (size_t)MROWS*DINNER;     // 1.57M
  float* t2   = t1   + (size_t)MROWS*DMODEL;     // 1.57M
  float* hLb  = t2   + (size_t)MROWS*DMODEL;     // 3.15M
  // bf16 buffers (short*), fresh:
  short* xcur_b = (short*)(hLb + (size_t)4*MROWS*NSTATE*NCHUNK/16*DINNER/DINNER*0 + (size_t)16*NCHUNK*NSTATE*DINNER); // = hLb + 3.15M floats
  // compute explicitly:
  xcur_b = (short*)(hLb + (size_t)(4*4)*NCHUNK*NSTATE*DINNER);   // hLb size = 16*16*16*768 = 3,145,728 floats
  short* in_w_b   = xcur_b + (size_t)MROWS*DMODEL;          // 1,179,648 elems
  short* xp_w_b   = in_w_b + (size_t)2*1536*DMODEL;
  short* mout_w_b = xp_w_b + (size_t)2*GCOLS*DINNER;        // 589,824
  short* bp_w_b   = mout_w_b + (size_t)2*DMODEL*DINNER;     // 294,912
  short* exp_w_b  = bp_w_b + (size_t)2*DMODEL*DMODEL;       // 294,912
  // aliases:
  float* Wb    = t1;                          // 3.15M (t1+t2), dead during scan
  short* ucv_b = (short*)acc;                 // 12.58M bf16 = 6.29M floats (acc+t1+t2); dead after xdb GEMM
  float* t3    = dtb;                         // [4096][384] after scan
  short* t2b   = (short*)(dtb + (size_t)2*1024*1024);   // 1.57M elems, after scan
  short* acc_b = (short*)(dtb + (size_t)3*1024*1024 + 262144);  // 3.15M elems, after scan
  float* xe    = acc;                         // reuse after layers

  // weight conversions (once per launch)
  f2b_k<<<dim3((2*1536*DMODEL+255)/256), dim3(256), 0, stream>>>(in_w,   in_w_b,   2*1536*DMODEL);
  f2b_k<<<dim3((2*GCOLS*DINNER+255)/256), dim3(256), 0, stream>>>(xp_w,  xp_w_b,   2*GCOLS*DINNER);
  f2b_k<<<dim3((2*DMODEL*DINNER+255)/256), dim3(256), 0, stream>>>(mout_w, mout_w_b, 2*DMODEL*DINNER);
  f2b_k<<<dim3((2*DMODEL*DMODEL+255)/256), dim3(256), 0, stream>>>(bp_w,  bp_w_b,   2*DMODEL*DMODEL);
  f2b_k<<<dim3((2*DMODEL*DMODEL+255)/256), dim3(256), 0, stream>>>(exp_w, exp_w_b,  2*DMODEL*DMODEL);
  cvt_dual_k<<<dim3((MROWS*DMODEL)/256), dim3(256), 0, stream>>>(x_in, xcur, xcur_b, MROWS*DMODEL);

  for (int i = 0; i < 2; i++) {
    // xz = x @ in_w^T   (M=4096, N=1536, K=384)  [MFMA]
    gemm_mfma_k<0><<<dim3(24,64), dim3(256), 0, stream>>>(
        xcur_b, DMODEL, in_w_b + (size_t)i*1536*DMODEL, DMODEL,
        xz, 1536, 1536, DMODEL, nullptr, nullptr);

    // depthwise conv + silu (fp32 + bf16)
    conv_k<<<dim3((4*MROWS*DINNER)/256), dim3(256), 0, stream>>>(
        xz, conv_w + (size_t)i*DINNER*4, conv_b + (size_t)i*DINNER, ucv, ucv_b);

    // xdb = u @ xp_w^T  (M=16384, N=56, K=768)  [MFMA, merged dirs]
    gemm_mfma_k<0><<<dim3(1,256), dim3(256), 0, stream>>>(
        ucv_b, DINNER, xp_w_b + (size_t)i*GCOLS*DINNER, DINNER,
        xdb, GCOLS, GCOLS, DINNER, nullptr, nullptr);

    // dt = softplus(xdb[:,:24] @ dt_w^T + dt_b)  (M=16384, N=768, K=24)  [SIMT, merged]
    gemm_k<1><<<dim3(12,256), dim3(256), 0, stream>>>(
        xdb, GCOLS, dt_w + (size_t)i*DINNER*DTRANK,
        dtb, DINNER, DINNER, DTRANK, dt_b + (size_t)i*DINNER, nullptr);

    zero_k<<<dim3((MROWS*DINNER)/256), dim3(256), 0, stream>>>(acc, MROWS*DINNER);
    chunk_scan_k<<<dim3(768), dim3(256), 0, stream>>>(
        dtb, ucv, xdb, A_log + (size_t)i*DINNER*NSTATE, Wb, hLb);
    chunk_comb_k<<<dim3(48), dim3(256), 0, stream>>>(Wb, hLb);
    chunk_emit_k<<<dim3(768), dim3(256), 0, stream>>>(
        dtb, ucv, xdb, A_log + (size_t)i*DINNER*NSTATE, Dp + (size_t)i*DINNER, hLb, acc);
    combine_k<<<dim3((MROWS*DINNER)/256), dim3(256), 0, stream>>>(acc, xz, acc_b);

    // t1 = ymix @ mout_w^T  (N=384, K=768)  [MFMA]
    gemm_mfma_k<0><<<dim3(6,64), dim3(256), 0, stream>>>(
        acc_b, DINNER, mout_w_b + (size_t)i*DMODEL*DINNER, DINNER,
        t1, DMODEL, DMODEL, DINNER, nullptr, nullptr);
    ln384_k<<<dim3(1024), dim3(256), 0, stream>>>(t1, t2, mn_w + (size_t)i*DMODEL, mn_b + (size_t)i*DMODEL, t2b);
    // t3 = xcur + t2 @ bp_w^T + bp_b  (N=384, K=384)  [MFMA + bias + res]
    gemm_mfma_k<2><<<dim3(6,64), dim3(256), 0, stream>>>(
        t2b, DMODEL, bp_w_b + (size_t)i*DMODEL*DMODEL, DMODEL,
        t3, DMODEL, DMODEL, DMODEL, bp_b + (size_t)i*DMODEL, xcur);
    ln384_k<<<dim3(1024), dim3(256), 0, stream>>>(t3, xcur, ln_w + (size_t)i*DMODEL, ln_b + (size_t)i*DMODEL, xcur_b);
  }

  // xe = x @ exp_w^T  (M=4096, N=768, K=384)  [MFMA]
  gemm_mfma_k<0><<<dim3(12,64), dim3(256), 0, stream>>>(
      xcur_b, DMODEL, exp_w_b, DMODEL, xe, 2*DMODEL, 2*DMODEL, DMODEL, nullptr, nullptr);
  // pixel-shuffle + LN(192) -> fp32 out
  peln_k<<<dim3(4096), dim3(256), 0, stream>>>(xe, pe_w, pe_b, (float*)d_out);
}

// Round 5
// 972.894 us; speedup vs baseline: 2.5094x; 1.0208x over previous
//
#include <hip/hip_runtime.h>
#include <hip/hip_bf16.h>
#include <math.h>

typedef __hip_bfloat16 bf16;

#define MROWS 4096      // BATCH * L
#define DMODEL 384
#define DINNER 768
#define GCOLS 56        // DT_RANK + 2*D_STATE
#define DTRANK 24
#define NSTATE 16
#define NCHUNK 16
#define TCHUNK 64

typedef __attribute__((ext_vector_type(8))) short bf16x8;
typedef __attribute__((ext_vector_type(4))) float f32x4;

__device__ __forceinline__ float silu_f(float x){ return x / (1.f + __expf(-x)); }
__device__ __forceinline__ short f2bs(float x){
  bf16 h = __float2bfloat16(x);
  return *(short*)&h;
}

// seq index t -> token index, per direction
__device__ __forceinline__ int perm_tok(int dir, int t){
  if (dir == 0) return t;
  if (dir == 2) return 1023 - t;
  int tt = (dir == 1) ? t : (1023 - t);
  int i = tt >> 5, j = tt & 31;
  return ((31 - j) << 5) | i;   // token = (31-j)*32 + i
}

// ---------------- bf16 MFMA GEMM: C[M,N] = A[M,K] @ W[N,K]^T (fp32 accum) ----
// EPI 0: none; 2: + bias[n] + res[m,n]
template<int EPI>
__launch_bounds__(256)
__global__ void gemm_mfma_k(const short* __restrict__ A, int lda,
                            const short* __restrict__ W, int ldw,
                            float* __restrict__ C, int ldc,
                            int Ndim, int Kdim,
                            const float* __restrict__ bias,
                            const float* __restrict__ res)
{
  const int wv = threadIdx.x >> 6, lane = threadIdx.x & 63;
  const int m0 = blockIdx.y * 64;
  const int n0 = blockIdx.x * 64 + wv * 16;
  const int lm = lane & 15;          // fragment row (A-m / B-n)
  const int kq = (lane >> 4) * 8;    // fragment k offset
  f32x4 acc0 = {0.f,0.f,0.f,0.f}, acc1 = acc0, acc2 = acc0, acc3 = acc0;
  const bool nok = (n0 + lm) < Ndim;
  const short* ap = A + (size_t)(m0 + lm) * lda + kq;
  const short* wp = W + (size_t)(nok ? (n0 + lm) : 0) * ldw + kq;
  const size_t ar16 = (size_t)16 * lda;
  const bf16x8 bz = {0,0,0,0,0,0,0,0};

  for (int k0 = 0; k0 < Kdim; k0 += 32) {
    bf16x8 b = bz;
    if (nok) b = *(const bf16x8*)(wp + k0);
    bf16x8 a0 = *(const bf16x8*)(ap + k0);
    bf16x8 a1 = *(const bf16x8*)(ap + ar16 + k0);
    bf16x8 a2 = *(const bf16x8*)(ap + 2*ar16 + k0);
    bf16x8 a3 = *(const bf16x8*)(ap + 3*ar16 + k0);
    acc0 = __builtin_amdgcn_mfma_f32_16x16x32_bf16(a0, b, acc0, 0, 0, 0);
    acc1 = __builtin_amdgcn_mfma_f32_16x16x32_bf16(a1, b, acc1, 0, 0, 0);
    acc2 = __builtin_amdgcn_mfma_f32_16x16x32_bf16(a2, b, acc2, 0, 0, 0);
    acc3 = __builtin_amdgcn_mfma_f32_16x16x32_bf16(a3, b, acc3, 0, 0, 0);
  }

  const int ncol = n0 + lm;                 // C/D: col = lane&15
  if (ncol < Ndim) {
    const int mr = m0 + (lane >> 4) * 4;    // C/D: row = quad*4 + reg
    f32x4 av[4] = {acc0, acc1, acc2, acc3};
#pragma unroll
    for (int mt = 0; mt < 4; mt++) {
#pragma unroll
      for (int reg = 0; reg < 4; reg++) {
        int m = mr + mt*16 + reg;
        float v = av[mt][reg];
        if (EPI == 2) v += bias[ncol] + res[(size_t)m*ldc + ncol];
        C[(size_t)m*ldc + ncol] = v;
      }
    }
  }
}

// ---------------- fp32 SIMT GEMM (kept for dt: K=24) ----------------
template<int EPI>
__launch_bounds__(256)
__global__ void gemm_k(const float* __restrict__ A, int lda,
                       const float* __restrict__ W,
                       float* __restrict__ C, int ldc,
                       int Ndim, int Kdim,
                       const float* __restrict__ bias,
                       const float* __restrict__ res)
{
  __shared__ float As[16][68];
  __shared__ float Bs[16][68];
  const int tid = threadIdx.x;
  const int m0 = blockIdx.y * 64;
  const int n0 = blockIdx.x * 64;
  const int tr = tid >> 4, tc = tid & 15;
  const int r  = tid >> 2, q  = tid & 3;
  float acc[4][4] = {};

  for (int k0 = 0; k0 < Kdim; k0 += 16) {
    {
      const float* ap = A + (size_t)(m0 + r) * lda + (k0 + q*4);
      float v0=0.f,v1=0.f,v2=0.f,v3=0.f;
      int kc = Kdim - (k0 + q*4);
      if (kc >= 4) { float4 t4 = *(const float4*)ap; v0=t4.x; v1=t4.y; v2=t4.z; v3=t4.w; }
      else { if (kc>0) v0=ap[0]; if (kc>1) v1=ap[1]; if (kc>2) v2=ap[2]; }
      As[q*4+0][r]=v0; As[q*4+1][r]=v1; As[q*4+2][r]=v2; As[q*4+3][r]=v3;
    }
    {
      int nr = n0 + r;
      float v0=0.f,v1=0.f,v2=0.f,v3=0.f;
      if (nr < Ndim) {
        const float* wp = W + (size_t)nr * Kdim + (k0 + q*4);
        int kc = Kdim - (k0 + q*4);
        if (kc >= 4) { float4 t4 = *(const float4*)wp; v0=t4.x; v1=t4.y; v2=t4.z; v3=t4.w; }
        else { if (kc>0) v0=wp[0]; if (kc>1) v1=wp[1]; if (kc>2) v2=wp[2]; }
      }
      Bs[q*4+0][r]=v0; Bs[q*4+1][r]=v1; Bs[q*4+2][r]=v2; Bs[q*4+3][r]=v3;
    }
    __syncthreads();
#pragma unroll
    for (int kk = 0; kk < 16; kk++) {
      float4 a4 = *(const float4*)&As[kk][tr*4];
      float4 b4 = *(const float4*)&Bs[kk][tc*4];
      float av[4] = {a4.x,a4.y,a4.z,a4.w};
      float bv[4] = {b4.x,b4.y,b4.z,b4.w};
#pragma unroll
      for (int i2=0;i2<4;i2++)
#pragma unroll
        for (int j2=0;j2<4;j2++)
          acc[i2][j2] = __builtin_fmaf(av[i2], bv[j2], acc[i2][j2]);
    }
    __syncthreads();
  }

#pragma unroll
  for (int i2=0;i2<4;i2++){
    int m = m0 + tr*4 + i2;
#pragma unroll
    for (int j2=0;j2<4;j2++){
      int n = n0 + tc*4 + j2;
      if (n < Ndim){
        float v = acc[i2][j2];
        if (EPI == 1) { v += bias[n]; v = (v > 20.f) ? v : log1pf(__expf(v)); }
        C[(size_t)m*ldc + n] = v;
      }
    }
  }
}

// ---------------- conversions / misc ----------------
// batched bf16 conversion of 5 weight tensors into contiguous dst
__global__ void f2b5_k(const float* __restrict__ a0, const float* __restrict__ a1,
                       const float* __restrict__ a2, const float* __restrict__ a3,
                       const float* __restrict__ a4, short* __restrict__ o,
                       int s0, int s1, int s2, int s3, int s4)
{
  int id = blockIdx.x*256 + threadIdx.x;
  int e0 = s0, e1 = e0+s1, e2 = e1+s2, e3 = e2+s3, e4 = e3+s4;
  if (id >= e4) return;
  float v;
  if      (id < e0) v = a0[id];
  else if (id < e1) v = a1[id-e0];
  else if (id < e2) v = a2[id-e1];
  else if (id < e3) v = a3[id-e2];
  else              v = a4[id-e3];
  o[id] = f2bs(v);
}
__global__ void cvt_dual_k(const float* __restrict__ in, float* __restrict__ of,
                           short* __restrict__ ob, int n){
  int id = blockIdx.x*256 + threadIdx.x;
  if (id < n) { float v = in[id]; of[id] = v; ob[id] = f2bs(v); }
}
__global__ void zero_k(float* __restrict__ p, int n){
  int id = blockIdx.x*256 + threadIdx.x;
  if (id < n) p[id] = 0.f;
}

// depthwise causal conv (k=4) over permuted sequence + bias + silu; fp32 + bf16 out
__launch_bounds__(256)
__global__ void conv_k(const float* __restrict__ xz, const float* __restrict__ cw,
                       const float* __restrict__ cb, float* __restrict__ ucv,
                       short* __restrict__ ucv_b)
{
  int id = blockIdx.x*256 + threadIdx.x;          // ((dir*4+b)*1024+t)*768+d
  int d = id % DINNER;
  int t = (id / DINNER) & 1023;
  int btdir = id / (DINNER*1024);
  int b_ = btdir & 3, dir = btdir >> 2;
  float s = cb[d];
  const float* up = xz + (size_t)b_*1024*1536 + d;
#pragma unroll
  for (int j=0;j<4;j++){
    int tm = t - 3 + j;
    if (tm >= 0) s += cw[d*4+j] * up[(size_t)perm_tok(dir,tm)*1536];
  }
  float v = silu_f(s);
  ucv[id] = v;
  ucv_b[id] = f2bs(v);
}

// ============ chunked selective scan ============
// grid (3, NCHUNK, 16): d = bx*256+tid (uniform B/C pointers -> scalar loads)
__launch_bounds__(256)
__global__ void chunk_scan_k(const float* __restrict__ dtb, const float* __restrict__ ucv,
                             const float* __restrict__ xdb, const float* __restrict__ A_log,
                             float* __restrict__ Wb, float* __restrict__ hLb)
{
  const int d  = blockIdx.x * 256 + threadIdx.x;   // 0..767
  const int c  = blockIdx.y;                       // chunk
  const int bd = blockIdx.z;                       // dir*4+b

  float A2[NSTATE];
#pragma unroll
  for (int n=0;n<NSTATE;n++)
    A2[n] = -__expf(A_log[d*NSTATE + n]) * 1.44269504f;

  const size_t rowbase = (size_t)bd*1024 + (size_t)c*TCHUNK;
  const float* dtp = dtb + rowbase*DINNER + d;
  const float* up  = ucv + rowbase*DINNER + d;
  const float* bc  = xdb + rowbase*GCOLS + DTRANK;   // block-uniform

  float h[NSTATE] = {};
  float Wp[NSTATE];
#pragma unroll
  for (int n=0;n<NSTATE;n++) Wp[n] = 1.f;

  for (int tt=0; tt<TCHUNK; tt++){
    float dt = dtp[(size_t)tt*DINNER];
    float u  = up[(size_t)tt*DINNER];
    float du = dt * u;
    const float* Bv = bc + tt*GCOLS;                 // uniform -> s_load
    float4 B0 = *(const float4*)(Bv+0), B1 = *(const float4*)(Bv+4);
    float4 B2 = *(const float4*)(Bv+8), B3 = *(const float4*)(Bv+12);
    float Bf[NSTATE] = {B0.x,B0.y,B0.z,B0.w, B1.x,B1.y,B1.z,B1.w,
                        B2.x,B2.y,B2.z,B2.w, B3.x,B3.y,B3.z,B3.w};
#pragma unroll
    for (int n=0;n<NSTATE;n++){
      float w = exp2f(dt * A2[n]);
      Wp[n] *= w;
      h[n] = h[n]*w + du * Bf[n];
    }
  }
  size_t ob = ((size_t)(bd*NCHUNK + c) * NSTATE) * DINNER + d;
#pragma unroll
  for (int n=0;n<NSTATE;n++){
    Wb[ob + (size_t)n*DINNER]  = Wp[n];
    hLb[ob + (size_t)n*DINNER] = h[n];
  }
}

__launch_bounds__(256)
__global__ void chunk_comb_k(const float* __restrict__ Wb, float* __restrict__ hLb)
{
  int id = blockIdx.x*256 + threadIdx.x;    // (dir*4+b)*768+d
  int d = id % DINNER;
  int bd = id / DINNER;
  float h[NSTATE] = {};
  for (int c=0; c<NCHUNK; c++){
    size_t ob = ((size_t)(bd*NCHUNK + c) * NSTATE) * DINNER + d;
#pragma unroll
    for (int n=0;n<NSTATE;n++){
      float Wc = Wb[ob + (size_t)n*DINNER];
      float hL = hLb[ob + (size_t)n*DINNER];
      float h0 = h[n];
      h[n] = Wc*h0 + hL;
      hLb[ob + (size_t)n*DINNER] = h0;
    }
  }
}

__launch_bounds__(256)
__global__ void chunk_emit_k(const float* __restrict__ dtb, const float* __restrict__ ucv,
                             const float* __restrict__ xdb, const float* __restrict__ A_log,
                             const float* __restrict__ Dp, const float* __restrict__ h0b,
                             float* __restrict__ acc)
{
  const int d  = blockIdx.x * 256 + threadIdx.x;
  const int c  = blockIdx.y;
  const int bd = blockIdx.z;
  const int b  = bd & 3, dir = bd >> 2;

  float A2[NSTATE];
#pragma unroll
  for (int n=0;n<NSTATE;n++)
    A2[n] = -__expf(A_log[d*NSTATE + n]) * 1.44269504f;
  float Dd = Dp[d];

  const size_t rowbase = (size_t)bd*1024 + (size_t)c*TCHUNK;
  const float* dtp = dtb + rowbase*DINNER + d;
  const float* up  = ucv + rowbase*DINNER + d;
  const float* bc  = xdb + rowbase*GCOLS + DTRANK;   // block-uniform
  float* ab = acc + (size_t)b*1024*DINNER + d;

  float h[NSTATE];
  size_t ob = ((size_t)(bd*NCHUNK + c) * NSTATE) * DINNER + d;
#pragma unroll
  for (int n=0;n<NSTATE;n++) h[n] = h0b[ob + (size_t)n*DINNER];

  const int t0 = c * TCHUNK;
  for (int tt=0; tt<TCHUNK; tt++){
    float dt = dtp[(size_t)tt*DINNER];
    float u  = up[(size_t)tt*DINNER];
    float du = dt * u;
    const float* Bv = bc + tt*GCOLS;                 // uniform -> s_load
    float4 B0 = *(const float4*)(Bv+0), B1 = *(const float4*)(Bv+4);
    float4 B2 = *(const float4*)(Bv+8), B3 = *(const float4*)(Bv+12);
    float4 C0 = *(const float4*)(Bv+16), C1 = *(const float4*)(Bv+20);
    float4 C2 = *(const float4*)(Bv+24), C3 = *(const float4*)(Bv+28);
    float Bf[NSTATE] = {B0.x,B0.y,B0.z,B0.w, B1.x,B1.y,B1.z,B1.w,
                        B2.x,B2.y,B2.z,B2.w, B3.x,B3.y,B3.z,B3.w};
    float Cf[NSTATE] = {C0.x,C0.y,C0.z,C0.w, C1.x,C1.y,C1.z,C1.w,
                        C2.x,C2.y,C2.z,C2.w, C3.x,C3.y,C3.z,C3.w};
    float y = 0.f;
#pragma unroll
    for (int n=0;n<NSTATE;n++){
      float w = exp2f(dt * A2[n]);
      h[n] = h[n]*w + du * Bf[n];
      y = __builtin_fmaf(h[n], Cf[n], y);
    }
    int tok = perm_tok(dir, t0 + tt);
    atomicAdd(ab + (size_t)tok*DINNER, y + u*Dd);
  }
}

// acc *= silu(z); also emit bf16
__global__ void combine_k(float* __restrict__ acc, const float* __restrict__ xz,
                          short* __restrict__ acc_b)
{
  int id = blockIdx.x*256 + threadIdx.x;     // < MROWS*DINNER
  int row = id / DINNER;
  int d = id - row*DINNER;
  float z = xz[(size_t)row*1536 + DINNER + d];
  float v = acc[id] * silu_f(z);
  acc[id] = v;
  acc_b[id] = f2bs(v);
}

// layernorm over 384; fp32 out + bf16 out
__launch_bounds__(256)
__global__ void ln384_k(const float* __restrict__ in, float* __restrict__ out,
                        const float* __restrict__ w, const float* __restrict__ b,
                        short* __restrict__ bout)
{
  int wv = threadIdx.x >> 6, lane = threadIdx.x & 63;
  size_t row = (size_t)blockIdx.x * 4 + wv;
  const float* ip = in + row * DMODEL;
  float v[6];
#pragma unroll
  for (int k=0;k<6;k++) v[k] = ip[lane + 64*k];
  float s = 0.f;
#pragma unroll
  for (int k=0;k<6;k++) s += v[k];
#pragma unroll
  for (int o=32;o>0;o>>=1) s += __shfl_xor(s, o);
  float mu = s * (1.f/DMODEL);
  float ss = 0.f;
#pragma unroll
  for (int k=0;k<6;k++){ float dd = v[k]-mu; ss += dd*dd; }
#pragma unroll
  for (int o=32;o>0;o>>=1) ss += __shfl_xor(ss, o);
  float inv = rsqrtf(ss*(1.f/DMODEL) + 1e-5f);
  float* op = out + row * DMODEL;
  short* bp = bout + row * DMODEL;
#pragma unroll
  for (int k=0;k<6;k++){
    int c = lane + 64*k;
    float r = (v[k]-mu)*inv*w[c] + b[c];
    op[c] = r;
    bp[c] = f2bs(r);
  }
}

// pixel-shuffle gather + layernorm over 192 + fp32 store
__launch_bounds__(256)
__global__ void peln_k(const float* __restrict__ xe, const float* __restrict__ w,
                       const float* __restrict__ b, float* __restrict__ out)
{
  int wv = threadIdx.x >> 6, lane = threadIdx.x & 63;
  int row = blockIdx.x * 4 + wv;          // b*4096 + h2*64 + w2
  int bb = row >> 12;
  int r2 = row & 4095;
  int h2 = r2 >> 6, w2 = r2 & 63;
  int h = h2 >> 1, s1 = h2 & 1, w_ = w2 >> 1, s2 = w2 & 1;
  const float* ip = xe + ((size_t)(bb*1024 + h*32 + w_))*768 + (s1*2+s2)*192;
  float v[3];
#pragma unroll
  for (int k=0;k<3;k++) v[k] = ip[lane + 64*k];
  float s = v[0]+v[1]+v[2];
#pragma unroll
  for (int o=32;o>0;o>>=1) s += __shfl_xor(s, o);
  float mu = s * (1.f/192);
  float ss = 0.f;
#pragma unroll
  for (int k=0;k<3;k++){ float dd=v[k]-mu; ss+=dd*dd; }
#pragma unroll
  for (int o=32;o>0;o>>=1) ss += __shfl_xor(ss, o);
  float inv = rsqrtf(ss*(1.f/192) + 1e-5f);
  float* op = out + (size_t)row * 192;
#pragma unroll
  for (int k=0;k<3;k++){ int c = lane + 64*k; op[c] = (v[k]-mu)*inv*w[c] + b[c]; }
}

extern "C" void kernel_launch(void* const* d_in, const int* in_sizes, int n_in,
                              void* d_out, int out_size, void* d_ws, size_t ws_size,
                              hipStream_t stream)
{
  const float* x_in   = (const float*)d_in[0];
  const float* in_w   = (const float*)d_in[1];
  const float* conv_w = (const float*)d_in[2];
  const float* conv_b = (const float*)d_in[3];
  const float* xp_w   = (const float*)d_in[4];
  const float* dt_w   = (const float*)d_in[5];
  const float* dt_b   = (const float*)d_in[6];
  const float* A_log  = (const float*)d_in[7];
  const float* Dp     = (const float*)d_in[8];
  const float* mn_w   = (const float*)d_in[9];
  const float* mn_b   = (const float*)d_in[10];
  const float* mout_w = (const float*)d_in[11];
  const float* bp_w   = (const float*)d_in[12];
  const float* bp_b   = (const float*)d_in[13];
  const float* ln_w   = (const float*)d_in[14];
  const float* ln_b   = (const float*)d_in[15];
  const float* exp_w  = (const float*)d_in[16];
  const float* pe_w   = (const float*)d_in[17];
  const float* pe_b   = (const float*)d_in[18];

  float* ws = (float*)d_ws;
  float* xcur = ws;                              // 1.57M
  float* xz   = xcur + (size_t)MROWS*DMODEL;     // 6.29M (u0 | z)
  float* ucv  = xz   + (size_t)MROWS*1536;       // 12.58M
  float* xdb  = ucv  + (size_t)4*MROWS*DINNER;   // 0.92M
  float* dtb  = xdb  + (size_t)4*MROWS*GCOLS;    // 12.58M
  float* acc  = dtb  + (size_t)4*MROWS*DINNER;   // 3.15M
  float* t1   = acc  + (size_t)MROWS*DINNER;     // 1.57M
  float* t2   = t1   + (size_t)MROWS*DMODEL;     // 1.57M
  float* hLb  = t2   + (size_t)MROWS*DMODEL;     // 3.15M
  short* xcur_b = (short*)(hLb + (size_t)16*NCHUNK*NSTATE*DINNER);
  short* in_w_b   = xcur_b + (size_t)MROWS*DMODEL;
  short* xp_w_b   = in_w_b + (size_t)2*1536*DMODEL;
  short* mout_w_b = xp_w_b + (size_t)2*GCOLS*DINNER;
  short* bp_w_b   = mout_w_b + (size_t)2*DMODEL*DINNER;
  short* exp_w_b  = bp_w_b + (size_t)2*DMODEL*DMODEL;
  // aliases:
  float* Wb    = t1;                          // t1+t2, dead during scan
  short* ucv_b = (short*)acc;                 // acc+t1+t2 region; dead after xdb GEMM
  float* t3    = dtb;
  short* t2b   = (short*)(dtb + (size_t)2*1024*1024);
  short* acc_b = (short*)(dtb + (size_t)3*1024*1024 + 262144);
  float* xe    = acc;

  // weight conversions (single batched launch)
  {
    int s0 = 2*1536*DMODEL, s1 = 2*GCOLS*DINNER, s2 = 2*DMODEL*DINNER,
        s3 = 2*DMODEL*DMODEL, s4 = 2*DMODEL*DMODEL;
    int tot = s0+s1+s2+s3+s4;
    f2b5_k<<<dim3((tot+255)/256), dim3(256), 0, stream>>>(
        in_w, xp_w, mout_w, bp_w, exp_w, in_w_b, s0, s1, s2, s3, s4);
  }
  cvt_dual_k<<<dim3((MROWS*DMODEL)/256), dim3(256), 0, stream>>>(x_in, xcur, xcur_b, MROWS*DMODEL);

  for (int i = 0; i < 2; i++) {
    // xz = x @ in_w^T   (M=4096, N=1536, K=384)  [MFMA]
    gemm_mfma_k<0><<<dim3(24,64), dim3(256), 0, stream>>>(
        xcur_b, DMODEL, in_w_b + (size_t)i*1536*DMODEL, DMODEL,
        xz, 1536, 1536, DMODEL, nullptr, nullptr);

    // depthwise conv + silu (fp32 + bf16)
    conv_k<<<dim3((4*MROWS*DINNER)/256), dim3(256), 0, stream>>>(
        xz, conv_w + (size_t)i*DINNER*4, conv_b + (size_t)i*DINNER, ucv, ucv_b);

    // xdb = u @ xp_w^T  (M=16384, N=56, K=768)  [MFMA, merged dirs]
    gemm_mfma_k<0><<<dim3(1,256), dim3(256), 0, stream>>>(
        ucv_b, DINNER, xp_w_b + (size_t)i*GCOLS*DINNER, DINNER,
        xdb, GCOLS, GCOLS, DINNER, nullptr, nullptr);

    // dt = softplus(xdb[:,:24] @ dt_w^T + dt_b)  (M=16384, N=768, K=24)  [SIMT]
    gemm_k<1><<<dim3(12,256), dim3(256), 0, stream>>>(
        xdb, GCOLS, dt_w + (size_t)i*DINNER*DTRANK,
        dtb, DINNER, DINNER, DTRANK, dt_b + (size_t)i*DINNER, nullptr);

    zero_k<<<dim3((MROWS*DINNER)/256), dim3(256), 0, stream>>>(acc, MROWS*DINNER);
    chunk_scan_k<<<dim3(3, NCHUNK, 16), dim3(256), 0, stream>>>(
        dtb, ucv, xdb, A_log + (size_t)i*DINNER*NSTATE, Wb, hLb);
    chunk_comb_k<<<dim3(48), dim3(256), 0, stream>>>(Wb, hLb);
    chunk_emit_k<<<dim3(3, NCHUNK, 16), dim3(256), 0, stream>>>(
        dtb, ucv, xdb, A_log + (size_t)i*DINNER*NSTATE, Dp + (size_t)i*DINNER, hLb, acc);
    combine_k<<<dim3((MROWS*DINNER)/256), dim3(256), 0, stream>>>(acc, xz, acc_b);

    // t1 = ymix @ mout_w^T  (N=384, K=768)  [MFMA]
    gemm_mfma_k<0><<<dim3(6,64), dim3(256), 0, stream>>>(
        acc_b, DINNER, mout_w_b + (size_t)i*DMODEL*DINNER, DINNER,
        t1, DMODEL, DMODEL, DINNER, nullptr, nullptr);
    ln384_k<<<dim3(1024), dim3(256), 0, stream>>>(t1, t2, mn_w + (size_t)i*DMODEL, mn_b + (size_t)i*DMODEL, t2b);
    // t3 = xcur + t2 @ bp_w^T + bp_b  (N=384, K=384)  [MFMA + bias + res]
    gemm_mfma_k<2><<<dim3(6,64), dim3(256), 0, stream>>>(
        t2b, DMODEL, bp_w_b + (size_t)i*DMODEL*DMODEL, DMODEL,
        t3, DMODEL, DMODEL, DMODEL, bp_b + (size_t)i*DMODEL, xcur);
    ln384_k<<<dim3(1024), dim3(256), 0, stream>>>(t3, xcur, ln_w + (size_t)i*DMODEL, ln_b + (size_t)i*DMODEL, xcur_b);
  }

  // xe = x @ exp_w^T  (M=4096, N=768, K=384)  [MFMA]
  gemm_mfma_k<0><<<dim3(12,64), dim3(256), 0, stream>>>(
      xcur_b, DMODEL, exp_w_b, DMODEL, xe, 2*DMODEL, 2*DMODEL, DMODEL, nullptr, nullptr);
  // pixel-shuffle + LN(192) -> fp32 out
  peln_k<<<dim3(4096), dim3(256), 0, stream>>>(xe, pe_w, pe_b, (float*)d_out);
}

// Round 6
// 955.434 us; speedup vs baseline: 2.5553x; 1.0183x over previous
//
#include <hip/hip_runtime.h>
#include <hip/hip_bf16.h>
#include <math.h>

typedef __hip_bfloat16 bf16;

#define MROWS 4096      // BATCH * L
#define DMODEL 384
#define DINNER 768
#define GCOLS 56        // DT_RANK + 2*D_STATE
#define DTRANK 24
#define NSTATE 16
#define NCHUNK 16
#define TCHUNK 64

typedef __attribute__((ext_vector_type(8))) short bf16x8;
typedef __attribute__((ext_vector_type(4))) float f32x4;

__device__ __forceinline__ float silu_f(float x){ return x / (1.f + __expf(-x)); }
__device__ __forceinline__ short f2bs(float x){
  bf16 h = __float2bfloat16(x);
  return *(short*)&h;
}

// seq index t -> token index, per direction
__device__ __forceinline__ int perm_tok(int dir, int t){
  if (dir == 0) return t;
  if (dir == 2) return 1023 - t;
  int tt = (dir == 1) ? t : (1023 - t);
  int i = tt >> 5, j = tt & 31;
  return ((31 - j) << 5) | i;   // token = (31-j)*32 + i
}

// ---------------- bf16 MFMA GEMM: C[M,N] = A[M,K] @ W[N,K]^T (fp32 accum) ----
// EPI 0: none; 2: + bias[n] + res[m,n]
template<int EPI>
__launch_bounds__(256)
__global__ void gemm_mfma_k(const short* __restrict__ A, int lda,
                            const short* __restrict__ W, int ldw,
                            float* __restrict__ C, int ldc,
                            int Ndim, int Kdim,
                            const float* __restrict__ bias,
                            const float* __restrict__ res)
{
  const int wv = threadIdx.x >> 6, lane = threadIdx.x & 63;
  const int m0 = blockIdx.y * 64;
  const int n0 = blockIdx.x * 64 + wv * 16;
  const int lm = lane & 15;          // fragment row (A-m / B-n)
  const int kq = (lane >> 4) * 8;    // fragment k offset
  f32x4 acc0 = {0.f,0.f,0.f,0.f}, acc1 = acc0, acc2 = acc0, acc3 = acc0;
  const bool nok = (n0 + lm) < Ndim;
  const short* ap = A + (size_t)(m0 + lm) * lda + kq;
  const short* wp = W + (size_t)(nok ? (n0 + lm) : 0) * ldw + kq;
  const size_t ar16 = (size_t)16 * lda;
  const bf16x8 bz = {0,0,0,0,0,0,0,0};

  for (int k0 = 0; k0 < Kdim; k0 += 32) {
    bf16x8 b = bz;
    if (nok) b = *(const bf16x8*)(wp + k0);
    bf16x8 a0 = *(const bf16x8*)(ap + k0);
    bf16x8 a1 = *(const bf16x8*)(ap + ar16 + k0);
    bf16x8 a2 = *(const bf16x8*)(ap + 2*ar16 + k0);
    bf16x8 a3 = *(const bf16x8*)(ap + 3*ar16 + k0);
    acc0 = __builtin_amdgcn_mfma_f32_16x16x32_bf16(a0, b, acc0, 0, 0, 0);
    acc1 = __builtin_amdgcn_mfma_f32_16x16x32_bf16(a1, b, acc1, 0, 0, 0);
    acc2 = __builtin_amdgcn_mfma_f32_16x16x32_bf16(a2, b, acc2, 0, 0, 0);
    acc3 = __builtin_amdgcn_mfma_f32_16x16x32_bf16(a3, b, acc3, 0, 0, 0);
  }

  const int ncol = n0 + lm;                 // C/D: col = lane&15
  if (ncol < Ndim) {
    const int mr = m0 + (lane >> 4) * 4;    // C/D: row = quad*4 + reg
    f32x4 av[4] = {acc0, acc1, acc2, acc3};
#pragma unroll
    for (int mt = 0; mt < 4; mt++) {
#pragma unroll
      for (int reg = 0; reg < 4; reg++) {
        int m = mr + mt*16 + reg;
        float v = av[mt][reg];
        if (EPI == 2) v += bias[ncol] + res[(size_t)m*ldc + ncol];
        C[(size_t)m*ldc + ncol] = v;
      }
    }
  }
}

// ---------------- fp32 SIMT GEMM (kept for dt: K=24) ----------------
template<int EPI>
__launch_bounds__(256)
__global__ void gemm_k(const float* __restrict__ A, int lda,
                       const float* __restrict__ W,
                       float* __restrict__ C, int ldc,
                       int Ndim, int Kdim,
                       const float* __restrict__ bias,
                       const float* __restrict__ res)
{
  __shared__ float As[16][68];
  __shared__ float Bs[16][68];
  const int tid = threadIdx.x;
  const int m0 = blockIdx.y * 64;
  const int n0 = blockIdx.x * 64;
  const int tr = tid >> 4, tc = tid & 15;
  const int r  = tid >> 2, q  = tid & 3;
  float acc[4][4] = {};

  for (int k0 = 0; k0 < Kdim; k0 += 16) {
    {
      const float* ap = A + (size_t)(m0 + r) * lda + (k0 + q*4);
      float v0=0.f,v1=0.f,v2=0.f,v3=0.f;
      int kc = Kdim - (k0 + q*4);
      if (kc >= 4) { float4 t4 = *(const float4*)ap; v0=t4.x; v1=t4.y; v2=t4.z; v3=t4.w; }
      else { if (kc>0) v0=ap[0]; if (kc>1) v1=ap[1]; if (kc>2) v2=ap[2]; }
      As[q*4+0][r]=v0; As[q*4+1][r]=v1; As[q*4+2][r]=v2; As[q*4+3][r]=v3;
    }
    {
      int nr = n0 + r;
      float v0=0.f,v1=0.f,v2=0.f,v3=0.f;
      if (nr < Ndim) {
        const float* wp = W + (size_t)nr * Kdim + (k0 + q*4);
        int kc = Kdim - (k0 + q*4);
        if (kc >= 4) { float4 t4 = *(const float4*)wp; v0=t4.x; v1=t4.y; v2=t4.z; v3=t4.w; }
        else { if (kc>0) v0=wp[0]; if (kc>1) v1=wp[1]; if (kc>2) v2=wp[2]; }
      }
      Bs[q*4+0][r]=v0; Bs[q*4+1][r]=v1; Bs[q*4+2][r]=v2; Bs[q*4+3][r]=v3;
    }
    __syncthreads();
#pragma unroll
    for (int kk = 0; kk < 16; kk++) {
      float4 a4 = *(const float4*)&As[kk][tr*4];
      float4 b4 = *(const float4*)&Bs[kk][tc*4];
      float av[4] = {a4.x,a4.y,a4.z,a4.w};
      float bv[4] = {b4.x,b4.y,b4.z,b4.w};
#pragma unroll
      for (int i2=0;i2<4;i2++)
#pragma unroll
        for (int j2=0;j2<4;j2++)
          acc[i2][j2] = __builtin_fmaf(av[i2], bv[j2], acc[i2][j2]);
    }
    __syncthreads();
  }

#pragma unroll
  for (int i2=0;i2<4;i2++){
    int m = m0 + tr*4 + i2;
#pragma unroll
    for (int j2=0;j2<4;j2++){
      int n = n0 + tc*4 + j2;
      if (n < Ndim){
        float v = acc[i2][j2];
        if (EPI == 1) { v += bias[n]; v = (v > 20.f) ? v : log1pf(__expf(v)); }
        C[(size_t)m*ldc + n] = v;
      }
    }
  }
}

// ---------------- conversions / misc ----------------
__global__ void f2b5_k(const float* __restrict__ a0, const float* __restrict__ a1,
                       const float* __restrict__ a2, const float* __restrict__ a3,
                       const float* __restrict__ a4, short* __restrict__ o,
                       int s0, int s1, int s2, int s3, int s4)
{
  int id = blockIdx.x*256 + threadIdx.x;
  int e0 = s0, e1 = e0+s1, e2 = e1+s2, e3 = e2+s3, e4 = e3+s4;
  if (id >= e4) return;
  float v;
  if      (id < e0) v = a0[id];
  else if (id < e1) v = a1[id-e0];
  else if (id < e2) v = a2[id-e1];
  else if (id < e3) v = a3[id-e2];
  else              v = a4[id-e3];
  o[id] = f2bs(v);
}
__global__ void cvt_dual_k(const float* __restrict__ in, float* __restrict__ of,
                           short* __restrict__ ob, int n){
  int id = blockIdx.x*256 + threadIdx.x;
  if (id < n) { float v = in[id]; of[id] = v; ob[id] = f2bs(v); }
}
__global__ void zero_k(float* __restrict__ p, int n){
  int id = blockIdx.x*256 + threadIdx.x;
  if (id < n) p[id] = 0.f;
}

// depthwise causal conv (k=4) over permuted sequence + bias + silu; fp32 + bf16 out
__launch_bounds__(256)
__global__ void conv_k(const float* __restrict__ xz, const float* __restrict__ cw,
                       const float* __restrict__ cb, float* __restrict__ ucv,
                       short* __restrict__ ucv_b)
{
  int id = blockIdx.x*256 + threadIdx.x;          // ((dir*4+b)*1024+t)*768+d
  int d = id % DINNER;
  int t = (id / DINNER) & 1023;
  int btdir = id / (DINNER*1024);
  int b_ = btdir & 3, dir = btdir >> 2;
  float s = cb[d];
  const float* up = xz + (size_t)b_*1024*1536 + d;
#pragma unroll
  for (int j=0;j<4;j++){
    int tm = t - 3 + j;
    if (tm >= 0) s += cw[d*4+j] * up[(size_t)perm_tok(dir,tm)*1536];
  }
  float v = silu_f(s);
  ucv[id] = v;
  ucv_b[id] = f2bs(v);
}

// ============ chunked selective scan ============
// grid (3, NCHUNK, 16); t-loop unrolled x4 with grouped loads (latency hiding)
__launch_bounds__(256)
__global__ void chunk_scan_k(const float* __restrict__ dtb, const float* __restrict__ ucv,
                             const float* __restrict__ xdb, const float* __restrict__ A_log,
                             float* __restrict__ Wb, float* __restrict__ hLb)
{
  const int d  = blockIdx.x * 256 + threadIdx.x;   // 0..767
  const int c  = blockIdx.y;                       // chunk
  const int bd = blockIdx.z;                       // dir*4+b

  float A2[NSTATE];
#pragma unroll
  for (int n=0;n<NSTATE;n++)
    A2[n] = -__expf(A_log[d*NSTATE + n]) * 1.44269504f;

  const size_t rowbase = (size_t)bd*1024 + (size_t)c*TCHUNK;
  const float* dtp = dtb + rowbase*DINNER + d;
  const float* up  = ucv + rowbase*DINNER + d;
  const float* bc  = xdb + rowbase*GCOLS + DTRANK;   // block-uniform

  float h[NSTATE] = {};
  float Wp[NSTATE];
#pragma unroll
  for (int n=0;n<NSTATE;n++) Wp[n] = 1.f;

  for (int tg=0; tg<TCHUNK; tg+=4){
    float dt4[4], u4[4];
#pragma unroll
    for (int q=0;q<4;q++){
      dt4[q] = dtp[(size_t)(tg+q)*DINNER];
      u4[q]  = up[(size_t)(tg+q)*DINNER];
    }
#pragma unroll
    for (int q=0;q<4;q++){
      const float* Bv = bc + (tg+q)*GCOLS;           // uniform -> s_load
      float4 B0 = *(const float4*)(Bv+0), B1 = *(const float4*)(Bv+4);
      float4 B2 = *(const float4*)(Bv+8), B3 = *(const float4*)(Bv+12);
      float Bf[NSTATE] = {B0.x,B0.y,B0.z,B0.w, B1.x,B1.y,B1.z,B1.w,
                          B2.x,B2.y,B2.z,B2.w, B3.x,B3.y,B3.z,B3.w};
      float dt = dt4[q], du = dt4[q]*u4[q];
#pragma unroll
      for (int n=0;n<NSTATE;n++){
        float w = exp2f(dt * A2[n]);
        Wp[n] *= w;
        h[n] = h[n]*w + du * Bf[n];
      }
    }
  }
  size_t ob = ((size_t)(bd*NCHUNK + c) * NSTATE) * DINNER + d;
#pragma unroll
  for (int n=0;n<NSTATE;n++){
    Wb[ob + (size_t)n*DINNER]  = Wp[n];
    hLb[ob + (size_t)n*DINNER] = h[n];
  }
}

__launch_bounds__(256)
__global__ void chunk_comb_k(const float* __restrict__ Wb, float* __restrict__ hLb)
{
  int id = blockIdx.x*256 + threadIdx.x;    // (dir*4+b)*768+d
  int d = id % DINNER;
  int bd = id / DINNER;
  float h[NSTATE] = {};
  for (int c=0; c<NCHUNK; c++){
    size_t ob = ((size_t)(bd*NCHUNK + c) * NSTATE) * DINNER + d;
#pragma unroll
    for (int n=0;n<NSTATE;n++){
      float Wc = Wb[ob + (size_t)n*DINNER];
      float hL = hLb[ob + (size_t)n*DINNER];
      float h0 = h[n];
      h[n] = Wc*h0 + hL;
      hLb[ob + (size_t)n*DINNER] = h0;
    }
  }
}

__launch_bounds__(256)
__global__ void chunk_emit_k(const float* __restrict__ dtb, const float* __restrict__ ucv,
                             const float* __restrict__ xdb, const float* __restrict__ A_log,
                             const float* __restrict__ Dp, const float* __restrict__ h0b,
                             float* __restrict__ acc)
{
  const int d  = blockIdx.x * 256 + threadIdx.x;
  const int c  = blockIdx.y;
  const int bd = blockIdx.z;
  const int b  = bd & 3, dir = bd >> 2;

  float A2[NSTATE];
#pragma unroll
  for (int n=0;n<NSTATE;n++)
    A2[n] = -__expf(A_log[d*NSTATE + n]) * 1.44269504f;
  float Dd = Dp[d];

  const size_t rowbase = (size_t)bd*1024 + (size_t)c*TCHUNK;
  const float* dtp = dtb + rowbase*DINNER + d;
  const float* up  = ucv + rowbase*DINNER + d;
  const float* bc  = xdb + rowbase*GCOLS + DTRANK;   // block-uniform
  float* ab = acc + (size_t)b*1024*DINNER + d;

  float h[NSTATE];
  size_t ob = ((size_t)(bd*NCHUNK + c) * NSTATE) * DINNER + d;
#pragma unroll
  for (int n=0;n<NSTATE;n++) h[n] = h0b[ob + (size_t)n*DINNER];

  const int t0 = c * TCHUNK;
  for (int tg=0; tg<TCHUNK; tg+=4){
    float dt4[4], u4[4];
#pragma unroll
    for (int q=0;q<4;q++){
      dt4[q] = dtp[(size_t)(tg+q)*DINNER];
      u4[q]  = up[(size_t)(tg+q)*DINNER];
    }
#pragma unroll
    for (int q=0;q<4;q++){
      const float* Bv = bc + (tg+q)*GCOLS;           // uniform -> s_load
      float4 B0 = *(const float4*)(Bv+0), B1 = *(const float4*)(Bv+4);
      float4 B2 = *(const float4*)(Bv+8), B3 = *(const float4*)(Bv+12);
      float4 C0 = *(const float4*)(Bv+16), C1 = *(const float4*)(Bv+20);
      float4 C2 = *(const float4*)(Bv+24), C3 = *(const float4*)(Bv+28);
      float Bf[NSTATE] = {B0.x,B0.y,B0.z,B0.w, B1.x,B1.y,B1.z,B1.w,
                          B2.x,B2.y,B2.z,B2.w, B3.x,B3.y,B3.z,B3.w};
      float Cf[NSTATE] = {C0.x,C0.y,C0.z,C0.w, C1.x,C1.y,C1.z,C1.w,
                          C2.x,C2.y,C2.z,C2.w, C3.x,C3.y,C3.z,C3.w};
      float dt = dt4[q], u = u4[q], du = dt*u;
      float y = 0.f;
#pragma unroll
      for (int n=0;n<NSTATE;n++){
        float w = exp2f(dt * A2[n]);
        h[n] = h[n]*w + du * Bf[n];
        y = __builtin_fmaf(h[n], Cf[n], y);
      }
      int tok = perm_tok(dir, t0 + tg + q);
      atomicAdd(ab + (size_t)tok*DINNER, y + u*Dd);
    }
  }
}

// acc *= silu(z); also emit bf16
__global__ void combine_k(float* __restrict__ acc, const float* __restrict__ xz,
                          short* __restrict__ acc_b)
{
  int id = blockIdx.x*256 + threadIdx.x;     // < MROWS*DINNER
  int row = id / DINNER;
  int d = id - row*DINNER;
  float z = xz[(size_t)row*1536 + DINNER + d];
  float v = acc[id] * silu_f(z);
  acc[id] = v;
  acc_b[id] = f2bs(v);
}

// layernorm over 384; fp32 out + bf16 out
__launch_bounds__(256)
__global__ void ln384_k(const float* __restrict__ in, float* __restrict__ out,
                        const float* __restrict__ w, const float* __restrict__ b,
                        short* __restrict__ bout)
{
  int wv = threadIdx.x >> 6, lane = threadIdx.x & 63;
  size_t row = (size_t)blockIdx.x * 4 + wv;
  const float* ip = in + row * DMODEL;
  float v[6];
#pragma unroll
  for (int k=0;k<6;k++) v[k] = ip[lane + 64*k];
  float s = 0.f;
#pragma unroll
  for (int k=0;k<6;k++) s += v[k];
#pragma unroll
  for (int o=32;o>0;o>>=1) s += __shfl_xor(s, o);
  float mu = s * (1.f/DMODEL);
  float ss = 0.f;
#pragma unroll
  for (int k=0;k<6;k++){ float dd = v[k]-mu; ss += dd*dd; }
#pragma unroll
  for (int o=32;o>0;o>>=1) ss += __shfl_xor(ss, o);
  float inv = rsqrtf(ss*(1.f/DMODEL) + 1e-5f);
  float* op = out + row * DMODEL;
  short* bp = bout + row * DMODEL;
#pragma unroll
  for (int k=0;k<6;k++){
    int c = lane + 64*k;
    float r = (v[k]-mu)*inv*w[c] + b[c];
    op[c] = r;
    bp[c] = f2bs(r);
  }
}

// pixel-shuffle gather + layernorm over 192 + fp32 store
__launch_bounds__(256)
__global__ void peln_k(const float* __restrict__ xe, const float* __restrict__ w,
                       const float* __restrict__ b, float* __restrict__ out)
{
  int wv = threadIdx.x >> 6, lane = threadIdx.x & 63;
  int row = blockIdx.x * 4 + wv;          // b*4096 + h2*64 + w2
  int bb = row >> 12;
  int r2 = row & 4095;
  int h2 = r2 >> 6, w2 = r2 & 63;
  int h = h2 >> 1, s1 = h2 & 1, w_ = w2 >> 1, s2 = w2 & 1;
  const float* ip = xe + ((size_t)(bb*1024 + h*32 + w_))*768 + (s1*2+s2)*192;
  float v[3];
#pragma unroll
  for (int k=0;k<3;k++) v[k] = ip[lane + 64*k];
  float s = v[0]+v[1]+v[2];
#pragma unroll
  for (int o=32;o>0;o>>=1) s += __shfl_xor(s, o);
  float mu = s * (1.f/192);
  float ss = 0.f;
#pragma unroll
  for (int k=0;k<3;k++){ float dd=v[k]-mu; ss+=dd*dd; }
#pragma unroll
  for (int o=32;o>0;o>>=1) ss += __shfl_xor(ss, o);
  float inv = rsqrtf(ss*(1.f/192) + 1e-5f);
  float* op = out + (size_t)row * 192;
#pragma unroll
  for (int k=0;k<3;k++){ int c = lane + 64*k; op[c] = (v[k]-mu)*inv*w[c] + b[c]; }
}

extern "C" void kernel_launch(void* const* d_in, const int* in_sizes, int n_in,
                              void* d_out, int out_size, void* d_ws, size_t ws_size,
                              hipStream_t stream)
{
  const float* x_in   = (const float*)d_in[0];
  const float* in_w   = (const float*)d_in[1];
  const float* conv_w = (const float*)d_in[2];
  const float* conv_b = (const float*)d_in[3];
  const float* xp_w   = (const float*)d_in[4];
  const float* dt_w   = (const float*)d_in[5];
  const float* dt_b   = (const float*)d_in[6];
  const float* A_log  = (const float*)d_in[7];
  const float* Dp     = (const float*)d_in[8];
  const float* mn_w   = (const float*)d_in[9];
  const float* mn_b   = (const float*)d_in[10];
  const float* mout_w = (const float*)d_in[11];
  const float* bp_w   = (const float*)d_in[12];
  const float* bp_b   = (const float*)d_in[13];
  const float* ln_w   = (const float*)d_in[14];
  const float* ln_b   = (const float*)d_in[15];
  const float* exp_w  = (const float*)d_in[16];
  const float* pe_w   = (const float*)d_in[17];
  const float* pe_b   = (const float*)d_in[18];

  float* ws = (float*)d_ws;
  float* xcur = ws;                              // 1.57M
  float* xz   = xcur + (size_t)MROWS*DMODEL;     // 6.29M (u0 | z)
  float* ucv  = xz   + (size_t)MROWS*1536;       // 12.58M
  float* xdb  = ucv  + (size_t)4*MROWS*DINNER;   // 0.92M
  float* dtb  = xdb  + (size_t)4*MROWS*GCOLS;    // 12.58M
  float* acc  = dtb  + (size_t)4*MROWS*DINNER;   // 3.15M
  float* t1   = acc  + (size_t)MROWS*DINNER;     // 1.57M
  float* t2   = t1   + (size_t)MROWS*DMODEL;     // 1.57M
  float* hLb  = t2   + (size_t)MROWS*DMODEL;     // 3.15M
  short* xcur_b = (short*)(hLb + (size_t)16*NCHUNK*NSTATE*DINNER);
  short* in_w_b   = xcur_b + (size_t)MROWS*DMODEL;
  short* xp_w_b   = in_w_b + (size_t)2*1536*DMODEL;
  short* mout_w_b = xp_w_b + (size_t)2*GCOLS*DINNER;
  short* bp_w_b   = mout_w_b + (size_t)2*DMODEL*DINNER;
  short* exp_w_b  = bp_w_b + (size_t)2*DMODEL*DMODEL;
  // aliases:
  float* Wb    = t1;                          // t1+t2, dead during scan
  short* ucv_b = (short*)acc;                 // acc+t1+t2 region; dead after xdb GEMM
  float* t3    = dtb;
  short* t2b   = (short*)(dtb + (size_t)2*1024*1024);
  short* acc_b = (short*)(dtb + (size_t)3*1024*1024 + 262144);
  float* xe    = acc;

  // weight conversions (single batched launch)
  {
    int s0 = 2*1536*DMODEL, s1 = 2*GCOLS*DINNER, s2 = 2*DMODEL*DINNER,
        s3 = 2*DMODEL*DMODEL, s4 = 2*DMODEL*DMODEL;
    int tot = s0+s1+s2+s3+s4;
    f2b5_k<<<dim3((tot+255)/256), dim3(256), 0, stream>>>(
        in_w, xp_w, mout_w, bp_w, exp_w, in_w_b, s0, s1, s2, s3, s4);
  }
  cvt_dual_k<<<dim3((MROWS*DMODEL)/256), dim3(256), 0, stream>>>(x_in, xcur, xcur_b, MROWS*DMODEL);

  for (int i = 0; i < 2; i++) {
    // xz = x @ in_w^T   (M=4096, N=1536, K=384)  [MFMA]
    gemm_mfma_k<0><<<dim3(24,64), dim3(256), 0, stream>>>(
        xcur_b, DMODEL, in_w_b + (size_t)i*1536*DMODEL, DMODEL,
        xz, 1536, 1536, DMODEL, nullptr, nullptr);

    // depthwise conv + silu (fp32 + bf16)
    conv_k<<<dim3((4*MROWS*DINNER)/256), dim3(256), 0, stream>>>(
        xz, conv_w + (size_t)i*DINNER*4, conv_b + (size_t)i*DINNER, ucv, ucv_b);

    // xdb = u @ xp_w^T  (M=16384, N=56, K=768)  [MFMA, merged dirs]
    gemm_mfma_k<0><<<dim3(1,256), dim3(256), 0, stream>>>(
        ucv_b, DINNER, xp_w_b + (size_t)i*GCOLS*DINNER, DINNER,
        xdb, GCOLS, GCOLS, DINNER, nullptr, nullptr);

    // dt = softplus(xdb[:,:24] @ dt_w^T + dt_b)  (M=16384, N=768, K=24)  [SIMT]
    gemm_k<1><<<dim3(12,256), dim3(256), 0, stream>>>(
        xdb, GCOLS, dt_w + (size_t)i*DINNER*DTRANK,
        dtb, DINNER, DINNER, DTRANK, dt_b + (size_t)i*DINNER, nullptr);

    zero_k<<<dim3((MROWS*DINNER)/256), dim3(256), 0, stream>>>(acc, MROWS*DINNER);
    chunk_scan_k<<<dim3(3, NCHUNK, 16), dim3(256), 0, stream>>>(
        dtb, ucv, xdb, A_log + (size_t)i*DINNER*NSTATE, Wb, hLb);
    chunk_comb_k<<<dim3(48), dim3(256), 0, stream>>>(Wb, hLb);
    chunk_emit_k<<<dim3(3, NCHUNK, 16), dim3(256), 0, stream>>>(
        dtb, ucv, xdb, A_log + (size_t)i*DINNER*NSTATE, Dp + (size_t)i*DINNER, hLb, acc);
    combine_k<<<dim3((MROWS*DINNER)/256), dim3(256), 0, stream>>>(acc, xz, acc_b);

    // t1 = ymix @ mout_w^T  (N=384, K=768)  [MFMA]
    gemm_mfma_k<0><<<dim3(6,64), dim3(256), 0, stream>>>(
        acc_b, DINNER, mout_w_b + (size_t)i*DMODEL*DINNER, DINNER,
        t1, DMODEL, DMODEL, DINNER, nullptr, nullptr);
    ln384_k<<<dim3(1024), dim3(256), 0, stream>>>(t1, t2, mn_w + (size_t)i*DMODEL, mn_b + (size_t)i*DMODEL, t2b);
    // t3 = xcur + t2 @ bp_w^T + bp_b  (N=384, K=384)  [MFMA + bias + res]
    gemm_mfma_k<2><<<dim3(6,64), dim3(256), 0, stream>>>(
        t2b, DMODEL, bp_w_b + (size_t)i*DMODEL*DMODEL, DMODEL,
        t3, DMODEL, DMODEL, DMODEL, bp_b + (size_t)i*DMODEL, xcur);
    ln384_k<<<dim3(1024), dim3(256), 0, stream>>>(t3, xcur, ln_w + (size_t)i*DMODEL, ln_b + (size_t)i*DMODEL, xcur_b);
  }

  // xe = x @ exp_w^T  (M=4096, N=768, K=384)  [MFMA]
  gemm_mfma_k<0><<<dim3(12,64), dim3(256), 0, stream>>>(
      xcur_b, DMODEL, exp_w_b, DMODEL, xe, 2*DMODEL, 2*DMODEL, DMODEL, nullptr, nullptr);
  // pixel-shuffle + LN(192) -> fp32 out
  peln_k<<<dim3(4096), dim3(256), 0, stream>>>(xe, pe_w, pe_b, (float*)d_out);
}

// Round 7
// 849.473 us; speedup vs baseline: 2.8740x; 1.1247x over previous
//
#include <hip/hip_runtime.h>
#include <hip/hip_bf16.h>
#include <math.h>

typedef __hip_bfloat16 bf16;

#define MROWS 4096      // BATCH * L
#define DMODEL 384
#define DINNER 768
#define GCOLS 56        // DT_RANK + 2*D_STATE
#define DTRANK 24
#define NSTATE 16
#define NCHUNK 32
#define TCHUNK 32

typedef __attribute__((ext_vector_type(8))) short bf16x8;
typedef __attribute__((ext_vector_type(4))) float f32x4;

#if __has_builtin(__builtin_amdgcn_exp2f)
#define EXP2F(x) __builtin_amdgcn_exp2f(x)
#else
#define EXP2F(x) exp2f(x)
#endif

__device__ __forceinline__ float silu_f(float x){ return x / (1.f + __expf(-x)); }
__device__ __forceinline__ short f2bs(float x){
  bf16 h = __float2bfloat16(x);
  return *(short*)&h;
}

// seq index t -> token index, per direction
__device__ __forceinline__ int perm_tok(int dir, int t){
  if (dir == 0) return t;
  if (dir == 2) return 1023 - t;
  int tt = (dir == 1) ? t : (1023 - t);
  int i = tt >> 5, j = tt & 31;
  return ((31 - j) << 5) | i;   // token = (31-j)*32 + i
}

// ---------------- bf16 MFMA GEMM: C[M,N] = A[M,K] @ W[N,K]^T (fp32 accum) ----
// EPI 0: none; 2: + bias[n] + res[m,n]
template<int EPI>
__launch_bounds__(256)
__global__ void gemm_mfma_k(const short* __restrict__ A, int lda,
                            const short* __restrict__ W, int ldw,
                            float* __restrict__ C, int ldc,
                            int Ndim, int Kdim,
                            const float* __restrict__ bias,
                            const float* __restrict__ res)
{
  const int wv = threadIdx.x >> 6, lane = threadIdx.x & 63;
  const int m0 = blockIdx.y * 64;
  const int n0 = blockIdx.x * 64 + wv * 16;
  const int lm = lane & 15;          // fragment row (A-m / B-n)
  const int kq = (lane >> 4) * 8;    // fragment k offset
  f32x4 acc0 = {0.f,0.f,0.f,0.f}, acc1 = acc0, acc2 = acc0, acc3 = acc0;
  const bool nok = (n0 + lm) < Ndim;
  const short* ap = A + (size_t)(m0 + lm) * lda + kq;
  const short* wp = W + (size_t)(nok ? (n0 + lm) : 0) * ldw + kq;
  const size_t ar16 = (size_t)16 * lda;
  const bf16x8 bz = {0,0,0,0,0,0,0,0};

  for (int k0 = 0; k0 < Kdim; k0 += 32) {
    bf16x8 b = bz;
    if (nok) b = *(const bf16x8*)(wp + k0);
    bf16x8 a0 = *(const bf16x8*)(ap + k0);
    bf16x8 a1 = *(const bf16x8*)(ap + ar16 + k0);
    bf16x8 a2 = *(const bf16x8*)(ap + 2*ar16 + k0);
    bf16x8 a3 = *(const bf16x8*)(ap + 3*ar16 + k0);
    acc0 = __builtin_amdgcn_mfma_f32_16x16x32_bf16(a0, b, acc0, 0, 0, 0);
    acc1 = __builtin_amdgcn_mfma_f32_16x16x32_bf16(a1, b, acc1, 0, 0, 0);
    acc2 = __builtin_amdgcn_mfma_f32_16x16x32_bf16(a2, b, acc2, 0, 0, 0);
    acc3 = __builtin_amdgcn_mfma_f32_16x16x32_bf16(a3, b, acc3, 0, 0, 0);
  }

  const int ncol = n0 + lm;                 // C/D: col = lane&15
  if (ncol < Ndim) {
    const int mr = m0 + (lane >> 4) * 4;    // C/D: row = quad*4 + reg
    f32x4 av[4] = {acc0, acc1, acc2, acc3};
#pragma unroll
    for (int mt = 0; mt < 4; mt++) {
#pragma unroll
      for (int reg = 0; reg < 4; reg++) {
        int m = mr + mt*16 + reg;
        float v = av[mt][reg];
        if (EPI == 2) v += bias[ncol] + res[(size_t)m*ldc + ncol];
        C[(size_t)m*ldc + ncol] = v;
      }
    }
  }
}

// ---------------- fp32 SIMT GEMM (kept for dt: K=24) ----------------
template<int EPI>
__launch_bounds__(256)
__global__ void gemm_k(const float* __restrict__ A, int lda,
                       const float* __restrict__ W,
                       float* __restrict__ C, int ldc,
                       int Ndim, int Kdim,
                       const float* __restrict__ bias,
                       const float* __restrict__ res)
{
  __shared__ float As[16][68];
  __shared__ float Bs[16][68];
  const int tid = threadIdx.x;
  const int m0 = blockIdx.y * 64;
  const int n0 = blockIdx.x * 64;
  const int tr = tid >> 4, tc = tid & 15;
  const int r  = tid >> 2, q  = tid & 3;
  float acc[4][4] = {};

  for (int k0 = 0; k0 < Kdim; k0 += 16) {
    {
      const float* ap = A + (size_t)(m0 + r) * lda + (k0 + q*4);
      float v0=0.f,v1=0.f,v2=0.f,v3=0.f;
      int kc = Kdim - (k0 + q*4);
      if (kc >= 4) { float4 t4 = *(const float4*)ap; v0=t4.x; v1=t4.y; v2=t4.z; v3=t4.w; }
      else { if (kc>0) v0=ap[0]; if (kc>1) v1=ap[1]; if (kc>2) v2=ap[2]; }
      As[q*4+0][r]=v0; As[q*4+1][r]=v1; As[q*4+2][r]=v2; As[q*4+3][r]=v3;
    }
    {
      int nr = n0 + r;
      float v0=0.f,v1=0.f,v2=0.f,v3=0.f;
      if (nr < Ndim) {
        const float* wp = W + (size_t)nr * Kdim + (k0 + q*4);
        int kc = Kdim - (k0 + q*4);
        if (kc >= 4) { float4 t4 = *(const float4*)wp; v0=t4.x; v1=t4.y; v2=t4.z; v3=t4.w; }
        else { if (kc>0) v0=wp[0]; if (kc>1) v1=wp[1]; if (kc>2) v2=wp[2]; }
      }
      Bs[q*4+0][r]=v0; Bs[q*4+1][r]=v1; Bs[q*4+2][r]=v2; Bs[q*4+3][r]=v3;
    }
    __syncthreads();
#pragma unroll
    for (int kk = 0; kk < 16; kk++) {
      float4 a4 = *(const float4*)&As[kk][tr*4];
      float4 b4 = *(const float4*)&Bs[kk][tc*4];
      float av[4] = {a4.x,a4.y,a4.z,a4.w};
      float bv[4] = {b4.x,b4.y,b4.z,b4.w};
#pragma unroll
      for (int i2=0;i2<4;i2++)
#pragma unroll
        for (int j2=0;j2<4;j2++)
          acc[i2][j2] = __builtin_fmaf(av[i2], bv[j2], acc[i2][j2]);
    }
    __syncthreads();
  }

#pragma unroll
  for (int i2=0;i2<4;i2++){
    int m = m0 + tr*4 + i2;
#pragma unroll
    for (int j2=0;j2<4;j2++){
      int n = n0 + tc*4 + j2;
      if (n < Ndim){
        float v = acc[i2][j2];
        if (EPI == 1) { v += bias[n]; v = (v > 20.f) ? v : log1pf(__expf(v)); }
        C[(size_t)m*ldc + n] = v;
      }
    }
  }
}

// ---------------- conversions / misc ----------------
__global__ void f2b5_k(const float* __restrict__ a0, const float* __restrict__ a1,
                       const float* __restrict__ a2, const float* __restrict__ a3,
                       const float* __restrict__ a4, short* __restrict__ o,
                       int s0, int s1, int s2, int s3, int s4)
{
  int id = blockIdx.x*256 + threadIdx.x;
  int e0 = s0, e1 = e0+s1, e2 = e1+s2, e3 = e2+s3, e4 = e3+s4;
  if (id >= e4) return;
  float v;
  if      (id < e0) v = a0[id];
  else if (id < e1) v = a1[id-e0];
  else if (id < e2) v = a2[id-e1];
  else if (id < e3) v = a3[id-e2];
  else              v = a4[id-e3];
  o[id] = f2bs(v);
}
__global__ void cvt_dual_k(const float* __restrict__ in, float* __restrict__ of,
                           short* __restrict__ ob, int n){
  int id = blockIdx.x*256 + threadIdx.x;
  if (id < n) { float v = in[id]; of[id] = v; ob[id] = f2bs(v); }
}
__global__ void zero_k(float* __restrict__ p, int n){
  int id = blockIdx.x*256 + threadIdx.x;
  if (id < n) p[id] = 0.f;
}

// depthwise causal conv (k=4) over permuted sequence + bias + silu; fp32 + bf16 out
__launch_bounds__(256)
__global__ void conv_k(const float* __restrict__ xz, const float* __restrict__ cw,
                       const float* __restrict__ cb, float* __restrict__ ucv,
                       short* __restrict__ ucv_b)
{
  int id = blockIdx.x*256 + threadIdx.x;          // ((dir*4+b)*1024+t)*768+d
  int d = id % DINNER;
  int t = (id / DINNER) & 1023;
  int btdir = id / (DINNER*1024);
  int b_ = btdir & 3, dir = btdir >> 2;
  float s = cb[d];
  const float* up = xz + (size_t)b_*1024*1536 + d;
#pragma unroll
  for (int j=0;j<4;j++){
    int tm = t - 3 + j;
    if (tm >= 0) s += cw[d*4+j] * up[(size_t)perm_tok(dir,tm)*1536];
  }
  float v = silu_f(s);
  ucv[id] = v;
  ucv_b[id] = f2bs(v);
}

// ============ chunked selective scan ============
// Pass A: grid (3, NCHUNK, 16): local scan from 0 -> hL[n]; accumulate sum_dt
__launch_bounds__(256)
__global__ void chunk_scan_k(const float* __restrict__ dtb, const float* __restrict__ ucv,
                             const float* __restrict__ xdb, const float* __restrict__ A_log,
                             float* __restrict__ sums, float* __restrict__ hLb)
{
  const int d  = blockIdx.x * 256 + threadIdx.x;   // 0..767
  const int c  = blockIdx.y;                       // chunk
  const int bd = blockIdx.z;                       // dir*4+b

  float A2[NSTATE];
#pragma unroll
  for (int n=0;n<NSTATE;n++)
    A2[n] = -__expf(A_log[d*NSTATE + n]) * 1.44269504f;

  const size_t rowbase = (size_t)bd*1024 + (size_t)c*TCHUNK;
  const float* dtp = dtb + rowbase*DINNER + d;
  const float* up  = ucv + rowbase*DINNER + d;
  const float* bc  = xdb + rowbase*GCOLS + DTRANK;   // block-uniform

  float h[NSTATE] = {};
  float sdt = 0.f;

  for (int tg=0; tg<TCHUNK; tg+=4){
    float dt4[4], u4[4];
#pragma unroll
    for (int q=0;q<4;q++){
      dt4[q] = dtp[(size_t)(tg+q)*DINNER];
      u4[q]  = up[(size_t)(tg+q)*DINNER];
    }
#pragma unroll
    for (int q=0;q<4;q++){
      const float* Bv = bc + (tg+q)*GCOLS;           // uniform -> s_load
      float4 B0 = *(const float4*)(Bv+0), B1 = *(const float4*)(Bv+4);
      float4 B2 = *(const float4*)(Bv+8), B3 = *(const float4*)(Bv+12);
      float Bf[NSTATE] = {B0.x,B0.y,B0.z,B0.w, B1.x,B1.y,B1.z,B1.w,
                          B2.x,B2.y,B2.z,B2.w, B3.x,B3.y,B3.z,B3.w};
      float dt = dt4[q], du = dt4[q]*u4[q];
      sdt += dt;
#pragma unroll
      for (int n=0;n<NSTATE;n++){
        float w = EXP2F(dt * A2[n]);
        h[n] = h[n]*w + du * Bf[n];
      }
    }
  }
  size_t ob = ((size_t)(bd*NCHUNK + c) * NSTATE) * DINNER + d;
#pragma unroll
  for (int n=0;n<NSTATE;n++)
    hLb[ob + (size_t)n*DINNER] = h[n];
  sums[(size_t)(bd*NCHUNK + c)*DINNER + d] = sdt;
}

// Pass B: serial combine over chunks; W reconstructed from sum_dt; hLb -> chunk-initial h0
__launch_bounds__(256)
__global__ void chunk_comb_k(const float* __restrict__ sums, const float* __restrict__ A_log,
                             float* __restrict__ hLb)
{
  int id = blockIdx.x*256 + threadIdx.x;    // (dir*4+b)*768+d
  int d = id % DINNER;
  int bd = id / DINNER;
  float A2[NSTATE];
#pragma unroll
  for (int n=0;n<NSTATE;n++)
    A2[n] = -__expf(A_log[d*NSTATE + n]) * 1.44269504f;
  float h[NSTATE] = {};
  for (int c=0; c<NCHUNK; c++){
    size_t ob = ((size_t)(bd*NCHUNK + c) * NSTATE) * DINNER + d;
    float sdt = sums[(size_t)(bd*NCHUNK + c)*DINNER + d];
#pragma unroll
    for (int n=0;n<NSTATE;n++){
      float Wc = EXP2F(A2[n] * sdt);
      float hL = hLb[ob + (size_t)n*DINNER];
      float h0 = h[n];
      h[n] = Wc*h0 + hL;
      hLb[ob + (size_t)n*DINNER] = h0;
    }
  }
}

// Pass C: replay from h0, emit y, scatter-add token-space
__launch_bounds__(256)
__global__ void chunk_emit_k(const float* __restrict__ dtb, const float* __restrict__ ucv,
                             const float* __restrict__ xdb, const float* __restrict__ A_log,
                             const float* __restrict__ Dp, const float* __restrict__ h0b,
                             float* __restrict__ acc)
{
  const int d  = blockIdx.x * 256 + threadIdx.x;
  const int c  = blockIdx.y;
  const int bd = blockIdx.z;
  const int b  = bd & 3, dir = bd >> 2;

  float A2[NSTATE];
#pragma unroll
  for (int n=0;n<NSTATE;n++)
    A2[n] = -__expf(A_log[d*NSTATE + n]) * 1.44269504f;
  float Dd = Dp[d];

  const size_t rowbase = (size_t)bd*1024 + (size_t)c*TCHUNK;
  const float* dtp = dtb + rowbase*DINNER + d;
  const float* up  = ucv + rowbase*DINNER + d;
  const float* bc  = xdb + rowbase*GCOLS + DTRANK;   // block-uniform
  float* ab = acc + (size_t)b*1024*DINNER + d;

  float h[NSTATE];
  size_t ob = ((size_t)(bd*NCHUNK + c) * NSTATE) * DINNER + d;
#pragma unroll
  for (int n=0;n<NSTATE;n++) h[n] = h0b[ob + (size_t)n*DINNER];

  const int t0 = c * TCHUNK;
  for (int tg=0; tg<TCHUNK; tg+=4){
    float dt4[4], u4[4];
#pragma unroll
    for (int q=0;q<4;q++){
      dt4[q] = dtp[(size_t)(tg+q)*DINNER];
      u4[q]  = up[(size_t)(tg+q)*DINNER];
    }
#pragma unroll
    for (int q=0;q<4;q++){
      const float* Bv = bc + (tg+q)*GCOLS;           // uniform -> s_load
      float4 B0 = *(const float4*)(Bv+0), B1 = *(const float4*)(Bv+4);
      float4 B2 = *(const float4*)(Bv+8), B3 = *(const float4*)(Bv+12);
      float4 C0 = *(const float4*)(Bv+16), C1 = *(const float4*)(Bv+20);
      float4 C2 = *(const float4*)(Bv+24), C3 = *(const float4*)(Bv+28);
      float Bf[NSTATE] = {B0.x,B0.y,B0.z,B0.w, B1.x,B1.y,B1.z,B1.w,
                          B2.x,B2.y,B2.z,B2.w, B3.x,B3.y,B3.z,B3.w};
      float Cf[NSTATE] = {C0.x,C0.y,C0.z,C0.w, C1.x,C1.y,C1.z,C1.w,
                          C2.x,C2.y,C2.z,C2.w, C3.x,C3.y,C3.z,C3.w};
      float dt = dt4[q], u = u4[q], du = dt*u;
      float y = 0.f;
#pragma unroll
      for (int n=0;n<NSTATE;n++){
        float w = EXP2F(dt * A2[n]);
        h[n] = h[n]*w + du * Bf[n];
        y = __builtin_fmaf(h[n], Cf[n], y);
      }
      int tok = perm_tok(dir, t0 + tg + q);
      atomicAdd(ab + (size_t)tok*DINNER, y + u*Dd);
    }
  }
}

// acc *= silu(z); also emit bf16
__global__ void combine_k(float* __restrict__ acc, const float* __restrict__ xz,
                          short* __restrict__ acc_b)
{
  int id = blockIdx.x*256 + threadIdx.x;     // < MROWS*DINNER
  int row = id / DINNER;
  int d = id - row*DINNER;
  float z = xz[(size_t)row*1536 + DINNER + d];
  float v = acc[id] * silu_f(z);
  acc[id] = v;
  acc_b[id] = f2bs(v);
}

// layernorm over 384; fp32 out + bf16 out
__launch_bounds__(256)
__global__ void ln384_k(const float* __restrict__ in, float* __restrict__ out,
                        const float* __restrict__ w, const float* __restrict__ b,
                        short* __restrict__ bout)
{
  int wv = threadIdx.x >> 6, lane = threadIdx.x & 63;
  size_t row = (size_t)blockIdx.x * 4 + wv;
  const float* ip = in + row * DMODEL;
  float v[6];
#pragma unroll
  for (int k=0;k<6;k++) v[k] = ip[lane + 64*k];
  float s = 0.f;
#pragma unroll
  for (int k=0;k<6;k++) s += v[k];
#pragma unroll
  for (int o=32;o>0;o>>=1) s += __shfl_xor(s, o);
  float mu = s * (1.f/DMODEL);
  float ss = 0.f;
#pragma unroll
  for (int k=0;k<6;k++){ float dd = v[k]-mu; ss += dd*dd; }
#pragma unroll
  for (int o=32;o>0;o>>=1) ss += __shfl_xor(ss, o);
  float inv = rsqrtf(ss*(1.f/DMODEL) + 1e-5f);
  float* op = out + row * DMODEL;
  short* bp = bout + row * DMODEL;
#pragma unroll
  for (int k=0;k<6;k++){
    int c = lane + 64*k;
    float r = (v[k]-mu)*inv*w[c] + b[c];
    op[c] = r;
    bp[c] = f2bs(r);
  }
}

// pixel-shuffle gather + layernorm over 192 + fp32 store
__launch_bounds__(256)
__global__ void peln_k(const float* __restrict__ xe, const float* __restrict__ w,
                       const float* __restrict__ b, float* __restrict__ out)
{
  int wv = threadIdx.x >> 6, lane = threadIdx.x & 63;
  int row = blockIdx.x * 4 + wv;          // b*4096 + h2*64 + w2
  int bb = row >> 12;
  int r2 = row & 4095;
  int h2 = r2 >> 6, w2 = r2 & 63;
  int h = h2 >> 1, s1 = h2 & 1, w_ = w2 >> 1, s2 = w2 & 1;
  const float* ip = xe + ((size_t)(bb*1024 + h*32 + w_))*768 + (s1*2+s2)*192;
  float v[3];
#pragma unroll
  for (int k=0;k<3;k++) v[k] = ip[lane + 64*k];
  float s = v[0]+v[1]+v[2];
#pragma unroll
  for (int o=32;o>0;o>>=1) s += __shfl_xor(s, o);
  float mu = s * (1.f/192);
  float ss = 0.f;
#pragma unroll
  for (int k=0;k<3;k++){ float dd=v[k]-mu; ss+=dd*dd; }
#pragma unroll
  for (int o=32;o>0;o>>=1) ss += __shfl_xor(ss, o);
  float inv = rsqrtf(ss*(1.f/192) + 1e-5f);
  float* op = out + (size_t)row * 192;
#pragma unroll
  for (int k=0;k<3;k++){ int c = lane + 64*k; op[c] = (v[k]-mu)*inv*w[c] + b[c]; }
}

extern "C" void kernel_launch(void* const* d_in, const int* in_sizes, int n_in,
                              void* d_out, int out_size, void* d_ws, size_t ws_size,
                              hipStream_t stream)
{
  const float* x_in   = (const float*)d_in[0];
  const float* in_w   = (const float*)d_in[1];
  const float* conv_w = (const float*)d_in[2];
  const float* conv_b = (const float*)d_in[3];
  const float* xp_w   = (const float*)d_in[4];
  const float* dt_w   = (const float*)d_in[5];
  const float* dt_b   = (const float*)d_in[6];
  const float* A_log  = (const float*)d_in[7];
  const float* Dp     = (const float*)d_in[8];
  const float* mn_w   = (const float*)d_in[9];
  const float* mn_b   = (const float*)d_in[10];
  const float* mout_w = (const float*)d_in[11];
  const float* bp_w   = (const float*)d_in[12];
  const float* bp_b   = (const float*)d_in[13];
  const float* ln_w   = (const float*)d_in[14];
  const float* ln_b   = (const float*)d_in[15];
  const float* exp_w  = (const float*)d_in[16];
  const float* pe_w   = (const float*)d_in[17];
  const float* pe_b   = (const float*)d_in[18];

  float* ws = (float*)d_ws;
  float* xcur = ws;                              // 1,572,864
  float* xz   = xcur + (size_t)MROWS*DMODEL;     // 6,291,456 (u0 | z)
  float* ucv  = xz   + (size_t)MROWS*1536;       // 12,582,912
  float* xdb  = ucv  + (size_t)4*MROWS*DINNER;   // 917,504
  float* dtb  = xdb  + (size_t)4*MROWS*GCOLS;    // 12,582,912
  float* acc  = dtb  + (size_t)4*MROWS*DINNER;   // 3,145,728
  float* big  = acc  + (size_t)MROWS*DINNER;     // 6,291,456 (t1|t2|scan-hL union)
  float* t1   = big;                             // 1,572,864
  float* t2   = t1   + (size_t)MROWS*DMODEL;     // 1,572,864
  float* hLb  = big;                             // 16*32*16*768 = 6,291,456 (scan phase)
  short* xcur_b   = (short*)(big + (size_t)6291456);
  short* in_w_b   = xcur_b + (size_t)MROWS*DMODEL;
  short* xp_w_b   = in_w_b + (size_t)2*1536*DMODEL;
  short* mout_w_b = xp_w_b + (size_t)2*GCOLS*DINNER;
  short* bp_w_b   = mout_w_b + (size_t)2*DMODEL*DINNER;
  short* exp_w_b  = bp_w_b + (size_t)2*DMODEL*DMODEL;
  float* sums     = (float*)(exp_w_b + (size_t)2*DMODEL*DMODEL);  // 16*32*768 = 393,216
  // aliases:
  short* ucv_b = (short*)acc;                 // acc+big region; dead after xdb GEMM
  float* t3    = dtb;
  short* t2b   = (short*)(dtb + (size_t)2*1024*1024);
  short* acc_b = (short*)(dtb + (size_t)3*1024*1024 + 262144);
  float* xe    = acc;

  // weight conversions (single batched launch)
  {
    int s0 = 2*1536*DMODEL, s1 = 2*GCOLS*DINNER, s2 = 2*DMODEL*DINNER,
        s3 = 2*DMODEL*DMODEL, s4 = 2*DMODEL*DMODEL;
    int tot = s0+s1+s2+s3+s4;
    f2b5_k<<<dim3((tot+255)/256), dim3(256), 0, stream>>>(
        in_w, xp_w, mout_w, bp_w, exp_w, in_w_b, s0, s1, s2, s3, s4);
  }
  cvt_dual_k<<<dim3((MROWS*DMODEL)/256), dim3(256), 0, stream>>>(x_in, xcur, xcur_b, MROWS*DMODEL);

  for (int i = 0; i < 2; i++) {
    // xz = x @ in_w^T   (M=4096, N=1536, K=384)  [MFMA]
    gemm_mfma_k<0><<<dim3(24,64), dim3(256), 0, stream>>>(
        xcur_b, DMODEL, in_w_b + (size_t)i*1536*DMODEL, DMODEL,
        xz, 1536, 1536, DMODEL, nullptr, nullptr);

    // depthwise conv + silu (fp32 + bf16)
    conv_k<<<dim3((4*MROWS*DINNER)/256), dim3(256), 0, stream>>>(
        xz, conv_w + (size_t)i*DINNER*4, conv_b + (size_t)i*DINNER, ucv, ucv_b);

    // xdb = u @ xp_w^T  (M=16384, N=56, K=768)  [MFMA, merged dirs]
    gemm_mfma_k<0><<<dim3(1,256), dim3(256), 0, stream>>>(
        ucv_b, DINNER, xp_w_b + (size_t)i*GCOLS*DINNER, DINNER,
        xdb, GCOLS, GCOLS, DINNER, nullptr, nullptr);

    // dt = softplus(xdb[:,:24] @ dt_w^T + dt_b)  (M=16384, N=768, K=24)  [SIMT]
    gemm_k<1><<<dim3(12,256), dim3(256), 0, stream>>>(
        xdb, GCOLS, dt_w + (size_t)i*DINNER*DTRANK,
        dtb, DINNER, DINNER, DTRANK, dt_b + (size_t)i*DINNER, nullptr);

    zero_k<<<dim3((MROWS*DINNER)/256), dim3(256), 0, stream>>>(acc, MROWS*DINNER);
    chunk_scan_k<<<dim3(3, NCHUNK, 16), dim3(256), 0, stream>>>(
        dtb, ucv, xdb, A_log + (size_t)i*DINNER*NSTATE, sums, hLb);
    chunk_comb_k<<<dim3(48), dim3(256), 0, stream>>>(sums, A_log + (size_t)i*DINNER*NSTATE, hLb);
    chunk_emit_k<<<dim3(3, NCHUNK, 16), dim3(256), 0, stream>>>(
        dtb, ucv, xdb, A_log + (size_t)i*DINNER*NSTATE, Dp + (size_t)i*DINNER, hLb, acc);
    combine_k<<<dim3((MROWS*DINNER)/256), dim3(256), 0, stream>>>(acc, xz, acc_b);

    // t1 = ymix @ mout_w^T  (N=384, K=768)  [MFMA]
    gemm_mfma_k<0><<<dim3(6,64), dim3(256), 0, stream>>>(
        acc_b, DINNER, mout_w_b + (size_t)i*DMODEL*DINNER, DINNER,
        t1, DMODEL, DMODEL, DINNER, nullptr, nullptr);
    ln384_k<<<dim3(1024), dim3(256), 0, stream>>>(t1, t2, mn_w + (size_t)i*DMODEL, mn_b + (size_t)i*DMODEL, t2b);
    // t3 = xcur + t2 @ bp_w^T + bp_b  (N=384, K=384)  [MFMA + bias + res]
    gemm_mfma_k<2><<<dim3(6,64), dim3(256), 0, stream>>>(
        t2b, DMODEL, bp_w_b + (size_t)i*DMODEL*DMODEL, DMODEL,
        t3, DMODEL, DMODEL, DMODEL, bp_b + (size_t)i*DMODEL, xcur);
    ln384_k<<<dim3(1024), dim3(256), 0, stream>>>(t3, xcur, ln_w + (size_t)i*DMODEL, ln_b + (size_t)i*DMODEL, xcur_b);
  }

  // xe = x @ exp_w^T  (M=4096, N=768, K=384)  [MFMA]
  gemm_mfma_k<0><<<dim3(12,64), dim3(256), 0, stream>>>(
      xcur_b, DMODEL, exp_w_b, DMODEL, xe, 2*DMODEL, 2*DMODEL, DMODEL, nullptr, nullptr);
  // pixel-shuffle + LN(192) -> fp32 out
  peln_k<<<dim3(4096), dim3(256), 0, stream>>>(xe, pe_w, pe_b, (float*)d_out);
}

// Round 8
// 828.498 us; speedup vs baseline: 2.9468x; 1.0253x over previous
//
#include <hip/hip_runtime.h>
#include <hip/hip_bf16.h>
#include <math.h>

typedef __hip_bfloat16 bf16;

#define MROWS 4096      // BATCH * L
#define DMODEL 384
#define DINNER 768
#define GCOLS 56        // DT_RANK + 2*D_STATE
#define DTRANK 24
#define NSTATE 16
#define NCHUNK 32
#define TCHUNK 32

typedef __attribute__((ext_vector_type(8))) short bf16x8;
typedef __attribute__((ext_vector_type(4))) float f32x4;

#if __has_builtin(__builtin_amdgcn_exp2f)
#define EXP2F(x) __builtin_amdgcn_exp2f(x)
#else
#define EXP2F(x) exp2f(x)
#endif

__device__ __forceinline__ float silu_f(float x){ return x / (1.f + __expf(-x)); }
__device__ __forceinline__ short f2bs(float x){
  bf16 h = __float2bfloat16(x);
  return *(short*)&h;
}
__device__ __forceinline__ float bs2f(short s){
  bf16 h = *(bf16*)&s;
  return __bfloat162float(h);
}

// seq index t -> token index, per direction
__device__ __forceinline__ int perm_tok(int dir, int t){
  if (dir == 0) return t;
  if (dir == 2) return 1023 - t;
  int tt = (dir == 1) ? t : (1023 - t);
  int i = tt >> 5, j = tt & 31;
  return ((31 - j) << 5) | i;   // token = (31-j)*32 + i
}

// ---------------- bf16 MFMA GEMM: C[M,N] = A[M,K] @ W[N,K]^T (fp32 accum) ----
// EPI 0: none (fp32 out); 2: + bias[n] + res[m,n] (fp32 out)
template<int EPI>
__launch_bounds__(256)
__global__ void gemm_mfma_k(const short* __restrict__ A, int lda,
                            const short* __restrict__ W, int ldw,
                            float* __restrict__ C, int ldc,
                            int Ndim, int Kdim,
                            const float* __restrict__ bias,
                            const float* __restrict__ res)
{
  const int wv = threadIdx.x >> 6, lane = threadIdx.x & 63;
  const int m0 = blockIdx.y * 64;
  const int n0 = blockIdx.x * 64 + wv * 16;
  const int lm = lane & 15;          // fragment row (A-m / B-n)
  const int kq = (lane >> 4) * 8;    // fragment k offset
  f32x4 acc0 = {0.f,0.f,0.f,0.f}, acc1 = acc0, acc2 = acc0, acc3 = acc0;
  const bool nok = (n0 + lm) < Ndim;
  const short* ap = A + (size_t)(m0 + lm) * lda + kq;
  const short* wp = W + (size_t)(nok ? (n0 + lm) : 0) * ldw + kq;
  const size_t ar16 = (size_t)16 * lda;
  const bf16x8 bz = {0,0,0,0,0,0,0,0};

  for (int k0 = 0; k0 < Kdim; k0 += 32) {
    bf16x8 b = bz;
    if (nok) b = *(const bf16x8*)(wp + k0);
    bf16x8 a0 = *(const bf16x8*)(ap + k0);
    bf16x8 a1 = *(const bf16x8*)(ap + ar16 + k0);
    bf16x8 a2 = *(const bf16x8*)(ap + 2*ar16 + k0);
    bf16x8 a3 = *(const bf16x8*)(ap + 3*ar16 + k0);
    acc0 = __builtin_amdgcn_mfma_f32_16x16x32_bf16(a0, b, acc0, 0, 0, 0);
    acc1 = __builtin_amdgcn_mfma_f32_16x16x32_bf16(a1, b, acc1, 0, 0, 0);
    acc2 = __builtin_amdgcn_mfma_f32_16x16x32_bf16(a2, b, acc2, 0, 0, 0);
    acc3 = __builtin_amdgcn_mfma_f32_16x16x32_bf16(a3, b, acc3, 0, 0, 0);
  }

  const int ncol = n0 + lm;                 // C/D: col = lane&15
  if (ncol < Ndim) {
    const int mr = m0 + (lane >> 4) * 4;    // C/D: row = quad*4 + reg
    f32x4 av[4] = {acc0, acc1, acc2, acc3};
#pragma unroll
    for (int mt = 0; mt < 4; mt++) {
#pragma unroll
      for (int reg = 0; reg < 4; reg++) {
        int m = mr + mt*16 + reg;
        float v = av[mt][reg];
        if (EPI == 2) v += bias[ncol] + res[(size_t)m*ldc + ncol];
        C[(size_t)m*ldc + ncol] = v;
      }
    }
  }
}

// same GEMM but bf16 output (for in_proj -> xz_b)
__launch_bounds__(256)
__global__ void gemm_mfma_bout_k(const short* __restrict__ A, int lda,
                                 const short* __restrict__ W, int ldw,
                                 short* __restrict__ C, int ldc,
                                 int Ndim, int Kdim)
{
  const int wv = threadIdx.x >> 6, lane = threadIdx.x & 63;
  const int m0 = blockIdx.y * 64;
  const int n0 = blockIdx.x * 64 + wv * 16;
  const int lm = lane & 15;
  const int kq = (lane >> 4) * 8;
  f32x4 acc0 = {0.f,0.f,0.f,0.f}, acc1 = acc0, acc2 = acc0, acc3 = acc0;
  const bool nok = (n0 + lm) < Ndim;
  const short* ap = A + (size_t)(m0 + lm) * lda + kq;
  const short* wp = W + (size_t)(nok ? (n0 + lm) : 0) * ldw + kq;
  const size_t ar16 = (size_t)16 * lda;
  const bf16x8 bz = {0,0,0,0,0,0,0,0};

  for (int k0 = 0; k0 < Kdim; k0 += 32) {
    bf16x8 b = bz;
    if (nok) b = *(const bf16x8*)(wp + k0);
    bf16x8 a0 = *(const bf16x8*)(ap + k0);
    bf16x8 a1 = *(const bf16x8*)(ap + ar16 + k0);
    bf16x8 a2 = *(const bf16x8*)(ap + 2*ar16 + k0);
    bf16x8 a3 = *(const bf16x8*)(ap + 3*ar16 + k0);
    acc0 = __builtin_amdgcn_mfma_f32_16x16x32_bf16(a0, b, acc0, 0, 0, 0);
    acc1 = __builtin_amdgcn_mfma_f32_16x16x32_bf16(a1, b, acc1, 0, 0, 0);
    acc2 = __builtin_amdgcn_mfma_f32_16x16x32_bf16(a2, b, acc2, 0, 0, 0);
    acc3 = __builtin_amdgcn_mfma_f32_16x16x32_bf16(a3, b, acc3, 0, 0, 0);
  }

  const int ncol = n0 + lm;
  if (ncol < Ndim) {
    const int mr = m0 + (lane >> 4) * 4;
    f32x4 av[4] = {acc0, acc1, acc2, acc3};
#pragma unroll
    for (int mt = 0; mt < 4; mt++) {
#pragma unroll
      for (int reg = 0; reg < 4; reg++) {
        int m = mr + mt*16 + reg;
        C[(size_t)m*ldc + ncol] = f2bs(av[mt][reg]);
      }
    }
  }
}

// ---------------- fp32 SIMT GEMM (kept for dt: K=24) ----------------
template<int EPI>
__launch_bounds__(256)
__global__ void gemm_k(const float* __restrict__ A, int lda,
                       const float* __restrict__ W,
                       float* __restrict__ C, int ldc,
                       int Ndim, int Kdim,
                       const float* __restrict__ bias,
                       const float* __restrict__ res)
{
  __shared__ float As[16][68];
  __shared__ float Bs[16][68];
  const int tid = threadIdx.x;
  const int m0 = blockIdx.y * 64;
  const int n0 = blockIdx.x * 64;
  const int tr = tid >> 4, tc = tid & 15;
  const int r  = tid >> 2, q  = tid & 3;
  float acc[4][4] = {};

  for (int k0 = 0; k0 < Kdim; k0 += 16) {
    {
      const float* ap = A + (size_t)(m0 + r) * lda + (k0 + q*4);
      float v0=0.f,v1=0.f,v2=0.f,v3=0.f;
      int kc = Kdim - (k0 + q*4);
      if (kc >= 4) { float4 t4 = *(const float4*)ap; v0=t4.x; v1=t4.y; v2=t4.z; v3=t4.w; }
      else { if (kc>0) v0=ap[0]; if (kc>1) v1=ap[1]; if (kc>2) v2=ap[2]; }
      As[q*4+0][r]=v0; As[q*4+1][r]=v1; As[q*4+2][r]=v2; As[q*4+3][r]=v3;
    }
    {
      int nr = n0 + r;
      float v0=0.f,v1=0.f,v2=0.f,v3=0.f;
      if (nr < Ndim) {
        const float* wp = W + (size_t)nr * Kdim + (k0 + q*4);
        int kc = Kdim - (k0 + q*4);
        if (kc >= 4) { float4 t4 = *(const float4*)wp; v0=t4.x; v1=t4.y; v2=t4.z; v3=t4.w; }
        else { if (kc>0) v0=wp[0]; if (kc>1) v1=wp[1]; if (kc>2) v2=wp[2]; }
      }
      Bs[q*4+0][r]=v0; Bs[q*4+1][r]=v1; Bs[q*4+2][r]=v2; Bs[q*4+3][r]=v3;
    }
    __syncthreads();
#pragma unroll
    for (int kk = 0; kk < 16; kk++) {
      float4 a4 = *(const float4*)&As[kk][tr*4];
      float4 b4 = *(const float4*)&Bs[kk][tc*4];
      float av[4] = {a4.x,a4.y,a4.z,a4.w};
      float bv[4] = {b4.x,b4.y,b4.z,b4.w};
#pragma unroll
      for (int i2=0;i2<4;i2++)
#pragma unroll
        for (int j2=0;j2<4;j2++)
          acc[i2][j2] = __builtin_fmaf(av[i2], bv[j2], acc[i2][j2]);
    }
    __syncthreads();
  }

#pragma unroll
  for (int i2=0;i2<4;i2++){
    int m = m0 + tr*4 + i2;
#pragma unroll
    for (int j2=0;j2<4;j2++){
      int n = n0 + tc*4 + j2;
      if (n < Ndim){
        float v = acc[i2][j2];
        if (EPI == 1) { v += bias[n]; v = (v > 20.f) ? v : log1pf(__expf(v)); }
        C[(size_t)m*ldc + n] = v;
      }
    }
  }
}

// ---------------- conversions / misc ----------------
__global__ void f2b5_k(const float* __restrict__ a0, const float* __restrict__ a1,
                       const float* __restrict__ a2, const float* __restrict__ a3,
                       const float* __restrict__ a4, short* __restrict__ o,
                       int s0, int s1, int s2, int s3, int s4)
{
  int id = blockIdx.x*256 + threadIdx.x;
  int e0 = s0, e1 = e0+s1, e2 = e1+s2, e3 = e2+s3, e4 = e3+s4;
  if (id >= e4) return;
  float v;
  if      (id < e0) v = a0[id];
  else if (id < e1) v = a1[id-e0];
  else if (id < e2) v = a2[id-e1];
  else if (id < e3) v = a3[id-e2];
  else              v = a4[id-e3];
  o[id] = f2bs(v);
}
__global__ void cvt_dual_k(const float* __restrict__ in, float* __restrict__ of,
                           short* __restrict__ ob, int n){
  int id = blockIdx.x*256 + threadIdx.x;
  if (id < n) { float v = in[id]; of[id] = v; ob[id] = f2bs(v); }
}

// depthwise causal conv (k=4) over permuted sequence + bias + silu; bf16 in/out
__launch_bounds__(256)
__global__ void conv_k(const short* __restrict__ xzb, const float* __restrict__ cw,
                       const float* __restrict__ cb, short* __restrict__ ucv_b)
{
  int id = blockIdx.x*256 + threadIdx.x;          // ((dir*4+b)*1024+t)*768+d
  int d = id % DINNER;
  int t = (id / DINNER) & 1023;
  int btdir = id / (DINNER*1024);
  int b_ = btdir & 3, dir = btdir >> 2;
  float s = cb[d];
  const short* up = xzb + (size_t)b_*1024*1536 + d;
#pragma unroll
  for (int j=0;j<4;j++){
    int tm = t - 3 + j;
    if (tm >= 0) s += cw[d*4+j] * bs2f(up[(size_t)perm_tok(dir,tm)*1536]);
  }
  ucv_b[id] = f2bs(silu_f(s));
}

// ============ chunked selective scan ============
// Pass A: grid (3, NCHUNK, 16): local scan from 0 -> hL[n]; accumulate sum_dt
__launch_bounds__(256)
__global__ void chunk_scan_k(const float* __restrict__ dtb, const short* __restrict__ ucv_b,
                             const float* __restrict__ xdb, const float* __restrict__ A_log,
                             float* __restrict__ sums, float* __restrict__ hLb)
{
  const int d  = blockIdx.x * 256 + threadIdx.x;   // 0..767
  const int c  = blockIdx.y;                       // chunk
  const int bd = blockIdx.z;                       // dir*4+b

  float A2[NSTATE];
#pragma unroll
  for (int n=0;n<NSTATE;n++)
    A2[n] = -__expf(A_log[d*NSTATE + n]) * 1.44269504f;

  const size_t rowbase = (size_t)bd*1024 + (size_t)c*TCHUNK;
  const float* dtp = dtb + rowbase*DINNER + d;
  const short* up  = ucv_b + rowbase*DINNER + d;
  const float* bc  = xdb + rowbase*GCOLS + DTRANK;   // block-uniform

  float h[NSTATE] = {};
  float sdt = 0.f;

  for (int tg=0; tg<TCHUNK; tg+=4){
    float dt4[4], u4[4];
#pragma unroll
    for (int q=0;q<4;q++){
      dt4[q] = dtp[(size_t)(tg+q)*DINNER];
      u4[q]  = bs2f(up[(size_t)(tg+q)*DINNER]);
    }
#pragma unroll
    for (int q=0;q<4;q++){
      const float* Bv = bc + (tg+q)*GCOLS;           // uniform -> s_load
      float4 B0 = *(const float4*)(Bv+0), B1 = *(const float4*)(Bv+4);
      float4 B2 = *(const float4*)(Bv+8), B3 = *(const float4*)(Bv+12);
      float Bf[NSTATE] = {B0.x,B0.y,B0.z,B0.w, B1.x,B1.y,B1.z,B1.w,
                          B2.x,B2.y,B2.z,B2.w, B3.x,B3.y,B3.z,B3.w};
      float dt = dt4[q], du = dt4[q]*u4[q];
      sdt += dt;
#pragma unroll
      for (int n=0;n<NSTATE;n++){
        float w = EXP2F(dt * A2[n]);
        h[n] = h[n]*w + du * Bf[n];
      }
    }
  }
  size_t ob = ((size_t)(bd*NCHUNK + c) * NSTATE) * DINNER + d;
#pragma unroll
  for (int n=0;n<NSTATE;n++)
    hLb[ob + (size_t)n*DINNER] = h[n];
  sums[(size_t)(bd*NCHUNK + c)*DINNER + d] = sdt;
}

// Pass B: serial combine over chunks; W reconstructed from sum_dt; hLb -> chunk-initial h0
__launch_bounds__(256)
__global__ void chunk_comb_k(const float* __restrict__ sums, const float* __restrict__ A_log,
                             float* __restrict__ hLb)
{
  int id = blockIdx.x*256 + threadIdx.x;    // (dir*4+b)*768+d
  int d = id % DINNER;
  int bd = id / DINNER;
  float A2[NSTATE];
#pragma unroll
  for (int n=0;n<NSTATE;n++)
    A2[n] = -__expf(A_log[d*NSTATE + n]) * 1.44269504f;
  float h[NSTATE] = {};
  for (int c=0; c<NCHUNK; c++){
    size_t ob = ((size_t)(bd*NCHUNK + c) * NSTATE) * DINNER + d;
    float sdt = sums[(size_t)(bd*NCHUNK + c)*DINNER + d];
#pragma unroll
    for (int n=0;n<NSTATE;n++){
      float Wc = EXP2F(A2[n] * sdt);
      float hL = hLb[ob + (size_t)n*DINNER];
      float h0 = h[n];
      h[n] = Wc*h0 + hL;
      hLb[ob + (size_t)n*DINNER] = h0;
    }
  }
}

// Pass C: replay from h0, emit y, scatter-add token-space
__launch_bounds__(256)
__global__ void chunk_emit_k(const float* __restrict__ dtb, const short* __restrict__ ucv_b,
                             const float* __restrict__ xdb, const float* __restrict__ A_log,
                             const float* __restrict__ Dp, const float* __restrict__ h0b,
                             float* __restrict__ acc)
{
  const int d  = blockIdx.x * 256 + threadIdx.x;
  const int c  = blockIdx.y;
  const int bd = blockIdx.z;
  const int b  = bd & 3, dir = bd >> 2;

  float A2[NSTATE];
#pragma unroll
  for (int n=0;n<NSTATE;n++)
    A2[n] = -__expf(A_log[d*NSTATE + n]) * 1.44269504f;
  float Dd = Dp[d];

  const size_t rowbase = (size_t)bd*1024 + (size_t)c*TCHUNK;
  const float* dtp = dtb + rowbase*DINNER + d;
  const short* up  = ucv_b + rowbase*DINNER + d;
  const float* bc  = xdb + rowbase*GCOLS + DTRANK;   // block-uniform
  float* ab = acc + (size_t)b*1024*DINNER + d;

  float h[NSTATE];
  size_t ob = ((size_t)(bd*NCHUNK + c) * NSTATE) * DINNER + d;
#pragma unroll
  for (int n=0;n<NSTATE;n++) h[n] = h0b[ob + (size_t)n*DINNER];

  const int t0 = c * TCHUNK;
  for (int tg=0; tg<TCHUNK; tg+=4){
    float dt4[4], u4[4];
#pragma unroll
    for (int q=0;q<4;q++){
      dt4[q] = dtp[(size_t)(tg+q)*DINNER];
      u4[q]  = bs2f(up[(size_t)(tg+q)*DINNER]);
    }
#pragma unroll
    for (int q=0;q<4;q++){
      const float* Bv = bc + (tg+q)*GCOLS;           // uniform -> s_load
      float4 B0 = *(const float4*)(Bv+0), B1 = *(const float4*)(Bv+4);
      float4 B2 = *(const float4*)(Bv+8), B3 = *(const float4*)(Bv+12);
      float4 C0 = *(const float4*)(Bv+16), C1 = *(const float4*)(Bv+20);
      float4 C2 = *(const float4*)(Bv+24), C3 = *(const float4*)(Bv+28);
      float Bf[NSTATE] = {B0.x,B0.y,B0.z,B0.w, B1.x,B1.y,B1.z,B1.w,
                          B2.x,B2.y,B2.z,B2.w, B3.x,B3.y,B3.z,B3.w};
      float Cf[NSTATE] = {C0.x,C0.y,C0.z,C0.w, C1.x,C1.y,C1.z,C1.w,
                          C2.x,C2.y,C2.z,C2.w, C3.x,C3.y,C3.z,C3.w};
      float dt = dt4[q], u = u4[q], du = dt*u;
      float y = 0.f;
#pragma unroll
      for (int n=0;n<NSTATE;n++){
        float w = EXP2F(dt * A2[n]);
        h[n] = h[n]*w + du * Bf[n];
        y = __builtin_fmaf(h[n], Cf[n], y);
      }
      int tok = perm_tok(dir, t0 + tg + q);
      atomicAdd(ab + (size_t)tok*DINNER, y + u*Dd);
    }
  }
}

// acc *= silu(z); also emit bf16 (z read from bf16 xz)
__global__ void combine_k(float* __restrict__ acc, const short* __restrict__ xzb,
                          short* __restrict__ acc_b)
{
  int id = blockIdx.x*256 + threadIdx.x;     // < MROWS*DINNER
  int row = id / DINNER;
  int d = id - row*DINNER;
  float z = bs2f(xzb[(size_t)row*1536 + DINNER + d]);
  float v = acc[id] * silu_f(z);
  acc[id] = v;
  acc_b[id] = f2bs(v);
}

// layernorm over 384; fp32 out + bf16 out
__launch_bounds__(256)
__global__ void ln384_k(const float* __restrict__ in, float* __restrict__ out,
                        const float* __restrict__ w, const float* __restrict__ b,
                        short* __restrict__ bout)
{
  int wv = threadIdx.x >> 6, lane = threadIdx.x & 63;
  size_t row = (size_t)blockIdx.x * 4 + wv;
  const float* ip = in + row * DMODEL;
  float v[6];
#pragma unroll
  for (int k=0;k<6;k++) v[k] = ip[lane + 64*k];
  float s = 0.f;
#pragma unroll
  for (int k=0;k<6;k++) s += v[k];
#pragma unroll
  for (int o=32;o>0;o>>=1) s += __shfl_xor(s, o);
  float mu = s * (1.f/DMODEL);
  float ss = 0.f;
#pragma unroll
  for (int k=0;k<6;k++){ float dd = v[k]-mu; ss += dd*dd; }
#pragma unroll
  for (int o=32;o>0;o>>=1) ss += __shfl_xor(ss, o);
  float inv = rsqrtf(ss*(1.f/DMODEL) + 1e-5f);
  float* op = out + row * DMODEL;
  short* bp = bout + row * DMODEL;
#pragma unroll
  for (int k=0;k<6;k++){
    int c = lane + 64*k;
    float r = (v[k]-mu)*inv*w[c] + b[c];
    op[c] = r;
    bp[c] = f2bs(r);
  }
}

// pixel-shuffle gather + layernorm over 192 + fp32 store
__launch_bounds__(256)
__global__ void peln_k(const float* __restrict__ xe, const float* __restrict__ w,
                       const float* __restrict__ b, float* __restrict__ out)
{
  int wv = threadIdx.x >> 6, lane = threadIdx.x & 63;
  int row = blockIdx.x * 4 + wv;          // b*4096 + h2*64 + w2
  int bb = row >> 12;
  int r2 = row & 4095;
  int h2 = r2 >> 6, w2 = r2 & 63;
  int h = h2 >> 1, s1 = h2 & 1, w_ = w2 >> 1, s2 = w2 & 1;
  const float* ip = xe + ((size_t)(bb*1024 + h*32 + w_))*768 + (s1*2+s2)*192;
  float v[3];
#pragma unroll
  for (int k=0;k<3;k++) v[k] = ip[lane + 64*k];
  float s = v[0]+v[1]+v[2];
#pragma unroll
  for (int o=32;o>0;o>>=1) s += __shfl_xor(s, o);
  float mu = s * (1.f/192);
  float ss = 0.f;
#pragma unroll
  for (int k=0;k<3;k++){ float dd=v[k]-mu; ss+=dd*dd; }
#pragma unroll
  for (int o=32;o>0;o>>=1) ss += __shfl_xor(ss, o);
  float inv = rsqrtf(ss*(1.f/192) + 1e-5f);
  float* op = out + (size_t)row * 192;
#pragma unroll
  for (int k=0;k<3;k++){ int c = lane + 64*k; op[c] = (v[k]-mu)*inv*w[c] + b[c]; }
}

extern "C" void kernel_launch(void* const* d_in, const int* in_sizes, int n_in,
                              void* d_out, int out_size, void* d_ws, size_t ws_size,
                              hipStream_t stream)
{
  const float* x_in   = (const float*)d_in[0];
  const float* in_w   = (const float*)d_in[1];
  const float* conv_w = (const float*)d_in[2];
  const float* conv_b = (const float*)d_in[3];
  const float* xp_w   = (const float*)d_in[4];
  const float* dt_w   = (const float*)d_in[5];
  const float* dt_b   = (const float*)d_in[6];
  const float* A_log  = (const float*)d_in[7];
  const float* Dp     = (const float*)d_in[8];
  const float* mn_w   = (const float*)d_in[9];
  const float* mn_b   = (const float*)d_in[10];
  const float* mout_w = (const float*)d_in[11];
  const float* bp_w   = (const float*)d_in[12];
  const float* bp_b   = (const float*)d_in[13];
  const float* ln_w   = (const float*)d_in[14];
  const float* ln_b   = (const float*)d_in[15];
  const float* exp_w  = (const float*)d_in[16];
  const float* pe_w   = (const float*)d_in[17];
  const float* pe_b   = (const float*)d_in[18];

  float* ws = (float*)d_ws;
  // layout in float units
  float* xcur = ws;                                      // 1,572,864
  short* xz_b = (short*)(xcur + 1572864);                // 6,291,456 shorts (3,145,728 f)
  short* ucv_b = (short*)(xcur + 1572864 + 3145728);     // 12,582,912 shorts (6,291,456 f)
  float* xdb  = xcur + 1572864 + 3145728 + 6291456;      // 917,504
  float* dtb  = xdb + 917504;                            // 12,582,912
  float* acc  = dtb + 12582912;                          // 3,145,728
  float* big  = acc + 3145728;                           // 6,291,456 (t1|t2 or hLb)
  float* t1   = big;
  float* t2   = t1 + 1572864;
  float* hLb  = big;
  short* in_w_b   = (short*)(big + 6291456);             // 1,179,648 sh
  short* xp_w_b   = in_w_b + (size_t)2*1536*DMODEL;      // 86,016 sh
  short* mout_w_b = xp_w_b + (size_t)2*GCOLS*DINNER;     // 589,824 sh
  short* bp_w_b   = mout_w_b + (size_t)2*DMODEL*DINNER;  // 294,912 sh
  short* exp_w_b  = bp_w_b + (size_t)2*DMODEL*DMODEL;    // 294,912 sh
  float* sums     = (float*)(exp_w_b + (size_t)2*DMODEL*DMODEL);  // 393,216 f
  short* xcur_b   = (short*)(sums + 393216);             // 3,145,728 sh
  // aliases (dtb dead after emit pass)
  float* t3    = dtb;
  short* t2b   = (short*)(dtb + (size_t)2*1024*1024);
  short* acc_b = (short*)(dtb + (size_t)3*1024*1024 + 262144);
  float* xe    = acc;

  // weight conversions (single batched launch)
  {
    int s0 = 2*1536*DMODEL, s1 = 2*GCOLS*DINNER, s2 = 2*DMODEL*DINNER,
        s3 = 2*DMODEL*DMODEL, s4 = 2*DMODEL*DMODEL;
    int tot = s0+s1+s2+s3+s4;
    f2b5_k<<<dim3((tot+255)/256), dim3(256), 0, stream>>>(
        in_w, xp_w, mout_w, bp_w, exp_w, in_w_b, s0, s1, s2, s3, s4);
  }
  cvt_dual_k<<<dim3((MROWS*DMODEL)/256), dim3(256), 0, stream>>>(x_in, xcur, xcur_b, MROWS*DMODEL);

  for (int i = 0; i < 2; i++) {
    // xz_b = bf16( x @ in_w^T )  (M=4096, N=1536, K=384)  [MFMA, bf16 out]
    gemm_mfma_bout_k<<<dim3(24,64), dim3(256), 0, stream>>>(
        xcur_b, DMODEL, in_w_b + (size_t)i*1536*DMODEL, DMODEL,
        xz_b, 1536, 1536, DMODEL);

    // depthwise conv + silu (bf16 in/out)
    conv_k<<<dim3((4*MROWS*DINNER)/256), dim3(256), 0, stream>>>(
        xz_b, conv_w + (size_t)i*DINNER*4, conv_b + (size_t)i*DINNER, ucv_b);

    // xdb = u @ xp_w^T  (M=16384, N=56, K=768)  [MFMA, merged dirs]
    gemm_mfma_k<0><<<dim3(1,256), dim3(256), 0, stream>>>(
        ucv_b, DINNER, xp_w_b + (size_t)i*GCOLS*DINNER, DINNER,
        xdb, GCOLS, GCOLS, DINNER, nullptr, nullptr);

    // dt = softplus(xdb[:,:24] @ dt_w^T + dt_b)  (M=16384, N=768, K=24)  [SIMT]
    gemm_k<1><<<dim3(12,256), dim3(256), 0, stream>>>(
        xdb, GCOLS, dt_w + (size_t)i*DINNER*DTRANK,
        dtb, DINNER, DINNER, DTRANK, dt_b + (size_t)i*DINNER, nullptr);

    hipMemsetAsync(acc, 0, (size_t)MROWS*DINNER*sizeof(float), stream);
    chunk_scan_k<<<dim3(3, NCHUNK, 16), dim3(256), 0, stream>>>(
        dtb, ucv_b, xdb, A_log + (size_t)i*DINNER*NSTATE, sums, hLb);
    chunk_comb_k<<<dim3(48), dim3(256), 0, stream>>>(sums, A_log + (size_t)i*DINNER*NSTATE, hLb);
    chunk_emit_k<<<dim3(3, NCHUNK, 16), dim3(256), 0, stream>>>(
        dtb, ucv_b, xdb, A_log + (size_t)i*DINNER*NSTATE, Dp + (size_t)i*DINNER, hLb, acc);
    combine_k<<<dim3((MROWS*DINNER)/256), dim3(256), 0, stream>>>(acc, xz_b, acc_b);

    // t1 = ymix @ mout_w^T  (N=384, K=768)  [MFMA]
    gemm_mfma_k<0><<<dim3(6,64), dim3(256), 0, stream>>>(
        acc_b, DINNER, mout_w_b + (size_t)i*DMODEL*DINNER, DINNER,
        t1, DMODEL, DMODEL, DINNER, nullptr, nullptr);
    ln384_k<<<dim3(1024), dim3(256), 0, stream>>>(t1, t2, mn_w + (size_t)i*DMODEL, mn_b + (size_t)i*DMODEL, t2b);
    // t3 = xcur + t2 @ bp_w^T + bp_b  (N=384, K=384)  [MFMA + bias + res]
    gemm_mfma_k<2><<<dim3(6,64), dim3(256), 0, stream>>>(
        t2b, DMODEL, bp_w_b + (size_t)i*DMODEL*DMODEL, DMODEL,
        t3, DMODEL, DMODEL, DMODEL, bp_b + (size_t)i*DMODEL, xcur);
    ln384_k<<<dim3(1024), dim3(256), 0, stream>>>(t3, xcur, ln_w + (size_t)i*DMODEL, ln_b + (size_t)i*DMODEL, xcur_b);
  }

  // xe = x @ exp_w^T  (M=4096, N=768, K=384)  [MFMA]
  gemm_mfma_k<0><<<dim3(12,64), dim3(256), 0, stream>>>(
      xcur_b, DMODEL, exp_w_b, DMODEL, xe, 2*DMODEL, 2*DMODEL, DMODEL, nullptr, nullptr);
  // pixel-shuffle + LN(192) -> fp32 out
  peln_k<<<dim3(4096), dim3(256), 0, stream>>>(xe, pe_w, pe_b, (float*)d_out);
}

// Round 9
// 778.347 us; speedup vs baseline: 3.1366x; 1.0644x over previous
//
#include <hip/hip_runtime.h>
#include <hip/hip_bf16.h>
#include <math.h>

typedef __hip_bfloat16 bf16;

#define MROWS 4096      // BATCH * L
#define DMODEL 384
#define DINNER 768
#define GCOLS 56        // DT_RANK + 2*D_STATE
#define DTRANK 24
#define NSTATE 16
#define NCHUNK 32
#define TCHUNK 32

typedef __attribute__((ext_vector_type(8))) short bf16x8;
typedef __attribute__((ext_vector_type(4))) float f32x4;

#if __has_builtin(__builtin_amdgcn_exp2f)
#define EXP2F(x) __builtin_amdgcn_exp2f(x)
#else
#define EXP2F(x) exp2f(x)
#endif

__device__ __forceinline__ float silu_f(float x){ return x / (1.f + __expf(-x)); }
__device__ __forceinline__ float softplus_f(float x){
  return (x > 20.f) ? x : __logf(1.f + __expf(x));
}
__device__ __forceinline__ short f2bs(float x){
  bf16 h = __float2bfloat16(x);
  return *(short*)&h;
}
__device__ __forceinline__ float bs2f(short s){
  bf16 h = *(bf16*)&s;
  return __bfloat162float(h);
}

// seq index t -> token index, per direction
__device__ __forceinline__ int perm_tok(int dir, int t){
  if (dir == 0) return t;
  if (dir == 2) return 1023 - t;
  int tt = (dir == 1) ? t : (1023 - t);
  int i = tt >> 5, j = tt & 31;
  return ((31 - j) << 5) | i;   // token = (31-j)*32 + i
}

// ---------------- bf16 MFMA GEMM: C[M,N] = A[M,K] @ W[N,K]^T (fp32 accum) ----
// EPI 0: none (fp32 out); 2: + bias[n] + res[m,n] (fp32 out)
template<int EPI>
__launch_bounds__(256)
__global__ void gemm_mfma_k(const short* __restrict__ A, int lda,
                            const short* __restrict__ W, int ldw,
                            float* __restrict__ C, int ldc,
                            int Ndim, int Kdim,
                            const float* __restrict__ bias,
                            const float* __restrict__ res)
{
  const int wv = threadIdx.x >> 6, lane = threadIdx.x & 63;
  const int m0 = blockIdx.y * 64;
  const int n0 = blockIdx.x * 64 + wv * 16;
  const int lm = lane & 15;          // fragment row (A-m / B-n)
  const int kq = (lane >> 4) * 8;    // fragment k offset
  f32x4 acc0 = {0.f,0.f,0.f,0.f}, acc1 = acc0, acc2 = acc0, acc3 = acc0;
  const bool nok = (n0 + lm) < Ndim;
  const short* ap = A + (size_t)(m0 + lm) * lda + kq;
  const short* wp = W + (size_t)(nok ? (n0 + lm) : 0) * ldw + kq;
  const size_t ar16 = (size_t)16 * lda;
  const bf16x8 bz = {0,0,0,0,0,0,0,0};

  for (int k0 = 0; k0 < Kdim; k0 += 32) {
    bf16x8 b = bz;
    if (nok) b = *(const bf16x8*)(wp + k0);
    bf16x8 a0 = *(const bf16x8*)(ap + k0);
    bf16x8 a1 = *(const bf16x8*)(ap + ar16 + k0);
    bf16x8 a2 = *(const bf16x8*)(ap + 2*ar16 + k0);
    bf16x8 a3 = *(const bf16x8*)(ap + 3*ar16 + k0);
    acc0 = __builtin_amdgcn_mfma_f32_16x16x32_bf16(a0, b, acc0, 0, 0, 0);
    acc1 = __builtin_amdgcn_mfma_f32_16x16x32_bf16(a1, b, acc1, 0, 0, 0);
    acc2 = __builtin_amdgcn_mfma_f32_16x16x32_bf16(a2, b, acc2, 0, 0, 0);
    acc3 = __builtin_amdgcn_mfma_f32_16x16x32_bf16(a3, b, acc3, 0, 0, 0);
  }

  const int ncol = n0 + lm;                 // C/D: col = lane&15
  if (ncol < Ndim) {
    const int mr = m0 + (lane >> 4) * 4;    // C/D: row = quad*4 + reg
    f32x4 av[4] = {acc0, acc1, acc2, acc3};
#pragma unroll
    for (int mt = 0; mt < 4; mt++) {
#pragma unroll
      for (int reg = 0; reg < 4; reg++) {
        int m = mr + mt*16 + reg;
        float v = av[mt][reg];
        if (EPI == 2) v += bias[ncol] + res[(size_t)m*ldc + ncol];
        C[(size_t)m*ldc + ncol] = v;
      }
    }
  }
}

// same GEMM but bf16 output (for in_proj -> xz_b)
__launch_bounds__(256)
__global__ void gemm_mfma_bout_k(const short* __restrict__ A, int lda,
                                 const short* __restrict__ W, int ldw,
                                 short* __restrict__ C, int ldc,
                                 int Ndim, int Kdim)
{
  const int wv = threadIdx.x >> 6, lane = threadIdx.x & 63;
  const int m0 = blockIdx.y * 64;
  const int n0 = blockIdx.x * 64 + wv * 16;
  const int lm = lane & 15;
  const int kq = (lane >> 4) * 8;
  f32x4 acc0 = {0.f,0.f,0.f,0.f}, acc1 = acc0, acc2 = acc0, acc3 = acc0;
  const bool nok = (n0 + lm) < Ndim;
  const short* ap = A + (size_t)(m0 + lm) * lda + kq;
  const short* wp = W + (size_t)(nok ? (n0 + lm) : 0) * ldw + kq;
  const size_t ar16 = (size_t)16 * lda;
  const bf16x8 bz = {0,0,0,0,0,0,0,0};

  for (int k0 = 0; k0 < Kdim; k0 += 32) {
    bf16x8 b = bz;
    if (nok) b = *(const bf16x8*)(wp + k0);
    bf16x8 a0 = *(const bf16x8*)(ap + k0);
    bf16x8 a1 = *(const bf16x8*)(ap + ar16 + k0);
    bf16x8 a2 = *(const bf16x8*)(ap + 2*ar16 + k0);
    bf16x8 a3 = *(const bf16x8*)(ap + 3*ar16 + k0);
    acc0 = __builtin_amdgcn_mfma_f32_16x16x32_bf16(a0, b, acc0, 0, 0, 0);
    acc1 = __builtin_amdgcn_mfma_f32_16x16x32_bf16(a1, b, acc1, 0, 0, 0);
    acc2 = __builtin_amdgcn_mfma_f32_16x16x32_bf16(a2, b, acc2, 0, 0, 0);
    acc3 = __builtin_amdgcn_mfma_f32_16x16x32_bf16(a3, b, acc3, 0, 0, 0);
  }

  const int ncol = n0 + lm;
  if (ncol < Ndim) {
    const int mr = m0 + (lane >> 4) * 4;
    f32x4 av[4] = {acc0, acc1, acc2, acc3};
#pragma unroll
    for (int mt = 0; mt < 4; mt++) {
#pragma unroll
      for (int reg = 0; reg < 4; reg++) {
        int m = mr + mt*16 + reg;
        C[(size_t)m*ldc + ncol] = f2bs(av[mt][reg]);
      }
    }
  }
}

// ---------------- conversions / misc ----------------
__global__ void f2b5_k(const float* __restrict__ a0, const float* __restrict__ a1,
                       const float* __restrict__ a2, const float* __restrict__ a3,
                       const float* __restrict__ a4, short* __restrict__ o,
                       int s0, int s1, int s2, int s3, int s4)
{
  int id = blockIdx.x*256 + threadIdx.x;
  int e0 = s0, e1 = e0+s1, e2 = e1+s2, e3 = e2+s3, e4 = e3+s4;
  if (id >= e4) return;
  float v;
  if      (id < e0) v = a0[id];
  else if (id < e1) v = a1[id-e0];
  else if (id < e2) v = a2[id-e1];
  else if (id < e3) v = a3[id-e2];
  else              v = a4[id-e3];
  o[id] = f2bs(v);
}
__global__ void cvt_dual_k(const float* __restrict__ in, float* __restrict__ of,
                           short* __restrict__ ob, int n){
  int id = blockIdx.x*256 + threadIdx.x;
  if (id < n) { float v = in[id]; of[id] = v; ob[id] = f2bs(v); }
}

// depthwise causal conv (k=4) over permuted sequence + bias + silu; bf16 in/out
__launch_bounds__(256)
__global__ void conv_k(const short* __restrict__ xzb, const float* __restrict__ cw,
                       const float* __restrict__ cb, short* __restrict__ ucv_b)
{
  int id = blockIdx.x*256 + threadIdx.x;          // ((dir*4+b)*1024+t)*768+d
  int d = id % DINNER;
  int t = (id / DINNER) & 1023;
  int btdir = id / (DINNER*1024);
  int b_ = btdir & 3, dir = btdir >> 2;
  float s = cb[d];
  const short* up = xzb + (size_t)b_*1024*1536 + d;
#pragma unroll
  for (int j=0;j<4;j++){
    int tm = t - 3 + j;
    if (tm >= 0) s += cw[d*4+j] * bs2f(up[(size_t)perm_tok(dir,tm)*1536]);
  }
  ucv_b[id] = f2bs(silu_f(s));
}

// ============ chunked selective scan (dt fused) ============
// Pass A: grid (3, NCHUNK, 16): local scan from 0 -> hL[n]; accumulate sum_dt
__launch_bounds__(256)
__global__ void chunk_scan_k(const short* __restrict__ ucv_b,
                             const float* __restrict__ xdb, const float* __restrict__ A_log,
                             const float* __restrict__ dt_w, const float* __restrict__ dt_b,
                             float* __restrict__ sums, float* __restrict__ hLb)
{
  const int d  = blockIdx.x * 256 + threadIdx.x;   // 0..767
  const int c  = blockIdx.y;                       // chunk
  const int bd = blockIdx.z;                       // dir*4+b

  float A2[NSTATE];
#pragma unroll
  for (int n=0;n<NSTATE;n++)
    A2[n] = -__expf(A_log[d*NSTATE + n]) * 1.44269504f;
  float w24[DTRANK];
#pragma unroll
  for (int r=0;r<DTRANK;r++) w24[r] = dt_w[d*DTRANK + r];
  const float bias = dt_b[d];

  const size_t rowbase = (size_t)bd*1024 + (size_t)c*TCHUNK;
  const short* up  = ucv_b + rowbase*DINNER + d;
  const float* bc  = xdb + rowbase*GCOLS;            // block-uniform

  float h[NSTATE] = {};
  float sdt = 0.f;

  for (int tg=0; tg<TCHUNK; tg+=4){
    float u4[4];
#pragma unroll
    for (int q=0;q<4;q++)
      u4[q]  = bs2f(up[(size_t)(tg+q)*DINNER]);
#pragma unroll
    for (int q=0;q<4;q++){
      const float* Xr = bc + (tg+q)*GCOLS;           // uniform -> s_load
      float v = bias;
#pragma unroll
      for (int r=0;r<DTRANK;r++) v = __builtin_fmaf(Xr[r], w24[r], v);
      float dt = softplus_f(v);
      const float* Bv = Xr + DTRANK;
      float4 B0 = *(const float4*)(Bv+0), B1 = *(const float4*)(Bv+4);
      float4 B2 = *(const float4*)(Bv+8), B3 = *(const float4*)(Bv+12);
      float Bf[NSTATE] = {B0.x,B0.y,B0.z,B0.w, B1.x,B1.y,B1.z,B1.w,
                          B2.x,B2.y,B2.z,B2.w, B3.x,B3.y,B3.z,B3.w};
      float du = dt*u4[q];
      sdt += dt;
#pragma unroll
      for (int n=0;n<NSTATE;n++){
        float w = EXP2F(dt * A2[n]);
        h[n] = h[n]*w + du * Bf[n];
      }
    }
  }
  size_t ob = ((size_t)(bd*NCHUNK + c) * NSTATE) * DINNER + d;
#pragma unroll
  for (int n=0;n<NSTATE;n++)
    hLb[ob + (size_t)n*DINNER] = h[n];
  sums[(size_t)(bd*NCHUNK + c)*DINNER + d] = sdt;
}

// Pass B: serial combine over chunks; W reconstructed from sum_dt; hLb -> chunk-initial h0
__launch_bounds__(256)
__global__ void chunk_comb_k(const float* __restrict__ sums, const float* __restrict__ A_log,
                             float* __restrict__ hLb)
{
  int id = blockIdx.x*256 + threadIdx.x;    // (dir*4+b)*768+d
  int d = id % DINNER;
  int bd = id / DINNER;
  float A2[NSTATE];
#pragma unroll
  for (int n=0;n<NSTATE;n++)
    A2[n] = -__expf(A_log[d*NSTATE + n]) * 1.44269504f;
  float h[NSTATE] = {};
  for (int c=0; c<NCHUNK; c++){
    size_t ob = ((size_t)(bd*NCHUNK + c) * NSTATE) * DINNER + d;
    float sdt = sums[(size_t)(bd*NCHUNK + c)*DINNER + d];
#pragma unroll
    for (int n=0;n<NSTATE;n++){
      float Wc = EXP2F(A2[n] * sdt);
      float hL = hLb[ob + (size_t)n*DINNER];
      float h0 = h[n];
      h[n] = Wc*h0 + hL;
      hLb[ob + (size_t)n*DINNER] = h0;
    }
  }
}

// Pass C: replay from h0, emit y, scatter-add token-space (dt fused)
__launch_bounds__(256)
__global__ void chunk_emit_k(const short* __restrict__ ucv_b,
                             const float* __restrict__ xdb, const float* __restrict__ A_log,
                             const float* __restrict__ dt_w, const float* __restrict__ dt_b,
                             const float* __restrict__ Dp, const float* __restrict__ h0b,
                             float* __restrict__ acc)
{
  const int d  = blockIdx.x * 256 + threadIdx.x;
  const int c  = blockIdx.y;
  const int bd = blockIdx.z;
  const int b  = bd & 3, dir = bd >> 2;

  float A2[NSTATE];
#pragma unroll
  for (int n=0;n<NSTATE;n++)
    A2[n] = -__expf(A_log[d*NSTATE + n]) * 1.44269504f;
  float w24[DTRANK];
#pragma unroll
  for (int r=0;r<DTRANK;r++) w24[r] = dt_w[d*DTRANK + r];
  const float bias = dt_b[d];
  float Dd = Dp[d];

  const size_t rowbase = (size_t)bd*1024 + (size_t)c*TCHUNK;
  const short* up  = ucv_b + rowbase*DINNER + d;
  const float* bc  = xdb + rowbase*GCOLS;            // block-uniform
  float* ab = acc + (size_t)b*1024*DINNER + d;

  float h[NSTATE];
  size_t ob = ((size_t)(bd*NCHUNK + c) * NSTATE) * DINNER + d;
#pragma unroll
  for (int n=0;n<NSTATE;n++) h[n] = h0b[ob + (size_t)n*DINNER];

  const int t0 = c * TCHUNK;
  for (int tg=0; tg<TCHUNK; tg+=4){
    float u4[4];
#pragma unroll
    for (int q=0;q<4;q++)
      u4[q]  = bs2f(up[(size_t)(tg+q)*DINNER]);
#pragma unroll
    for (int q=0;q<4;q++){
      const float* Xr = bc + (tg+q)*GCOLS;           // uniform -> s_load
      float v = bias;
#pragma unroll
      for (int r=0;r<DTRANK;r++) v = __builtin_fmaf(Xr[r], w24[r], v);
      float dt = softplus_f(v);
      const float* Bv = Xr + DTRANK;
      float4 B0 = *(const float4*)(Bv+0), B1 = *(const float4*)(Bv+4);
      float4 B2 = *(const float4*)(Bv+8), B3 = *(const float4*)(Bv+12);
      float4 C0 = *(const float4*)(Bv+16), C1 = *(const float4*)(Bv+20);
      float4 C2 = *(const float4*)(Bv+24), C3 = *(const float4*)(Bv+28);
      float Bf[NSTATE] = {B0.x,B0.y,B0.z,B0.w, B1.x,B1.y,B1.z,B1.w,
                          B2.x,B2.y,B2.z,B2.w, B3.x,B3.y,B3.z,B3.w};
      float Cf[NSTATE] = {C0.x,C0.y,C0.z,C0.w, C1.x,C1.y,C1.z,C1.w,
                          C2.x,C2.y,C2.z,C2.w, C3.x,C3.y,C3.z,C3.w};
      float u = u4[q], du = dt*u;
      float y = 0.f;
#pragma unroll
      for (int n=0;n<NSTATE;n++){
        float w = EXP2F(dt * A2[n]);
        h[n] = h[n]*w + du * Bf[n];
        y = __builtin_fmaf(h[n], Cf[n], y);
      }
      int tok = perm_tok(dir, t0 + tg + q);
      atomicAdd(ab + (size_t)tok*DINNER, y + u*Dd);
    }
  }
}

// acc *= silu(z); also emit bf16 (z read from bf16 xz)
__global__ void combine_k(float* __restrict__ acc, const short* __restrict__ xzb,
                          short* __restrict__ acc_b)
{
  int id = blockIdx.x*256 + threadIdx.x;     // < MROWS*DINNER
  int row = id / DINNER;
  int d = id - row*DINNER;
  float z = bs2f(xzb[(size_t)row*1536 + DINNER + d]);
  float v = acc[id] * silu_f(z);
  acc[id] = v;
  acc_b[id] = f2bs(v);
}

// layernorm over 384; fp32 out + bf16 out
__launch_bounds__(256)
__global__ void ln384_k(const float* __restrict__ in, float* __restrict__ out,
                        const float* __restrict__ w, const float* __restrict__ b,
                        short* __restrict__ bout)
{
  int wv = threadIdx.x >> 6, lane = threadIdx.x & 63;
  size_t row = (size_t)blockIdx.x * 4 + wv;
  const float* ip = in + row * DMODEL;
  float v[6];
#pragma unroll
  for (int k=0;k<6;k++) v[k] = ip[lane + 64*k];
  float s = 0.f;
#pragma unroll
  for (int k=0;k<6;k++) s += v[k];
#pragma unroll
  for (int o=32;o>0;o>>=1) s += __shfl_xor(s, o);
  float mu = s * (1.f/DMODEL);
  float ss = 0.f;
#pragma unroll
  for (int k=0;k<6;k++){ float dd = v[k]-mu; ss += dd*dd; }
#pragma unroll
  for (int o=32;o>0;o>>=1) ss += __shfl_xor(ss, o);
  float inv = rsqrtf(ss*(1.f/DMODEL) + 1e-5f);
  float* op = out + row * DMODEL;
  short* bp = bout + row * DMODEL;
#pragma unroll
  for (int k=0;k<6;k++){
    int c = lane + 64*k;
    float r = (v[k]-mu)*inv*w[c] + b[c];
    op[c] = r;
    bp[c] = f2bs(r);
  }
}

// pixel-shuffle gather + layernorm over 192 + fp32 store
__launch_bounds__(256)
__global__ void peln_k(const float* __restrict__ xe, const float* __restrict__ w,
                       const float* __restrict__ b, float* __restrict__ out)
{
  int wv = threadIdx.x >> 6, lane = threadIdx.x & 63;
  int row = blockIdx.x * 4 + wv;          // b*4096 + h2*64 + w2
  int bb = row >> 12;
  int r2 = row & 4095;
  int h2 = r2 >> 6, w2 = r2 & 63;
  int h = h2 >> 1, s1 = h2 & 1, w_ = w2 >> 1, s2 = w2 & 1;
  const float* ip = xe + ((size_t)(bb*1024 + h*32 + w_))*768 + (s1*2+s2)*192;
  float v[3];
#pragma unroll
  for (int k=0;k<3;k++) v[k] = ip[lane + 64*k];
  float s = v[0]+v[1]+v[2];
#pragma unroll
  for (int o=32;o>0;o>>=1) s += __shfl_xor(s, o);
  float mu = s * (1.f/192);
  float ss = 0.f;
#pragma unroll
  for (int k=0;k<3;k++){ float dd=v[k]-mu; ss+=dd*dd; }
#pragma unroll
  for (int o=32;o>0;o>>=1) ss += __shfl_xor(ss, o);
  float inv = rsqrtf(ss*(1.f/192) + 1e-5f);
  float* op = out + (size_t)row * 192;
#pragma unroll
  for (int k=0;k<3;k++){ int c = lane + 64*k; op[c] = (v[k]-mu)*inv*w[c] + b[c]; }
}

extern "C" void kernel_launch(void* const* d_in, const int* in_sizes, int n_in,
                              void* d_out, int out_size, void* d_ws, size_t ws_size,
                              hipStream_t stream)
{
  const float* x_in   = (const float*)d_in[0];
  const float* in_w   = (const float*)d_in[1];
  const float* conv_w = (const float*)d_in[2];
  const float* conv_b = (const float*)d_in[3];
  const float* xp_w   = (const float*)d_in[4];
  const float* dt_w   = (const float*)d_in[5];
  const float* dt_b   = (const float*)d_in[6];
  const float* A_log  = (const float*)d_in[7];
  const float* Dp     = (const float*)d_in[8];
  const float* mn_w   = (const float*)d_in[9];
  const float* mn_b   = (const float*)d_in[10];
  const float* mout_w = (const float*)d_in[11];
  const float* bp_w   = (const float*)d_in[12];
  const float* bp_b   = (const float*)d_in[13];
  const float* ln_w   = (const float*)d_in[14];
  const float* ln_b   = (const float*)d_in[15];
  const float* exp_w  = (const float*)d_in[16];
  const float* pe_w   = (const float*)d_in[17];
  const float* pe_b   = (const float*)d_in[18];

  float* ws = (float*)d_ws;
  // layout in float units
  float* xcur = ws;                                      // 1,572,864
  short* xz_b = (short*)(xcur + 1572864);                // 6,291,456 shorts
  short* ucv_b = (short*)(xcur + 1572864 + 3145728);     // 12,582,912 shorts
  float* xdb  = xcur + 1572864 + 3145728 + 6291456;      // 917,504
  float* scratch = xdb + 917504;                         // 12,582,912 (t3|t2b|acc_b)
  float* acc  = scratch + 12582912;                      // 3,145,728
  float* big  = acc + 3145728;                           // 6,291,456 (t1|t2 or hLb)
  float* t1   = big;
  float* t2   = t1 + 1572864;
  float* hLb  = big;
  short* in_w_b   = (short*)(big + 6291456);
  short* xp_w_b   = in_w_b + (size_t)2*1536*DMODEL;
  short* mout_w_b = xp_w_b + (size_t)2*GCOLS*DINNER;
  short* bp_w_b   = mout_w_b + (size_t)2*DMODEL*DINNER;
  short* exp_w_b  = bp_w_b + (size_t)2*DMODEL*DMODEL;
  float* sums     = (float*)(exp_w_b + (size_t)2*DMODEL*DMODEL);  // 393,216 f
  short* xcur_b   = (short*)(sums + 393216);             // 3,145,728 sh
  // aliases inside scratch
  float* t3    = scratch;
  short* t2b   = (short*)(scratch + (size_t)2*1024*1024);
  short* acc_b = (short*)(scratch + (size_t)3*1024*1024 + 262144);
  float* xe    = acc;

  // weight conversions (single batched launch)
  {
    int s0 = 2*1536*DMODEL, s1 = 2*GCOLS*DINNER, s2 = 2*DMODEL*DINNER,
        s3 = 2*DMODEL*DMODEL, s4 = 2*DMODEL*DMODEL;
    int tot = s0+s1+s2+s3+s4;
    f2b5_k<<<dim3((tot+255)/256), dim3(256), 0, stream>>>(
        in_w, xp_w, mout_w, bp_w, exp_w, in_w_b, s0, s1, s2, s3, s4);
  }
  cvt_dual_k<<<dim3((MROWS*DMODEL)/256), dim3(256), 0, stream>>>(x_in, xcur, xcur_b, MROWS*DMODEL);

  for (int i = 0; i < 2; i++) {
    // xz_b = bf16( x @ in_w^T )  (M=4096, N=1536, K=384)  [MFMA, bf16 out]
    gemm_mfma_bout_k<<<dim3(24,64), dim3(256), 0, stream>>>(
        xcur_b, DMODEL, in_w_b + (size_t)i*1536*DMODEL, DMODEL,
        xz_b, 1536, 1536, DMODEL);

    // depthwise conv + silu (bf16 in/out)
    conv_k<<<dim3((4*MROWS*DINNER)/256), dim3(256), 0, stream>>>(
        xz_b, conv_w + (size_t)i*DINNER*4, conv_b + (size_t)i*DINNER, ucv_b);

    // xdb = u @ xp_w^T  (M=16384, N=56, K=768)  [MFMA, merged dirs]
    gemm_mfma_k<0><<<dim3(1,256), dim3(256), 0, stream>>>(
        ucv_b, DINNER, xp_w_b + (size_t)i*GCOLS*DINNER, DINNER,
        xdb, GCOLS, GCOLS, DINNER, nullptr, nullptr);

    hipMemsetAsync(acc, 0, (size_t)MROWS*DINNER*sizeof(float), stream);
    chunk_scan_k<<<dim3(3, NCHUNK, 16), dim3(256), 0, stream>>>(
        ucv_b, xdb, A_log + (size_t)i*DINNER*NSTATE,
        dt_w + (size_t)i*DINNER*DTRANK, dt_b + (size_t)i*DINNER, sums, hLb);
    chunk_comb_k<<<dim3(48), dim3(256), 0, stream>>>(sums, A_log + (size_t)i*DINNER*NSTATE, hLb);
    chunk_emit_k<<<dim3(3, NCHUNK, 16), dim3(256), 0, stream>>>(
        ucv_b, xdb, A_log + (size_t)i*DINNER*NSTATE,
        dt_w + (size_t)i*DINNER*DTRANK, dt_b + (size_t)i*DINNER,
        Dp + (size_t)i*DINNER, hLb, acc);
    combine_k<<<dim3((MROWS*DINNER)/256), dim3(256), 0, stream>>>(acc, xz_b, acc_b);

    // t1 = ymix @ mout_w^T  (N=384, K=768)  [MFMA]
    gemm_mfma_k<0><<<dim3(6,64), dim3(256), 0, stream>>>(
        acc_b, DINNER, mout_w_b + (size_t)i*DMODEL*DINNER, DINNER,
        t1, DMODEL, DMODEL, DINNER, nullptr, nullptr);
    ln384_k<<<dim3(1024), dim3(256), 0, stream>>>(t1, t2, mn_w + (size_t)i*DMODEL, mn_b + (size_t)i*DMODEL, t2b);
    // t3 = xcur + t2 @ bp_w^T + bp_b  (N=384, K=384)  [MFMA + bias + res]
    gemm_mfma_k<2><<<dim3(6,64), dim3(256), 0, stream>>>(
        t2b, DMODEL, bp_w_b + (size_t)i*DMODEL*DMODEL, DMODEL,
        t3, DMODEL, DMODEL, DMODEL, bp_b + (size_t)i*DMODEL, xcur);
    ln384_k<<<dim3(1024), dim3(256), 0, stream>>>(t3, xcur, ln_w + (size_t)i*DMODEL, ln_b + (size_t)i*DMODEL, xcur_b);
  }

  // xe = x @ exp_w^T  (M=4096, N=768, K=384)  [MFMA]
  gemm_mfma_k<0><<<dim3(12,64), dim3(256), 0, stream>>>(
      xcur_b, DMODEL, exp_w_b, DMODEL, xe, 2*DMODEL, 2*DMODEL, DMODEL, nullptr, nullptr);
  // pixel-shuffle + LN(192) -> fp32 out
  peln_k<<<dim3(4096), dim3(256), 0, stream>>>(xe, pe_w, pe_b, (float*)d_out);
}